// Round 2
// baseline (1259.343 us; speedup 1.0000x reference)
//
#include <hip/hip_runtime.h>
#include <math.h>

#define D_MODEL 1024
#define D_STATE 8
#define D_CONV  4
#define D_INNER 1536
#define DT_RANK 64
#define D_FF    2048
#define BATCH   2
#define SEQ     2048
#define NROWS   (BATCH*SEQ)      // 4096
#define NC      32               // scan chunks
#define LC      (SEQ/NC)         // 64
#define XDBL_W  (DT_RANK + 2*D_STATE)  // 80

// ---------------- LayerNorm ----------------
__global__ __launch_bounds__(256) void ln_kernel(const float* __restrict__ x,
                                                 const float* __restrict__ g,
                                                 const float* __restrict__ b,
                                                 float* __restrict__ out) {
    __shared__ float sbuf[4];
    int row = blockIdx.x;
    int t = threadIdx.x;
    const float4* xr = (const float4*)(x + (size_t)row * D_MODEL);
    float4 v = xr[t];
    float s = v.x + v.y + v.z + v.w;
    for (int o = 32; o; o >>= 1) s += __shfl_down(s, o, 64);
    if ((t & 63) == 0) sbuf[t >> 6] = s;
    __syncthreads();
    float mu = (sbuf[0] + sbuf[1] + sbuf[2] + sbuf[3]) * (1.0f / D_MODEL);
    __syncthreads();
    float d0 = v.x - mu, d1 = v.y - mu, d2 = v.z - mu, d3 = v.w - mu;
    float q = d0*d0 + d1*d1 + d2*d2 + d3*d3;
    for (int o = 32; o; o >>= 1) q += __shfl_down(q, o, 64);
    if ((t & 63) == 0) sbuf[t >> 6] = q;
    __syncthreads();
    float var = (sbuf[0] + sbuf[1] + sbuf[2] + sbuf[3]) * (1.0f / D_MODEL);
    float rs = rsqrtf(var + 1e-5f);
    float4 gv = ((const float4*)g)[t];
    float4 bv = ((const float4*)b)[t];
    float4 o4;
    o4.x = d0 * rs * gv.x + bv.x;
    o4.y = d1 * rs * gv.y + bv.y;
    o4.z = d2 * rs * gv.z + bv.z;
    o4.w = d3 * rs * gv.w + bv.w;
    ((float4*)(out + (size_t)row * D_MODEL))[t] = o4;
}

// ---------------- GEMM (NT: C[m,n] = sum_k A[m,k]*B[n,k]) ----------------
// Epilogues
#define EPI_STORE        0
#define EPI_SOFTPLUS_B   1
#define EPI_RESID        2
#define EPI_BIAS_GELU    3
#define EPI_BIAS_RESID   4

__device__ inline float softplus_f(float x) {
    return (x > 20.0f) ? x : log1pf(__expf(x));
}
__device__ inline float gelu_f(float x) {
    return 0.5f * x * (1.0f + erff(x * 0.70710678118654752f));
}

template<int EPI, bool NGUARD>
__global__ __launch_bounds__(256) void gemm_nt(const float* __restrict__ A, int lda,
                                               const float* __restrict__ B, int ldb,
                                               float* __restrict__ C, int ldc,
                                               int N, int K,
                                               const float* __restrict__ bias,
                                               const float* __restrict__ resid) {
    __shared__ float As[16][68];
    __shared__ float Bs[16][68];
    int t = threadIdx.x;
    int m0 = blockIdx.y * 64;
    int n0 = blockIdx.x * 64;
    int lr = t >> 2;          // 0..63
    int lk = (t & 3) * 4;     // 0,4,8,12
    const float* Aptr = A + (size_t)(m0 + lr) * lda + lk;
    bool bvalid = true;
    int brow = n0 + lr;
    if (NGUARD) { bvalid = brow < N; if (!bvalid) brow = 0; }
    const float* Bptr = B + (size_t)brow * ldb + lk;

    float acc[4][4] = {};
    int tn = t & 15, tm = t >> 4;

    for (int k0 = 0; k0 < K; k0 += 16) {
        float4 a = *(const float4*)(Aptr + k0);
        float4 bb;
        if (NGUARD && !bvalid) { bb.x = bb.y = bb.z = bb.w = 0.0f; }
        else bb = *(const float4*)(Bptr + k0);
        __syncthreads();
        As[lk + 0][lr] = a.x; As[lk + 1][lr] = a.y;
        As[lk + 2][lr] = a.z; As[lk + 3][lr] = a.w;
        Bs[lk + 0][lr] = bb.x; Bs[lk + 1][lr] = bb.y;
        Bs[lk + 2][lr] = bb.z; Bs[lk + 3][lr] = bb.w;
        __syncthreads();
        #pragma unroll
        for (int kk = 0; kk < 16; kk++) {
            float av[4], bv[4];
            #pragma unroll
            for (int i = 0; i < 4; i++) av[i] = As[kk][tm * 4 + i];
            #pragma unroll
            for (int j = 0; j < 4; j++) bv[j] = Bs[kk][tn * 4 + j];
            #pragma unroll
            for (int i = 0; i < 4; i++)
                #pragma unroll
                for (int j = 0; j < 4; j++)
                    acc[i][j] += av[i] * bv[j];
        }
    }

    int col0 = n0 + tn * 4;
    float bc4[4] = {0, 0, 0, 0};
    if (EPI == EPI_SOFTPLUS_B || EPI == EPI_BIAS_GELU || EPI == EPI_BIAS_RESID) {
        #pragma unroll
        for (int j = 0; j < 4; j++) bc4[j] = bias[col0 + j];
    }
    #pragma unroll
    for (int i = 0; i < 4; i++) {
        int r = m0 + tm * 4 + i;
        float v[4];
        #pragma unroll
        for (int j = 0; j < 4; j++) {
            float val = acc[i][j];
            if (EPI == EPI_SOFTPLUS_B) val = softplus_f(val + bc4[j]);
            else if (EPI == EPI_BIAS_GELU) val = gelu_f(val + bc4[j]);
            else if (EPI == EPI_BIAS_RESID) val = val + bc4[j];
            v[j] = val;
        }
        if (EPI == EPI_RESID || EPI == EPI_BIAS_RESID) {
            float4 rv = *(const float4*)(resid + (size_t)r * ldc + col0);
            v[0] += rv.x; v[1] += rv.y; v[2] += rv.z; v[3] += rv.w;
        }
        if (NGUARD) {
            #pragma unroll
            for (int j = 0; j < 4; j++)
                if (col0 + j < N) C[(size_t)r * ldc + col0 + j] = v[j];
        } else {
            float4 st; st.x = v[0]; st.y = v[1]; st.z = v[2]; st.w = v[3];
            *(float4*)(C + (size_t)r * ldc + col0) = st;
        }
    }
}

// ---------------- causal depthwise conv (k=4) + SiLU ----------------
__global__ __launch_bounds__(256) void conv_silu(const float* __restrict__ xz,
                                                 const float* __restrict__ w,
                                                 const float* __restrict__ cb,
                                                 float* __restrict__ u) {
    int idx = blockIdx.x * 256 + threadIdx.x;   // (b*L + l)*D_INNER + d
    int d = idx % D_INNER;
    int bl = idx / D_INNER;                      // b*SEQ + l
    int l = bl % SEQ;
    float s = cb[d];
    #pragma unroll
    for (int k = 0; k < 4; k++) {
        int lp = l - 3 + k;
        if (lp >= 0) s += xz[(size_t)(bl - 3 + k) * (2 * D_INNER) + d] * w[d * 4 + k];
    }
    float sig = 1.0f / (1.0f + __expf(-s));
    u[idx] = s * sig;
}

// ---------------- selective scan: pass A (per-chunk affine) ----------------
__global__ __launch_bounds__(256) void scan_passA(const float* __restrict__ delta,
                                                  const float* __restrict__ u,
                                                  const float* __restrict__ xdbl,
                                                  const float* __restrict__ A_log,
                                                  float* __restrict__ P,
                                                  float* __restrict__ S) {
    int d = blockIdx.x * 256 + threadIdx.x;
    int c = blockIdx.y, b = blockIdx.z;
    __shared__ float bc[LC][16];
    int base_row = b * SEQ + c * LC;
    for (int e = threadIdx.x; e < LC * 16; e += 256) {
        int lrr = e >> 4, col = e & 15;
        bc[lrr][col] = xdbl[(size_t)(base_row + lrr) * XDBL_W + DT_RANK + col];
    }
    __syncthreads();
    float Ad[8];
    #pragma unroll
    for (int n = 0; n < 8; n++) Ad[n] = -__expf(A_log[d * 8 + n]);
    float prod[8], hs[8];
    #pragma unroll
    for (int n = 0; n < 8; n++) { prod[n] = 1.0f; hs[n] = 0.0f; }
    for (int lrr = 0; lrr < LC; lrr++) {
        int row = base_row + lrr;
        float dl = delta[(size_t)row * D_INNER + d];
        float uu = u[(size_t)row * D_INNER + d];
        float du = dl * uu;
        #pragma unroll
        for (int n = 0; n < 8; n++) {
            float dA = __expf(dl * Ad[n]);
            prod[n] *= dA;
            hs[n] = dA * hs[n] + du * bc[lrr][n];
        }
    }
    size_t o = ((size_t)((size_t)b * NC + c) * D_INNER + d) * 8;
    #pragma unroll
    for (int n = 0; n < 8; n++) { P[o + n] = prod[n]; S[o + n] = hs[n]; }
}

// ---------------- scan: pass B (combine chunks) ----------------
__global__ __launch_bounds__(256) void scan_passB(const float* __restrict__ P,
                                                  const float* __restrict__ S,
                                                  float* __restrict__ hstart) {
    int tid = blockIdx.x * 256 + threadIdx.x;    // B * D_INNER * 8 = 24576
    int b = tid / (D_INNER * 8);
    int rem = tid % (D_INNER * 8);
    float h = 0.0f;
    for (int c = 0; c < NC; c++) {
        size_t o = (size_t)(b * NC + c) * (D_INNER * 8) + rem;
        hstart[o] = h;
        h = P[o] * h + S[o];
    }
}

// ---------------- scan: pass C (final y + gate) ----------------
__global__ __launch_bounds__(256) void scan_passC(const float* __restrict__ delta,
                                                  const float* __restrict__ u,
                                                  const float* __restrict__ xdbl,
                                                  const float* __restrict__ A_log,
                                                  const float* __restrict__ hstart,
                                                  const float* __restrict__ xz,
                                                  const float* __restrict__ Dp,
                                                  float* __restrict__ ygate) {
    int d = blockIdx.x * 256 + threadIdx.x;
    int c = blockIdx.y, b = blockIdx.z;
    __shared__ float bc[LC][16];
    int base_row = b * SEQ + c * LC;
    for (int e = threadIdx.x; e < LC * 16; e += 256) {
        int lrr = e >> 4, col = e & 15;
        bc[lrr][col] = xdbl[(size_t)(base_row + lrr) * XDBL_W + DT_RANK + col];
    }
    __syncthreads();
    float Ad[8];
    #pragma unroll
    for (int n = 0; n < 8; n++) Ad[n] = -__expf(A_log[d * 8 + n]);
    float h[8];
    size_t ho = ((size_t)((size_t)b * NC + c) * D_INNER + d) * 8;
    #pragma unroll
    for (int n = 0; n < 8; n++) h[n] = hstart[ho + n];
    float Dd = Dp[d];
    for (int lrr = 0; lrr < LC; lrr++) {
        int row = base_row + lrr;
        float dl = delta[(size_t)row * D_INNER + d];
        float uu = u[(size_t)row * D_INNER + d];
        float du = dl * uu;
        float y = 0.0f;
        #pragma unroll
        for (int n = 0; n < 8; n++) {
            float dA = __expf(dl * Ad[n]);
            h[n] = dA * h[n] + du * bc[lrr][n];
            y += h[n] * bc[lrr][8 + n];
        }
        y += uu * Dd;
        float z = xz[(size_t)row * (2 * D_INNER) + D_INNER + d];
        float sig = 1.0f / (1.0f + __expf(-z));
        ygate[(size_t)row * D_INNER + d] = y * (z * sig);
    }
}

// ---------------- launch ----------------
extern "C" void kernel_launch(void* const* d_in, const int* in_sizes, int n_in,
                              void* d_out, int out_size, void* d_ws, size_t ws_size,
                              hipStream_t stream) {
    const float* x         = (const float*)d_in[0];
    const float* ln1_g     = (const float*)d_in[1];
    const float* ln1_b     = (const float*)d_in[2];
    const float* ln2_g     = (const float*)d_in[3];
    const float* ln2_b     = (const float*)d_in[4];
    const float* in_proj_w = (const float*)d_in[5];
    const float* conv_w    = (const float*)d_in[6];
    const float* conv_b    = (const float*)d_in[7];
    const float* x_proj_w  = (const float*)d_in[8];
    const float* dt_proj_w = (const float*)d_in[9];
    const float* dt_proj_b = (const float*)d_in[10];
    const float* A_log     = (const float*)d_in[11];
    const float* Dp        = (const float*)d_in[12];
    const float* out_proj_w= (const float*)d_in[13];
    const float* ffn_w1    = (const float*)d_in[14];
    const float* ffn_b1    = (const float*)d_in[15];
    const float* ffn_w2    = (const float*)d_in[16];
    const float* ffn_b2    = (const float*)d_in[17];
    float* out = (float*)d_out;
    float* ws  = (float*)d_ws;

    // workspace layout (floats)
    float* xz     = ws;                                  // 4096*3072 = 12,582,912 (reused later for hff)
    float* xp     = xz + (size_t)NROWS * 2 * D_INNER;    // 4096*1024 (reused for xn)
    float* u      = xp + (size_t)NROWS * D_MODEL;        // 4096*1536
    float* xdbl   = u + (size_t)NROWS * D_INNER;         // 4096*80
    float* delta  = xdbl + (size_t)NROWS * XDBL_W;       // 4096*1536
    float* P      = delta + (size_t)NROWS * D_INNER;     // 2*32*1536*8
    float* S      = P + (size_t)BATCH * NC * D_INNER * 8;
    float* hstart = S + (size_t)BATCH * NC * D_INNER * 8;
    float* ygate  = hstart + (size_t)BATCH * NC * D_INNER * 8;  // 4096*1536
    float* x2     = ygate + (size_t)NROWS * D_INNER;     // 4096*1024
    float* xn     = xp;       // reuse (xp dead after in_proj GEMM)
    float* hff    = xz;       // reuse (xz dead after passC)

    // 1. LN1
    ln_kernel<<<NROWS, 256, 0, stream>>>(x, ln1_g, ln1_b, xp);
    // 2. in_proj: xz = xp @ in_proj_w^T   (4096 x 3072, K=1024)
    gemm_nt<EPI_STORE, false><<<dim3(3072/64, NROWS/64), 256, 0, stream>>>(
        xp, D_MODEL, in_proj_w, D_MODEL, xz, 2*D_INNER, 2*D_INNER, D_MODEL, nullptr, nullptr);
    // 3. conv + silu -> u
    conv_silu<<<(NROWS * D_INNER) / 256, 256, 0, stream>>>(xz, conv_w, conv_b, u);
    // 4. x_proj: xdbl = u @ x_proj_w^T   (4096 x 80, K=1536)
    gemm_nt<EPI_STORE, true><<<dim3(2, NROWS/64), 256, 0, stream>>>(
        u, D_INNER, x_proj_w, D_INNER, xdbl, XDBL_W, XDBL_W, D_INNER, nullptr, nullptr);
    // 5. dt_proj + softplus: delta = softplus(xdbl[:, :64] @ dt_proj_w^T + b)  (4096 x 1536, K=64)
    gemm_nt<EPI_SOFTPLUS_B, false><<<dim3(D_INNER/64, NROWS/64), 256, 0, stream>>>(
        xdbl, XDBL_W, dt_proj_w, DT_RANK, delta, D_INNER, D_INNER, DT_RANK, dt_proj_b, nullptr);
    // 6-8. selective scan
    scan_passA<<<dim3(D_INNER/256, NC, BATCH), 256, 0, stream>>>(delta, u, xdbl, A_log, P, S);
    scan_passB<<<(BATCH * D_INNER * 8) / 256, 256, 0, stream>>>(P, S, hstart);
    scan_passC<<<dim3(D_INNER/256, NC, BATCH), 256, 0, stream>>>(delta, u, xdbl, A_log, hstart, xz, Dp, ygate);
    // 9. out_proj + residual: x2 = ygate @ out_proj_w^T + x   (4096 x 1024, K=1536)
    gemm_nt<EPI_RESID, false><<<dim3(D_MODEL/64, NROWS/64), 256, 0, stream>>>(
        ygate, D_INNER, out_proj_w, D_INNER, x2, D_MODEL, D_MODEL, D_INNER, nullptr, x);
    // 10. LN2
    ln_kernel<<<NROWS, 256, 0, stream>>>(x2, ln2_g, ln2_b, xn);
    // 11. ffn1 + gelu: hff = gelu(xn @ ffn_w1^T + b1)   (4096 x 2048, K=1024)
    gemm_nt<EPI_BIAS_GELU, false><<<dim3(D_FF/64, NROWS/64), 256, 0, stream>>>(
        xn, D_MODEL, ffn_w1, D_MODEL, hff, D_FF, D_FF, D_MODEL, ffn_b1, nullptr);
    // 12. ffn2 + bias + residual: out = x2 + hff @ ffn_w2^T + b2   (4096 x 1024, K=2048)
    gemm_nt<EPI_BIAS_RESID, false><<<dim3(D_MODEL/64, NROWS/64), 256, 0, stream>>>(
        hff, D_FF, ffn_w2, D_FF, out, D_MODEL, D_MODEL, D_FF, ffn_b2, x2);
}

// Round 3
// 364.919 us; speedup vs baseline: 3.4510x; 3.4510x over previous
//
#include <hip/hip_runtime.h>
#include <math.h>

#define D_MODEL 1024
#define D_STATE 8
#define D_CONV  4
#define D_INNER 1536
#define DT_RANK 64
#define D_FF    2048
#define BATCH   2
#define SEQ     2048
#define NROWS   (BATCH*SEQ)      // 4096
#define NC      32               // scan chunks
#define LC      (SEQ/NC)         // 64
#define XPAD    128              // padded x_dbl width (was 80)

typedef short bf16x8 __attribute__((ext_vector_type(8)));
typedef float f32x4  __attribute__((ext_vector_type(4)));

__device__ inline unsigned short f2bf(float x) {
    union { float f; unsigned u; } v; v.f = x;
    unsigned r = v.u + 0x7fffu + ((v.u >> 16) & 1u);
    return (unsigned short)(r >> 16);
}
__device__ inline float bf2f(unsigned short h) {
    union { unsigned u; float f; } v; v.u = ((unsigned)h) << 16;
    return v.f;
}
__device__ inline float softplus_f(float x) {
    return (x > 20.0f) ? x : log1pf(__expf(x));
}
__device__ inline float gelu_f(float x) {
    return 0.5f * x * (1.0f + erff(x * 0.70710678118654752f));
}
__device__ inline float silu_f(float x) {
    return x / (1.0f + __expf(-x));
}
__device__ inline void gload16(const unsigned short* g, unsigned short* l) {
    typedef unsigned int u32;
    __builtin_amdgcn_global_load_lds(
        (const __attribute__((address_space(1))) u32*)g,
        (__attribute__((address_space(3))) u32*)l, 16, 0, 0);
}

// ---------------- weight f32 -> bf16 conversion (fused 5 segments) ----------------
// seg sizes (elems): in_proj 3145728, dt 98304, out 1572864, ffn1 2097152, ffn2 2097152
__global__ __launch_bounds__(256) void wconv(const float* __restrict__ s0, unsigned short* __restrict__ d0,
                                             const float* __restrict__ s1, unsigned short* __restrict__ d1,
                                             const float* __restrict__ s2, unsigned short* __restrict__ d2,
                                             const float* __restrict__ s3, unsigned short* __restrict__ d3,
                                             const float* __restrict__ s4, unsigned short* __restrict__ d4) {
    int b = blockIdx.x;
    const float* s; unsigned short* d; int base;
    if      (b < 1536) { s = s0; d = d0; base = b * 2048; }
    else if (b < 1584) { s = s1; d = d1; base = (b - 1536) * 2048; }
    else if (b < 2352) { s = s2; d = d2; base = (b - 1584) * 2048; }
    else if (b < 3376) { s = s3; d = d3; base = (b - 2352) * 2048; }
    else               { s = s4; d = d4; base = (b - 3376) * 2048; }
    int i = base + threadIdx.x * 8;
    float4 v0 = *(const float4*)(s + i);
    float4 v1 = *(const float4*)(s + i + 4);
    ushort4 a, c;
    a.x = f2bf(v0.x); a.y = f2bf(v0.y); a.z = f2bf(v0.z); a.w = f2bf(v0.w);
    c.x = f2bf(v1.x); c.y = f2bf(v1.y); c.z = f2bf(v1.z); c.w = f2bf(v1.w);
    *(ushort4*)(d + i)     = a;
    *(ushort4*)(d + i + 4) = c;
}

// x_proj_w [80][1536] -> padded bf16 [128][1536]
__global__ __launch_bounds__(256) void xproj_pad(const float* __restrict__ src, unsigned short* __restrict__ dst) {
    int row = blockIdx.x;
    for (int c = threadIdx.x; c < D_INNER; c += 256)
        dst[row * D_INNER + c] = (row < 80) ? f2bf(src[row * D_INNER + c]) : (unsigned short)0;
}

// ---------------- LayerNorm -> bf16 ----------------
__global__ __launch_bounds__(256) void ln_kernel(const float* __restrict__ x,
                                                 const float* __restrict__ g,
                                                 const float* __restrict__ b,
                                                 unsigned short* __restrict__ out) {
    __shared__ float sbuf[4];
    int row = blockIdx.x;
    int t = threadIdx.x;
    const float4* xr = (const float4*)(x + (size_t)row * D_MODEL);
    float4 v = xr[t];
    float s = v.x + v.y + v.z + v.w;
    for (int o = 32; o; o >>= 1) s += __shfl_down(s, o, 64);
    if ((t & 63) == 0) sbuf[t >> 6] = s;
    __syncthreads();
    float mu = (sbuf[0] + sbuf[1] + sbuf[2] + sbuf[3]) * (1.0f / D_MODEL);
    __syncthreads();
    float d0 = v.x - mu, d1 = v.y - mu, d2 = v.z - mu, d3 = v.w - mu;
    float q = d0*d0 + d1*d1 + d2*d2 + d3*d3;
    for (int o = 32; o; o >>= 1) q += __shfl_down(q, o, 64);
    if ((t & 63) == 0) sbuf[t >> 6] = q;
    __syncthreads();
    float var = (sbuf[0] + sbuf[1] + sbuf[2] + sbuf[3]) * (1.0f / D_MODEL);
    float rs = rsqrtf(var + 1e-5f);
    float4 gv = ((const float4*)g)[t];
    float4 bv = ((const float4*)b)[t];
    ushort4 st;
    st.x = f2bf(d0 * rs * gv.x + bv.x);
    st.y = f2bf(d1 * rs * gv.y + bv.y);
    st.z = f2bf(d2 * rs * gv.z + bv.z);
    st.w = f2bf(d3 * rs * gv.w + bv.w);
    ((ushort4*)(out + (size_t)row * D_MODEL))[t] = st;
}

// ---------------- bf16 MFMA GEMM (NT): C[m,n] = sum_k A[m,k]*B[n,k] ----------------
// 128x128 tile, BK=32, 4 waves (2x2), 16x16x32 MFMA, global_load_lds staging.
#define EPI_F32        0   // Cf = acc
#define EPI_F32_BF16   1   // Cf = acc, Cb = bf16(acc)
#define EPI_SOFTPLUS   2   // Cf = softplus(acc + bias)
#define EPI_RESID      3   // Cf = acc + resid
#define EPI_GELU_BF16  4   // Cb = bf16(gelu(acc + bias))
#define EPI_BIAS_RESID 5   // Cf = acc + bias + resid

template<int EPI>
__global__ __launch_bounds__(256) void gemm_mfma(
    const unsigned short* __restrict__ A, int lda,
    const unsigned short* __restrict__ B, int ldb, int K,
    float* __restrict__ Cf, unsigned short* __restrict__ Cb, int ldc,
    const float* __restrict__ bias,
    const float* __restrict__ resid, int ldr) {
    __shared__ unsigned short As[128 * 32];
    __shared__ unsigned short Bs[128 * 32];
    int t = threadIdx.x, l = t & 63, w = t >> 6;
    int m0 = blockIdx.y * 128, n0 = blockIdx.x * 128;
    // staging: 8 chunks of 1KB each per tile; wave w stages chunks 2w, 2w+1
    int c0 = 2 * w, c1 = 2 * w + 1;
    int srow = l >> 2, scol = (l & 3) * 8;
    const unsigned short* Ag0 = A + (size_t)(m0 + 16 * c0 + srow) * lda + scol;
    const unsigned short* Ag1 = A + (size_t)(m0 + 16 * c1 + srow) * lda + scol;
    const unsigned short* Bg0 = B + (size_t)(n0 + 16 * c0 + srow) * ldb + scol;
    const unsigned short* Bg1 = B + (size_t)(n0 + 16 * c1 + srow) * ldb + scol;
    unsigned short* Al0 = &As[c0 * 512];
    unsigned short* Al1 = &As[c1 * 512];
    unsigned short* Bl0 = &Bs[c0 * 512];
    unsigned short* Bl1 = &Bs[c1 * 512];
    // compute: wave (wr,wc) owns 64x64 quadrant; 4x4 fragments of 16x16
    int wr = w >> 1, wc = w & 1;
    const unsigned short* ApL = &As[(wr * 64 + (l & 15)) * 32 + (l >> 4) * 8];
    const unsigned short* BpL = &Bs[(wc * 64 + (l & 15)) * 32 + (l >> 4) * 8];

    f32x4 acc[4][4] = {};

    for (int k0 = 0; k0 < K; k0 += 32) {
        gload16(Ag0 + k0, Al0);
        gload16(Ag1 + k0, Al1);
        gload16(Bg0 + k0, Bl0);
        gload16(Bg1 + k0, Bl1);
        __syncthreads();   // drains vmcnt before barrier -> staging visible
        bf16x8 af[4], bfv[4];
        #pragma unroll
        for (int i = 0; i < 4; i++) af[i] = *(const bf16x8*)(ApL + i * 512);
        #pragma unroll
        for (int i = 0; i < 4; i++) bfv[i] = *(const bf16x8*)(BpL + i * 512);
        #pragma unroll
        for (int mi = 0; mi < 4; mi++)
            #pragma unroll
            for (int ni = 0; ni < 4; ni++)
                acc[mi][ni] = __builtin_amdgcn_mfma_f32_16x16x32_bf16(af[mi], bfv[ni], acc[mi][ni], 0, 0, 0);
        __syncthreads();   // compute done before next-iter staging overwrites
    }

    // epilogue: D layout col=lane&15, row=(lane>>4)*4+j  [m89 verified]
    int colb = n0 + wc * 64 + (l & 15);
    int rowb = m0 + wr * 64 + (l >> 4) * 4;
    #pragma unroll
    for (int ni = 0; ni < 4; ni++) {
        int col = colb + ni * 16;
        float bv = 0.0f;
        if (EPI == EPI_SOFTPLUS || EPI == EPI_GELU_BF16 || EPI == EPI_BIAS_RESID) bv = bias[col];
        #pragma unroll
        for (int mi = 0; mi < 4; mi++) {
            #pragma unroll
            for (int j = 0; j < 4; j++) {
                int row = rowb + mi * 16 + j;
                float v = acc[mi][ni][j];
                if (EPI == EPI_SOFTPLUS)        v = softplus_f(v + bv);
                else if (EPI == EPI_GELU_BF16)  v = gelu_f(v + bv);
                else if (EPI == EPI_RESID)      v = v + resid[(size_t)row * ldr + col];
                else if (EPI == EPI_BIAS_RESID) v = v + bv + resid[(size_t)row * ldr + col];
                if (EPI == EPI_GELU_BF16) {
                    Cb[(size_t)row * ldc + col] = f2bf(v);
                } else {
                    Cf[(size_t)row * ldc + col] = v;
                    if (EPI == EPI_F32_BF16) Cb[(size_t)row * ldc + col] = f2bf(v);
                }
            }
        }
    }
}

// ---------------- causal depthwise conv (k=4) + SiLU -> bf16 u ----------------
__global__ __launch_bounds__(256) void conv_silu(const float* __restrict__ xz,
                                                 const float* __restrict__ w,
                                                 const float* __restrict__ cb,
                                                 unsigned short* __restrict__ u) {
    int idx = blockIdx.x * 256 + threadIdx.x;   // (b*L + l)*D_INNER + d
    int d = idx % D_INNER;
    int bl = idx / D_INNER;
    int l = bl % SEQ;
    float s = cb[d];
    #pragma unroll
    for (int k = 0; k < 4; k++) {
        int lp = l - 3 + k;
        if (lp >= 0) s += xz[(size_t)(bl - 3 + k) * (2 * D_INNER) + d] * w[d * 4 + k];
    }
    u[idx] = f2bf(silu_f(s));
}

// ---------------- selective scan: pass A (per-chunk affine) ----------------
__global__ __launch_bounds__(256) void scan_passA(const float* __restrict__ delta,
                                                  const unsigned short* __restrict__ u,
                                                  const float* __restrict__ xdbl,
                                                  const float* __restrict__ A_log,
                                                  float* __restrict__ P,
                                                  float* __restrict__ S) {
    int d = blockIdx.x * 256 + threadIdx.x;
    int c = blockIdx.y, b = blockIdx.z;
    __shared__ float bc[LC][16];
    int base_row = b * SEQ + c * LC;
    for (int e = threadIdx.x; e < LC * 16; e += 256) {
        int lrr = e >> 4, col = e & 15;
        bc[lrr][col] = xdbl[(size_t)(base_row + lrr) * XPAD + DT_RANK + col];
    }
    __syncthreads();
    float Ad[8];
    #pragma unroll
    for (int n = 0; n < 8; n++) Ad[n] = -__expf(A_log[d * 8 + n]);
    float prod[8], hs[8];
    #pragma unroll
    for (int n = 0; n < 8; n++) { prod[n] = 1.0f; hs[n] = 0.0f; }
    for (int lrr = 0; lrr < LC; lrr++) {
        int row = base_row + lrr;
        float dl = delta[(size_t)row * D_INNER + d];
        float uu = bf2f(u[(size_t)row * D_INNER + d]);
        float du = dl * uu;
        #pragma unroll
        for (int n = 0; n < 8; n++) {
            float dA = __expf(dl * Ad[n]);
            prod[n] *= dA;
            hs[n] = dA * hs[n] + du * bc[lrr][n];
        }
    }
    size_t o = ((size_t)((size_t)b * NC + c) * D_INNER + d) * 8;
    #pragma unroll
    for (int n = 0; n < 8; n++) { P[o + n] = prod[n]; S[o + n] = hs[n]; }
}

// ---------------- scan: pass B (combine chunks) ----------------
__global__ __launch_bounds__(256) void scan_passB(const float* __restrict__ P,
                                                  const float* __restrict__ S,
                                                  float* __restrict__ hstart) {
    int tid = blockIdx.x * 256 + threadIdx.x;    // B * D_INNER * 8 = 24576
    int b = tid / (D_INNER * 8);
    int rem = tid % (D_INNER * 8);
    float h = 0.0f;
    for (int c = 0; c < NC; c++) {
        size_t o = (size_t)(b * NC + c) * (D_INNER * 8) + rem;
        hstart[o] = h;
        h = P[o] * h + S[o];
    }
}

// ---------------- scan: pass C (final y + gate) -> bf16 ygate ----------------
__global__ __launch_bounds__(256) void scan_passC(const float* __restrict__ delta,
                                                  const unsigned short* __restrict__ u,
                                                  const float* __restrict__ xdbl,
                                                  const float* __restrict__ A_log,
                                                  const float* __restrict__ hstart,
                                                  const float* __restrict__ xz,
                                                  const float* __restrict__ Dp,
                                                  unsigned short* __restrict__ ygate) {
    int d = blockIdx.x * 256 + threadIdx.x;
    int c = blockIdx.y, b = blockIdx.z;
    __shared__ float bc[LC][16];
    int base_row = b * SEQ + c * LC;
    for (int e = threadIdx.x; e < LC * 16; e += 256) {
        int lrr = e >> 4, col = e & 15;
        bc[lrr][col] = xdbl[(size_t)(base_row + lrr) * XPAD + DT_RANK + col];
    }
    __syncthreads();
    float Ad[8];
    #pragma unroll
    for (int n = 0; n < 8; n++) Ad[n] = -__expf(A_log[d * 8 + n]);
    float h[8];
    size_t ho = ((size_t)((size_t)b * NC + c) * D_INNER + d) * 8;
    #pragma unroll
    for (int n = 0; n < 8; n++) h[n] = hstart[ho + n];
    float Dd = Dp[d];
    for (int lrr = 0; lrr < LC; lrr++) {
        int row = base_row + lrr;
        float dl = delta[(size_t)row * D_INNER + d];
        float uu = bf2f(u[(size_t)row * D_INNER + d]);
        float du = dl * uu;
        float y = 0.0f;
        #pragma unroll
        for (int n = 0; n < 8; n++) {
            float dA = __expf(dl * Ad[n]);
            h[n] = dA * h[n] + du * bc[lrr][n];
            y += h[n] * bc[lrr][8 + n];
        }
        y += uu * Dd;
        float z = xz[(size_t)row * (2 * D_INNER) + D_INNER + d];
        ygate[(size_t)row * D_INNER + d] = f2bf(y * silu_f(z));
    }
}

// ---------------- launch ----------------
extern "C" void kernel_launch(void* const* d_in, const int* in_sizes, int n_in,
                              void* d_out, int out_size, void* d_ws, size_t ws_size,
                              hipStream_t stream) {
    const float* x         = (const float*)d_in[0];
    const float* ln1_g     = (const float*)d_in[1];
    const float* ln1_b     = (const float*)d_in[2];
    const float* ln2_g     = (const float*)d_in[3];
    const float* ln2_b     = (const float*)d_in[4];
    const float* in_proj_w = (const float*)d_in[5];
    const float* conv_w    = (const float*)d_in[6];
    const float* conv_b    = (const float*)d_in[7];
    const float* x_proj_w  = (const float*)d_in[8];
    const float* dt_proj_w = (const float*)d_in[9];
    const float* dt_proj_b = (const float*)d_in[10];
    const float* A_log     = (const float*)d_in[11];
    const float* Dp        = (const float*)d_in[12];
    const float* out_proj_w= (const float*)d_in[13];
    const float* ffn_w1    = (const float*)d_in[14];
    const float* ffn_b1    = (const float*)d_in[15];
    const float* ffn_w2    = (const float*)d_in[16];
    const float* ffn_b2    = (const float*)d_in[17];
    float* out = (float*)d_out;

    // ---- workspace layout ----
    float* xz    = (float*)d_ws;                           // 4096*3072 f32 (z-gate + conv src; later hff_bf overlay)
    float* xdbl  = xz + (size_t)NROWS * 2 * D_INNER;       // 4096*128 f32
    float* delta = xdbl + (size_t)NROWS * XPAD;            // 4096*1536 f32
    float* P     = delta + (size_t)NROWS * D_INNER;        // 2*32*1536*8
    float* S     = P + (size_t)BATCH * NC * D_INNER * 8;
    float* hst   = S + (size_t)BATCH * NC * D_INNER * 8;
    float* x2    = hst + (size_t)BATCH * NC * D_INNER * 8; // 4096*1024 f32
    unsigned short* xp_bf   = (unsigned short*)(x2 + (size_t)NROWS * D_MODEL); // 4096*1024 (reused as xn_bf)
    unsigned short* u_bf    = xp_bf + (size_t)NROWS * D_MODEL;                 // 4096*1536
    unsigned short* xdbl_bf = u_bf + (size_t)NROWS * D_INNER;                  // 4096*128
    unsigned short* yg_bf   = xdbl_bf + (size_t)NROWS * XPAD;                  // 4096*1536
    unsigned short* w_in    = yg_bf + (size_t)NROWS * D_INNER;                 // 3072*1024
    unsigned short* w_xp    = w_in + (size_t)2 * D_INNER * D_MODEL;            // 128*1536 (padded)
    unsigned short* w_dt    = w_xp + (size_t)XPAD * D_INNER;                   // 1536*64
    unsigned short* w_out   = w_dt + (size_t)D_INNER * DT_RANK;                // 1024*1536
    unsigned short* w_f1    = w_out + (size_t)D_MODEL * D_INNER;               // 2048*1024
    unsigned short* w_f2    = w_f1 + (size_t)D_FF * D_MODEL;                   // 1024*2048
    unsigned short* hff_bf  = (unsigned short*)xz;   // overlay: xz dead after scan_passC

    // 0. weight conversions
    wconv<<<4400, 256, 0, stream>>>(in_proj_w, w_in, dt_proj_w, w_dt, out_proj_w, w_out,
                                    ffn_w1, w_f1, ffn_w2, w_f2);
    xproj_pad<<<XPAD, 256, 0, stream>>>(x_proj_w, w_xp);
    // 1. LN1 -> bf16
    ln_kernel<<<NROWS, 256, 0, stream>>>(x, ln1_g, ln1_b, xp_bf);
    // 2. in_proj: xz = xp @ in_proj_w^T  (4096 x 3072, K=1024)
    gemm_mfma<EPI_F32><<<dim3(3072 / 128, NROWS / 128), 256, 0, stream>>>(
        xp_bf, D_MODEL, w_in, D_MODEL, D_MODEL, xz, nullptr, 2 * D_INNER, nullptr, nullptr, 0);
    // 3. conv + silu -> u (bf16)
    conv_silu<<<(NROWS * D_INNER) / 256, 256, 0, stream>>>(xz, conv_w, conv_b, u_bf);
    // 4. x_proj: xdbl = u @ x_proj_w^T  (4096 x 128pad, K=1536) -> f32 + bf16
    gemm_mfma<EPI_F32_BF16><<<dim3(1, NROWS / 128), 256, 0, stream>>>(
        u_bf, D_INNER, w_xp, D_INNER, D_INNER, xdbl, xdbl_bf, XPAD, nullptr, nullptr, 0);
    // 5. dt_proj + softplus: delta (4096 x 1536, K=64)
    gemm_mfma<EPI_SOFTPLUS><<<dim3(D_INNER / 128, NROWS / 128), 256, 0, stream>>>(
        xdbl_bf, XPAD, w_dt, DT_RANK, DT_RANK, delta, nullptr, D_INNER, dt_proj_b, nullptr, 0);
    // 6-8. selective scan
    scan_passA<<<dim3(D_INNER / 256, NC, BATCH), 256, 0, stream>>>(delta, u_bf, xdbl, A_log, P, S);
    scan_passB<<<(BATCH * D_INNER * 8) / 256, 256, 0, stream>>>(P, S, hst);
    scan_passC<<<dim3(D_INNER / 256, NC, BATCH), 256, 0, stream>>>(delta, u_bf, xdbl, A_log, hst, xz, Dp, yg_bf);
    // 9. out_proj + residual: x2 = ygate @ out_proj_w^T + x  (4096 x 1024, K=1536)
    gemm_mfma<EPI_RESID><<<dim3(D_MODEL / 128, NROWS / 128), 256, 0, stream>>>(
        yg_bf, D_INNER, w_out, D_INNER, D_INNER, x2, nullptr, D_MODEL, nullptr, x, D_MODEL);
    // 10. LN2 -> bf16 (reuse xp_bf)
    ln_kernel<<<NROWS, 256, 0, stream>>>(x2, ln2_g, ln2_b, xp_bf);
    // 11. ffn1 + gelu -> bf16 hff  (4096 x 2048, K=1024)
    gemm_mfma<EPI_GELU_BF16><<<dim3(D_FF / 128, NROWS / 128), 256, 0, stream>>>(
        xp_bf, D_MODEL, w_f1, D_MODEL, D_MODEL, nullptr, hff_bf, D_FF, ffn_b1, nullptr, 0);
    // 12. ffn2 + bias + residual: out = x2 + hff @ ffn_w2^T + b2  (4096 x 1024, K=2048)
    gemm_mfma<EPI_BIAS_RESID><<<dim3(D_MODEL / 128, NROWS / 128), 256, 0, stream>>>(
        hff_bf, D_FF, w_f2, D_FF, D_FF, out, nullptr, D_MODEL, ffn_b2, x2, D_MODEL);
}

// Round 4
// 333.232 us; speedup vs baseline: 3.7792x; 1.0951x over previous
//
#include <hip/hip_runtime.h>
#include <math.h>

#define D_MODEL 1024
#define D_STATE 8
#define D_CONV  4
#define D_INNER 1536
#define DT_RANK 64
#define D_FF    2048
#define BATCH   2
#define SEQ     2048
#define NROWS   (BATCH*SEQ)      // 4096
#define NC      32               // scan chunks
#define LC      (SEQ/NC)         // 64
#define XPAD    128              // padded x_dbl width (was 80)

typedef short bf16x8 __attribute__((ext_vector_type(8)));
typedef unsigned short u16x8 __attribute__((ext_vector_type(8)));
typedef float f32x4  __attribute__((ext_vector_type(4)));

__device__ inline unsigned short f2bf(float x) {
    union { float f; unsigned u; } v; v.f = x;
    unsigned r = v.u + 0x7fffu + ((v.u >> 16) & 1u);
    return (unsigned short)(r >> 16);
}
__device__ inline float bf2f(unsigned short h) {
    union { unsigned u; float f; } v; v.u = ((unsigned)h) << 16;
    return v.f;
}
__device__ inline float softplus_f(float x) {
    return (x > 20.0f) ? x : log1pf(__expf(x));
}
__device__ inline float gelu_f(float x) {
    return 0.5f * x * (1.0f + erff(x * 0.70710678118654752f));
}
__device__ inline float silu_f(float x) {
    return x / (1.0f + __expf(-x));
}
__device__ inline void gload16(const unsigned short* g, unsigned short* l) {
    typedef unsigned int u32;
    __builtin_amdgcn_global_load_lds(
        (const __attribute__((address_space(1))) u32*)g,
        (__attribute__((address_space(3))) u32*)l, 16, 0, 0);
}

// ---------------- weight f32 -> bf16 conversion (fused 5 segments) ----------------
__global__ __launch_bounds__(256) void wconv(const float* __restrict__ s0, unsigned short* __restrict__ d0,
                                             const float* __restrict__ s1, unsigned short* __restrict__ d1,
                                             const float* __restrict__ s2, unsigned short* __restrict__ d2,
                                             const float* __restrict__ s3, unsigned short* __restrict__ d3,
                                             const float* __restrict__ s4, unsigned short* __restrict__ d4) {
    int b = blockIdx.x;
    const float* s; unsigned short* d; int base;
    if      (b < 1536) { s = s0; d = d0; base = b * 2048; }
    else if (b < 1584) { s = s1; d = d1; base = (b - 1536) * 2048; }
    else if (b < 2352) { s = s2; d = d2; base = (b - 1584) * 2048; }
    else if (b < 3376) { s = s3; d = d3; base = (b - 2352) * 2048; }
    else               { s = s4; d = d4; base = (b - 3376) * 2048; }
    int i = base + threadIdx.x * 8;
    float4 v0 = *(const float4*)(s + i);
    float4 v1 = *(const float4*)(s + i + 4);
    ushort4 a, c;
    a.x = f2bf(v0.x); a.y = f2bf(v0.y); a.z = f2bf(v0.z); a.w = f2bf(v0.w);
    c.x = f2bf(v1.x); c.y = f2bf(v1.y); c.z = f2bf(v1.z); c.w = f2bf(v1.w);
    *(ushort4*)(d + i)     = a;
    *(ushort4*)(d + i + 4) = c;
}

// x_proj_w [80][1536] -> padded bf16 [128][1536]
__global__ __launch_bounds__(256) void xproj_pad(const float* __restrict__ src, unsigned short* __restrict__ dst) {
    int row = blockIdx.x;
    for (int c = threadIdx.x; c < D_INNER; c += 256)
        dst[row * D_INNER + c] = (row < 80) ? f2bf(src[row * D_INNER + c]) : (unsigned short)0;
}

// ---------------- LayerNorm -> bf16 ----------------
__global__ __launch_bounds__(256) void ln_kernel(const float* __restrict__ x,
                                                 const float* __restrict__ g,
                                                 const float* __restrict__ b,
                                                 unsigned short* __restrict__ out) {
    __shared__ float sbuf[4];
    int row = blockIdx.x;
    int t = threadIdx.x;
    const float4* xr = (const float4*)(x + (size_t)row * D_MODEL);
    float4 v = xr[t];
    float s = v.x + v.y + v.z + v.w;
    for (int o = 32; o; o >>= 1) s += __shfl_down(s, o, 64);
    if ((t & 63) == 0) sbuf[t >> 6] = s;
    __syncthreads();
    float mu = (sbuf[0] + sbuf[1] + sbuf[2] + sbuf[3]) * (1.0f / D_MODEL);
    __syncthreads();
    float d0 = v.x - mu, d1 = v.y - mu, d2 = v.z - mu, d3 = v.w - mu;
    float q = d0*d0 + d1*d1 + d2*d2 + d3*d3;
    for (int o = 32; o; o >>= 1) q += __shfl_down(q, o, 64);
    if ((t & 63) == 0) sbuf[t >> 6] = q;
    __syncthreads();
    float var = (sbuf[0] + sbuf[1] + sbuf[2] + sbuf[3]) * (1.0f / D_MODEL);
    float rs = rsqrtf(var + 1e-5f);
    float4 gv = ((const float4*)g)[t];
    float4 bv = ((const float4*)b)[t];
    ushort4 st;
    st.x = f2bf(d0 * rs * gv.x + bv.x);
    st.y = f2bf(d1 * rs * gv.y + bv.y);
    st.z = f2bf(d2 * rs * gv.z + bv.z);
    st.w = f2bf(d3 * rs * gv.w + bv.w);
    ((ushort4*)(out + (size_t)row * D_MODEL))[t] = st;
}

// ---------------- bf16 MFMA GEMM (NT), double-buffered prefetch ----------------
// 128x128 tile, BK=32, 4 waves (2x2), 16x16x32 MFMA, global_load_lds staging,
// XCD-aware bijective block swizzle (grid blocks % 8 == 0 required).
#define EPI_F32        0   // Cf = acc
#define EPI_F32_BF16   1   // Cf = acc, Cb = bf16(acc)
#define EPI_SOFTPLUS   2   // Cf = softplus(acc + bias)
#define EPI_RESID      3   // Cf = acc + resid
#define EPI_GELU_BF16  4   // Cb = bf16(gelu(acc + bias))
#define EPI_BIAS_RESID 5   // Cf = acc + bias + resid
#define EPI_BF16       6   // Cb = bf16(acc)

template<int EPI>
__global__ __launch_bounds__(256) void gemm_mfma(
    const unsigned short* __restrict__ A, int lda,
    const unsigned short* __restrict__ B, int ldb, int K,
    float* __restrict__ Cf, unsigned short* __restrict__ Cb, int ldc,
    const float* __restrict__ bias,
    const float* __restrict__ resid, int ldr) {
    __shared__ unsigned short As[2][128 * 32];
    __shared__ unsigned short Bs[2][128 * 32];
    int t = threadIdx.x, l = t & 63, w = t >> 6;
    // XCD-aware bijective swizzle: 8 XCDs get contiguous chunks of the grid
    int nx = gridDim.x;
    int nwg = nx * gridDim.y;
    int bid = blockIdx.y * nx + blockIdx.x;
    int q = nwg >> 3;
    int swz = (bid & 7) * q + (bid >> 3);
    int m0 = (swz / nx) * 128, n0 = (swz % nx) * 128;
    // staging: 8 chunks of 16 rows x 32 cols per operand; wave w stages chunks 2w, 2w+1
    int c0 = 2 * w, c1 = 2 * w + 1;
    int srow = l >> 2, scol = (l & 3) * 8;
    const unsigned short* Ag0 = A + (size_t)(m0 + 16 * c0 + srow) * lda + scol;
    const unsigned short* Ag1 = A + (size_t)(m0 + 16 * c1 + srow) * lda + scol;
    const unsigned short* Bg0 = B + (size_t)(n0 + 16 * c0 + srow) * ldb + scol;
    const unsigned short* Bg1 = B + (size_t)(n0 + 16 * c1 + srow) * ldb + scol;
    // compute: wave (wr,wc) owns 64x64 quadrant; 4x4 fragments of 16x16
    int wr = w >> 1, wc = w & 1;
    int aoff = (wr * 64 + (l & 15)) * 32 + (l >> 4) * 8;
    int boff = (wc * 64 + (l & 15)) * 32 + (l >> 4) * 8;

    f32x4 acc[4][4] = {};
    int nt = K >> 5;

    // prologue: stage tile 0 into buf 0
    gload16(Ag0, &As[0][c0 * 512]);
    gload16(Ag1, &As[0][c1 * 512]);
    gload16(Bg0, &Bs[0][c0 * 512]);
    gload16(Bg1, &Bs[0][c1 * 512]);
    __syncthreads();   // vmcnt(0) drain + barrier

    int cur = 0;
    for (int ti = 0; ti < nt; ti++) {
        if (ti + 1 < nt) {            // issue next-tile loads into other buffer
            int k0 = (ti + 1) << 5;
            int nb = cur ^ 1;
            gload16(Ag0 + k0, &As[nb][c0 * 512]);
            gload16(Ag1 + k0, &As[nb][c1 * 512]);
            gload16(Bg0 + k0, &Bs[nb][c0 * 512]);
            gload16(Bg1 + k0, &Bs[nb][c1 * 512]);
        }
        bf16x8 af[4], bfv[4];
        #pragma unroll
        for (int i = 0; i < 4; i++) af[i] = *(const bf16x8*)(&As[cur][aoff + i * 512]);
        #pragma unroll
        for (int i = 0; i < 4; i++) bfv[i] = *(const bf16x8*)(&Bs[cur][boff + i * 512]);
        #pragma unroll
        for (int mi = 0; mi < 4; mi++)
            #pragma unroll
            for (int ni = 0; ni < 4; ni++)
                acc[mi][ni] = __builtin_amdgcn_mfma_f32_16x16x32_bf16(af[mi], bfv[ni], acc[mi][ni], 0, 0, 0);
        __syncthreads();   // drains vmcnt (next tile landed) + protects cur buf
        cur ^= 1;
    }

    // epilogue: D layout col=lane&15, row=(lane>>4)*4+j  [m89 verified]
    int colb = n0 + wc * 64 + (l & 15);
    int rowb = m0 + wr * 64 + (l >> 4) * 4;
    #pragma unroll
    for (int ni = 0; ni < 4; ni++) {
        int col = colb + ni * 16;
        float bv = 0.0f;
        if (EPI == EPI_SOFTPLUS || EPI == EPI_GELU_BF16 || EPI == EPI_BIAS_RESID) bv = bias[col];
        #pragma unroll
        for (int mi = 0; mi < 4; mi++) {
            #pragma unroll
            for (int j = 0; j < 4; j++) {
                int row = rowb + mi * 16 + j;
                float v = acc[mi][ni][j];
                if (EPI == EPI_SOFTPLUS)        v = softplus_f(v + bv);
                else if (EPI == EPI_GELU_BF16)  v = gelu_f(v + bv);
                else if (EPI == EPI_RESID)      v = v + resid[(size_t)row * ldr + col];
                else if (EPI == EPI_BIAS_RESID) v = v + bv + resid[(size_t)row * ldr + col];
                if (EPI == EPI_GELU_BF16 || EPI == EPI_BF16) {
                    Cb[(size_t)row * ldc + col] = f2bf(v);
                } else {
                    Cf[(size_t)row * ldc + col] = v;
                    if (EPI == EPI_F32_BF16) Cb[(size_t)row * ldc + col] = f2bf(v);
                }
            }
        }
    }
}

// ---------------- causal depthwise conv (k=4) + SiLU -> bf16 u (8-wide) ----------------
__global__ __launch_bounds__(256) void conv_silu(const unsigned short* __restrict__ xz,
                                                 const float* __restrict__ w,
                                                 const float* __restrict__ cb,
                                                 unsigned short* __restrict__ u) {
    int idx = (blockIdx.x * 256 + threadIdx.x) * 8;   // (b*L + l)*D_INNER + d, d%8==0
    int d = idx % D_INNER;
    int bl = idx / D_INNER;
    int l = bl & (SEQ - 1);
    float acc[8];
    float4 wv[8];
    #pragma unroll
    for (int j = 0; j < 8; j++) wv[j] = *(const float4*)(w + (d + j) * 4);
    float4 cb0 = *(const float4*)(cb + d);
    float4 cb1 = *(const float4*)(cb + d + 4);
    acc[0] = cb0.x; acc[1] = cb0.y; acc[2] = cb0.z; acc[3] = cb0.w;
    acc[4] = cb1.x; acc[5] = cb1.y; acc[6] = cb1.z; acc[7] = cb1.w;
    #pragma unroll
    for (int k = 0; k < 4; k++) {
        int lp = l - 3 + k;
        if (lp >= 0) {
            u16x8 s = *(const u16x8*)(xz + (size_t)(bl - 3 + k) * (2 * D_INNER) + d);
            #pragma unroll
            for (int j = 0; j < 8; j++) {
                float wk = (k == 0) ? wv[j].x : (k == 1) ? wv[j].y : (k == 2) ? wv[j].z : wv[j].w;
                acc[j] += bf2f((unsigned short)s[j]) * wk;
            }
        }
    }
    u16x8 o;
    #pragma unroll
    for (int j = 0; j < 8; j++) o[j] = f2bf(silu_f(acc[j]));
    *(u16x8*)(u + idx) = o;
}

// ---------------- selective scan: pass A (per-chunk affine) ----------------
__global__ __launch_bounds__(256) void scan_passA(const float* __restrict__ delta,
                                                  const unsigned short* __restrict__ u,
                                                  const float* __restrict__ xdbl,
                                                  const float* __restrict__ A_log,
                                                  float* __restrict__ P,
                                                  float* __restrict__ S) {
    int d = blockIdx.x * 256 + threadIdx.x;
    int c = blockIdx.y, b = blockIdx.z;
    __shared__ float bc[LC][16];
    int base_row = b * SEQ + c * LC;
    for (int e = threadIdx.x; e < LC * 16; e += 256) {
        int lrr = e >> 4, col = e & 15;
        bc[lrr][col] = xdbl[(size_t)(base_row + lrr) * XPAD + DT_RANK + col];
    }
    __syncthreads();
    float Ad[8];
    #pragma unroll
    for (int n = 0; n < 8; n++) Ad[n] = -__expf(A_log[d * 8 + n]);
    float prod[8], hs[8];
    #pragma unroll
    for (int n = 0; n < 8; n++) { prod[n] = 1.0f; hs[n] = 0.0f; }
    for (int lrr = 0; lrr < LC; lrr++) {
        int row = base_row + lrr;
        float dl = delta[(size_t)row * D_INNER + d];
        float uu = bf2f(u[(size_t)row * D_INNER + d]);
        float du = dl * uu;
        #pragma unroll
        for (int n = 0; n < 8; n++) {
            float dA = __expf(dl * Ad[n]);
            prod[n] *= dA;
            hs[n] = dA * hs[n] + du * bc[lrr][n];
        }
    }
    size_t o = ((size_t)((size_t)b * NC + c) * D_INNER + d) * 8;
    #pragma unroll
    for (int n = 0; n < 8; n++) { P[o + n] = prod[n]; S[o + n] = hs[n]; }
}

// ---------------- scan: pass B (combine chunks) ----------------
__global__ __launch_bounds__(256) void scan_passB(const float* __restrict__ P,
                                                  const float* __restrict__ S,
                                                  float* __restrict__ hstart) {
    int tid = blockIdx.x * 256 + threadIdx.x;    // B * D_INNER * 8 = 24576
    int b = tid / (D_INNER * 8);
    int rem = tid % (D_INNER * 8);
    float h = 0.0f;
    for (int c = 0; c < NC; c++) {
        size_t o = (size_t)(b * NC + c) * (D_INNER * 8) + rem;
        hstart[o] = h;
        h = P[o] * h + S[o];
    }
}

// ---------------- scan: pass C (final y + gate) -> bf16 ygate ----------------
__global__ __launch_bounds__(256) void scan_passC(const float* __restrict__ delta,
                                                  const unsigned short* __restrict__ u,
                                                  const float* __restrict__ xdbl,
                                                  const float* __restrict__ A_log,
                                                  const float* __restrict__ hstart,
                                                  const unsigned short* __restrict__ xz,
                                                  const float* __restrict__ Dp,
                                                  unsigned short* __restrict__ ygate) {
    int d = blockIdx.x * 256 + threadIdx.x;
    int c = blockIdx.y, b = blockIdx.z;
    __shared__ float bc[LC][16];
    int base_row = b * SEQ + c * LC;
    for (int e = threadIdx.x; e < LC * 16; e += 256) {
        int lrr = e >> 4, col = e & 15;
        bc[lrr][col] = xdbl[(size_t)(base_row + lrr) * XPAD + DT_RANK + col];
    }
    __syncthreads();
    float Ad[8];
    #pragma unroll
    for (int n = 0; n < 8; n++) Ad[n] = -__expf(A_log[d * 8 + n]);
    float h[8];
    size_t ho = ((size_t)((size_t)b * NC + c) * D_INNER + d) * 8;
    #pragma unroll
    for (int n = 0; n < 8; n++) h[n] = hstart[ho + n];
    float Dd = Dp[d];
    for (int lrr = 0; lrr < LC; lrr++) {
        int row = base_row + lrr;
        float dl = delta[(size_t)row * D_INNER + d];
        float uu = bf2f(u[(size_t)row * D_INNER + d]);
        float du = dl * uu;
        float y = 0.0f;
        #pragma unroll
        for (int n = 0; n < 8; n++) {
            float dA = __expf(dl * Ad[n]);
            h[n] = dA * h[n] + du * bc[lrr][n];
            y += h[n] * bc[lrr][8 + n];
        }
        y += uu * Dd;
        float z = bf2f(xz[(size_t)row * (2 * D_INNER) + D_INNER + d]);
        ygate[(size_t)row * D_INNER + d] = f2bf(y * silu_f(z));
    }
}

// ---------------- launch ----------------
extern "C" void kernel_launch(void* const* d_in, const int* in_sizes, int n_in,
                              void* d_out, int out_size, void* d_ws, size_t ws_size,
                              hipStream_t stream) {
    const float* x         = (const float*)d_in[0];
    const float* ln1_g     = (const float*)d_in[1];
    const float* ln1_b     = (const float*)d_in[2];
    const float* ln2_g     = (const float*)d_in[3];
    const float* ln2_b     = (const float*)d_in[4];
    const float* in_proj_w = (const float*)d_in[5];
    const float* conv_w    = (const float*)d_in[6];
    const float* conv_b    = (const float*)d_in[7];
    const float* x_proj_w  = (const float*)d_in[8];
    const float* dt_proj_w = (const float*)d_in[9];
    const float* dt_proj_b = (const float*)d_in[10];
    const float* A_log     = (const float*)d_in[11];
    const float* Dp        = (const float*)d_in[12];
    const float* out_proj_w= (const float*)d_in[13];
    const float* ffn_w1    = (const float*)d_in[14];
    const float* ffn_b1    = (const float*)d_in[15];
    const float* ffn_w2    = (const float*)d_in[16];
    const float* ffn_b2    = (const float*)d_in[17];
    float* out = (float*)d_out;

    // ---- workspace layout ----
    float* xdbl  = (float*)d_ws;                           // 4096*128 f32
    float* delta = xdbl + (size_t)NROWS * XPAD;            // 4096*1536 f32
    float* P     = delta + (size_t)NROWS * D_INNER;        // 2*32*1536*8
    float* S     = P + (size_t)BATCH * NC * D_INNER * 8;
    float* hst   = S + (size_t)BATCH * NC * D_INNER * 8;
    float* x2    = hst + (size_t)BATCH * NC * D_INNER * 8; // 4096*1024 f32
    unsigned short* xz_bf   = (unsigned short*)(x2 + (size_t)NROWS * D_MODEL); // 4096*3072 bf16 (later hff overlay)
    unsigned short* xp_bf   = xz_bf + (size_t)NROWS * 2 * D_INNER;             // 4096*1024 (reused as xn_bf)
    unsigned short* u_bf    = xp_bf + (size_t)NROWS * D_MODEL;                 // 4096*1536
    unsigned short* xdbl_bf = u_bf + (size_t)NROWS * D_INNER;                  // 4096*128
    unsigned short* yg_bf   = xdbl_bf + (size_t)NROWS * XPAD;                  // 4096*1536
    unsigned short* w_in    = yg_bf + (size_t)NROWS * D_INNER;                 // 3072*1024
    unsigned short* w_xp    = w_in + (size_t)2 * D_INNER * D_MODEL;            // 128*1536 (padded)
    unsigned short* w_dt    = w_xp + (size_t)XPAD * D_INNER;                   // 1536*64
    unsigned short* w_out   = w_dt + (size_t)D_INNER * DT_RANK;                // 1024*1536
    unsigned short* w_f1    = w_out + (size_t)D_MODEL * D_INNER;               // 2048*1024
    unsigned short* w_f2    = w_f1 + (size_t)D_FF * D_MODEL;                   // 1024*2048
    unsigned short* hff_bf  = xz_bf;   // overlay: xz dead after scan_passC

    // 0. weight conversions
    wconv<<<4400, 256, 0, stream>>>(in_proj_w, w_in, dt_proj_w, w_dt, out_proj_w, w_out,
                                    ffn_w1, w_f1, ffn_w2, w_f2);
    xproj_pad<<<XPAD, 256, 0, stream>>>(x_proj_w, w_xp);
    // 1. LN1 -> bf16
    ln_kernel<<<NROWS, 256, 0, stream>>>(x, ln1_g, ln1_b, xp_bf);
    // 2. in_proj: xz = xp @ in_proj_w^T  (4096 x 3072, K=1024) -> bf16
    gemm_mfma<EPI_BF16><<<dim3(3072 / 128, NROWS / 128), 256, 0, stream>>>(
        xp_bf, D_MODEL, w_in, D_MODEL, D_MODEL, nullptr, xz_bf, 2 * D_INNER, nullptr, nullptr, 0);
    // 3. conv + silu -> u (bf16)
    conv_silu<<<(NROWS * D_INNER) / (256 * 8), 256, 0, stream>>>(xz_bf, conv_w, conv_b, u_bf);
    // 4. x_proj: xdbl = u @ x_proj_w^T  (4096 x 128pad, K=1536) -> f32 + bf16
    gemm_mfma<EPI_F32_BF16><<<dim3(1, NROWS / 128), 256, 0, stream>>>(
        u_bf, D_INNER, w_xp, D_INNER, D_INNER, xdbl, xdbl_bf, XPAD, nullptr, nullptr, 0);
    // 5. dt_proj + softplus: delta (4096 x 1536, K=64)
    gemm_mfma<EPI_SOFTPLUS><<<dim3(D_INNER / 128, NROWS / 128), 256, 0, stream>>>(
        xdbl_bf, XPAD, w_dt, DT_RANK, DT_RANK, delta, nullptr, D_INNER, dt_proj_b, nullptr, 0);
    // 6-8. selective scan
    scan_passA<<<dim3(D_INNER / 256, NC, BATCH), 256, 0, stream>>>(delta, u_bf, xdbl, A_log, P, S);
    scan_passB<<<(BATCH * D_INNER * 8) / 256, 256, 0, stream>>>(P, S, hst);
    scan_passC<<<dim3(D_INNER / 256, NC, BATCH), 256, 0, stream>>>(delta, u_bf, xdbl, A_log, hst, xz_bf, Dp, yg_bf);
    // 9. out_proj + residual: x2 = ygate @ out_proj_w^T + x  (4096 x 1024, K=1536)
    gemm_mfma<EPI_RESID><<<dim3(D_MODEL / 128, NROWS / 128), 256, 0, stream>>>(
        yg_bf, D_INNER, w_out, D_INNER, D_INNER, x2, nullptr, D_MODEL, nullptr, x, D_MODEL);
    // 10. LN2 -> bf16 (reuse xp_bf)
    ln_kernel<<<NROWS, 256, 0, stream>>>(x2, ln2_g, ln2_b, xp_bf);
    // 11. ffn1 + gelu -> bf16 hff  (4096 x 2048, K=1024)
    gemm_mfma<EPI_GELU_BF16><<<dim3(D_FF / 128, NROWS / 128), 256, 0, stream>>>(
        xp_bf, D_MODEL, w_f1, D_MODEL, D_MODEL, nullptr, hff_bf, D_FF, ffn_b1, nullptr, 0);
    // 12. ffn2 + bias + residual: out = x2 + hff @ ffn_w2^T + b2  (4096 x 1024, K=2048)
    gemm_mfma<EPI_BIAS_RESID><<<dim3(D_MODEL / 128, NROWS / 128), 256, 0, stream>>>(
        hff_bf, D_FF, w_f2, D_FF, D_FF, out, nullptr, D_MODEL, ffn_b2, x2, D_MODEL);
}

// Round 5
// 313.330 us; speedup vs baseline: 4.0192x; 1.0635x over previous
//
#include <hip/hip_runtime.h>
#include <math.h>

#define D_MODEL 1024
#define D_STATE 8
#define D_CONV  4
#define D_INNER 1536
#define DT_RANK 64
#define D_FF    2048
#define BATCH   2
#define SEQ     2048
#define NROWS   (BATCH*SEQ)      // 4096
#define NC      32               // scan chunks
#define LC      (SEQ/NC)         // 64
#define XPAD    128              // padded x_dbl width (was 80)

typedef short bf16x8 __attribute__((ext_vector_type(8)));
typedef unsigned short u16x8 __attribute__((ext_vector_type(8)));
typedef float f32x4  __attribute__((ext_vector_type(4)));

__device__ inline unsigned short f2bf(float x) {
    union { float f; unsigned u; } v; v.f = x;
    unsigned r = v.u + 0x7fffu + ((v.u >> 16) & 1u);
    return (unsigned short)(r >> 16);
}
__device__ inline float bf2f(unsigned short h) {
    union { unsigned u; float f; } v; v.u = ((unsigned)h) << 16;
    return v.f;
}
__device__ inline float softplus_f(float x) {
    return (x > 20.0f) ? x : log1pf(__expf(x));
}
__device__ inline float gelu_f(float x) {
    return 0.5f * x * (1.0f + erff(x * 0.70710678118654752f));
}
__device__ inline float silu_f(float x) {
    return x / (1.0f + __expf(-x));
}
__device__ inline void gload16(const unsigned short* g, unsigned short* l) {
    typedef unsigned int u32;
    __builtin_amdgcn_global_load_lds(
        (const __attribute__((address_space(1))) u32*)g,
        (__attribute__((address_space(3))) u32*)l, 16, 0, 0);
}

// ---------------- weight f32 -> bf16 conversion (fused 5 segments) ----------------
__global__ __launch_bounds__(256) void wconv(const float* __restrict__ s0, unsigned short* __restrict__ d0,
                                             const float* __restrict__ s1, unsigned short* __restrict__ d1,
                                             const float* __restrict__ s2, unsigned short* __restrict__ d2,
                                             const float* __restrict__ s3, unsigned short* __restrict__ d3,
                                             const float* __restrict__ s4, unsigned short* __restrict__ d4) {
    int b = blockIdx.x;
    const float* s; unsigned short* d; int base;
    if      (b < 1536) { s = s0; d = d0; base = b * 2048; }
    else if (b < 1584) { s = s1; d = d1; base = (b - 1536) * 2048; }
    else if (b < 2352) { s = s2; d = d2; base = (b - 1584) * 2048; }
    else if (b < 3376) { s = s3; d = d3; base = (b - 2352) * 2048; }
    else               { s = s4; d = d4; base = (b - 3376) * 2048; }
    int i = base + threadIdx.x * 8;
    float4 v0 = *(const float4*)(s + i);
    float4 v1 = *(const float4*)(s + i + 4);
    ushort4 a, c;
    a.x = f2bf(v0.x); a.y = f2bf(v0.y); a.z = f2bf(v0.z); a.w = f2bf(v0.w);
    c.x = f2bf(v1.x); c.y = f2bf(v1.y); c.z = f2bf(v1.z); c.w = f2bf(v1.w);
    *(ushort4*)(d + i)     = a;
    *(ushort4*)(d + i + 4) = c;
}

// x_proj_w [80][1536] -> padded bf16 [128][1536]
__global__ __launch_bounds__(256) void xproj_pad(const float* __restrict__ src, unsigned short* __restrict__ dst) {
    int row = blockIdx.x;
    for (int c = threadIdx.x; c < D_INNER; c += 256)
        dst[row * D_INNER + c] = (row < 80) ? f2bf(src[row * D_INNER + c]) : (unsigned short)0;
}

// ---------------- LayerNorm -> bf16 ----------------
__global__ __launch_bounds__(256) void ln_kernel(const float* __restrict__ x,
                                                 const float* __restrict__ g,
                                                 const float* __restrict__ b,
                                                 unsigned short* __restrict__ out) {
    __shared__ float sbuf[4];
    int row = blockIdx.x;
    int t = threadIdx.x;
    const float4* xr = (const float4*)(x + (size_t)row * D_MODEL);
    float4 v = xr[t];
    float s = v.x + v.y + v.z + v.w;
    for (int o = 32; o; o >>= 1) s += __shfl_down(s, o, 64);
    if ((t & 63) == 0) sbuf[t >> 6] = s;
    __syncthreads();
    float mu = (sbuf[0] + sbuf[1] + sbuf[2] + sbuf[3]) * (1.0f / D_MODEL);
    __syncthreads();
    float d0 = v.x - mu, d1 = v.y - mu, d2 = v.z - mu, d3 = v.w - mu;
    float q = d0*d0 + d1*d1 + d2*d2 + d3*d3;
    for (int o = 32; o; o >>= 1) q += __shfl_down(q, o, 64);
    if ((t & 63) == 0) sbuf[t >> 6] = q;
    __syncthreads();
    float var = (sbuf[0] + sbuf[1] + sbuf[2] + sbuf[3]) * (1.0f / D_MODEL);
    float rs = rsqrtf(var + 1e-5f);
    float4 gv = ((const float4*)g)[t];
    float4 bv = ((const float4*)b)[t];
    ushort4 st;
    st.x = f2bf(d0 * rs * gv.x + bv.x);
    st.y = f2bf(d1 * rs * gv.y + bv.y);
    st.z = f2bf(d2 * rs * gv.z + bv.z);
    st.w = f2bf(d3 * rs * gv.w + bv.w);
    ((ushort4*)(out + (size_t)row * D_MODEL))[t] = st;
}

// ---------------- bf16 MFMA GEMM (NT), 3-buffer depth-2 pipeline ----------------
// 128x128 tile, BK=32, 4 waves (2x2), 16x16x32 MFMA, global_load_lds staging,
// counted s_waitcnt vmcnt(N) (never 0 in steady state) + raw s_barrier,
// XCD-aware bijective block swizzle (grid x*y blocks % 8 == 0 required).
#define EPI_F32        0   // Cf = acc
#define EPI_F32_BF16   1   // Cf = acc, Cb = bf16(acc)
#define EPI_SOFTPLUS   2   // Cf = softplus(acc + bias)
#define EPI_RESID      3   // Cf = acc + resid
#define EPI_GELU_BF16  4   // Cb = bf16(gelu(acc + bias))
#define EPI_BIAS_RESID 5   // Cf = acc + bias + resid
#define EPI_BF16       6   // Cb = bf16(acc)

template<int EPI, int SPLITK>
__global__ __launch_bounds__(256) void gemm_mfma(
    const unsigned short* __restrict__ A, int lda,
    const unsigned short* __restrict__ B, int ldb, int K,   // K = per-split length
    float* __restrict__ Cf, unsigned short* __restrict__ Cb, int ldc,
    const float* __restrict__ bias,
    const float* __restrict__ resid, int ldr) {
    __shared__ unsigned short As[3][128 * 32];
    __shared__ unsigned short Bs[3][128 * 32];
    int t = threadIdx.x, l = t & 63, w = t >> 6;
    // XCD-aware bijective swizzle over x*y plane
    int nx = gridDim.x;
    int nwg = nx * gridDim.y;
    int bid = blockIdx.y * nx + blockIdx.x;
    int q = nwg >> 3;
    int swz = (bid & 7) * q + (bid >> 3);
    int m0 = (swz / nx) * 128, n0 = (swz % nx) * 128;
    int kbase = (SPLITK > 1) ? blockIdx.z * K : 0;
    // staging: 8 chunks of 16 rows x 32 cols per operand; wave w stages chunks 2w, 2w+1
    int c0 = 2 * w, c1 = 2 * w + 1;
    int srow = l >> 2, scol = (l & 3) * 8;
    const unsigned short* Ag0 = A + (size_t)(m0 + 16 * c0 + srow) * lda + kbase + scol;
    const unsigned short* Ag1 = A + (size_t)(m0 + 16 * c1 + srow) * lda + kbase + scol;
    const unsigned short* Bg0 = B + (size_t)(n0 + 16 * c0 + srow) * ldb + kbase + scol;
    const unsigned short* Bg1 = B + (size_t)(n0 + 16 * c1 + srow) * ldb + kbase + scol;
    // compute: wave (wr,wc) owns 64x64 quadrant; 4x4 fragments of 16x16
    int wr = w >> 1, wc = w & 1;
    int aoff = (wr * 64 + (l & 15)) * 32 + (l >> 4) * 8;
    int boff = (wc * 64 + (l & 15)) * 32 + (l >> 4) * 8;

    f32x4 acc[4][4] = {};
    int nt = K >> 5;

    // prologue: stage tiles 0,1 into buffers 0,1 (8 vmem ops in flight per wave)
    {
        gload16(Ag0, &As[0][c0 * 512]);
        gload16(Ag1, &As[0][c1 * 512]);
        gload16(Bg0, &Bs[0][c0 * 512]);
        gload16(Bg1, &Bs[0][c1 * 512]);
        if (nt > 1) {
            gload16(Ag0 + 32, &As[1][c0 * 512]);
            gload16(Ag1 + 32, &As[1][c1 * 512]);
            gload16(Bg0 + 32, &Bs[1][c0 * 512]);
            gload16(Bg1 + 32, &Bs[1][c1 * 512]);
        }
    }

    int cur = 0;
    for (int ti = 0; ti < nt; ti++) {
        int pf = ti + 2;
        if (pf < nt) {                       // stage tile ti+2 into buffer (ti+2)%3 == cur after 2 steps
            int nb = cur - 1; if (nb < 0) nb += 3;   // (cur+2)%3
            int k0 = pf << 5;
            gload16(Ag0 + k0, &As[nb][c0 * 512]);
            gload16(Ag1 + k0, &As[nb][c1 * 512]);
            gload16(Bg0 + k0, &Bs[nb][c0 * 512]);
            gload16(Bg1 + k0, &Bs[nb][c1 * 512]);
        }
        // counted wait: only tile ti must have landed; tiles ti+1, ti+2 stay in flight
        int rem = nt - 1 - ti;
        if (rem >= 2)      asm volatile("s_waitcnt vmcnt(8)" ::: "memory");
        else if (rem == 1) asm volatile("s_waitcnt vmcnt(4)" ::: "memory");
        else               asm volatile("s_waitcnt vmcnt(0)" ::: "memory");
        __builtin_amdgcn_s_barrier();

        const unsigned short* Ab = &As[cur][0];
        const unsigned short* Bb = &Bs[cur][0];
        bf16x8 af[4], bfv[4];
        #pragma unroll
        for (int i = 0; i < 4; i++) af[i] = *(const bf16x8*)(Ab + aoff + i * 512);
        #pragma unroll
        for (int i = 0; i < 4; i++) bfv[i] = *(const bf16x8*)(Bb + boff + i * 512);
        __builtin_amdgcn_s_setprio(1);
        #pragma unroll
        for (int mi = 0; mi < 4; mi++)
            #pragma unroll
            for (int ni = 0; ni < 4; ni++)
                acc[mi][ni] = __builtin_amdgcn_mfma_f32_16x16x32_bf16(af[mi], bfv[ni], acc[mi][ni], 0, 0, 0);
        __builtin_amdgcn_s_setprio(0);
        __builtin_amdgcn_s_barrier();        // readers done before buffer cur is re-staged next iter
        cur++; if (cur == 3) cur = 0;
    }

    // epilogue: D layout col=lane&15, row=(lane>>4)*4+j  [m89 verified]
    if (SPLITK > 1) Cf += (size_t)blockIdx.z * NROWS * ldc;
    int colb = n0 + wc * 64 + (l & 15);
    int rowb = m0 + wr * 64 + (l >> 4) * 4;
    #pragma unroll
    for (int ni = 0; ni < 4; ni++) {
        int col = colb + ni * 16;
        float bv = 0.0f;
        if (EPI == EPI_SOFTPLUS || EPI == EPI_GELU_BF16 || EPI == EPI_BIAS_RESID) bv = bias[col];
        #pragma unroll
        for (int mi = 0; mi < 4; mi++) {
            #pragma unroll
            for (int j = 0; j < 4; j++) {
                int row = rowb + mi * 16 + j;
                float v = acc[mi][ni][j];
                if (EPI == EPI_SOFTPLUS)        v = softplus_f(v + bv);
                else if (EPI == EPI_GELU_BF16)  v = gelu_f(v + bv);
                else if (EPI == EPI_RESID)      v = v + resid[(size_t)row * ldr + col];
                else if (EPI == EPI_BIAS_RESID) v = v + bv + resid[(size_t)row * ldr + col];
                if (EPI == EPI_GELU_BF16 || EPI == EPI_BF16) {
                    Cb[(size_t)row * ldc + col] = f2bf(v);
                } else {
                    Cf[(size_t)row * ldc + col] = v;
                    if (EPI == EPI_F32_BF16) Cb[(size_t)row * ldc + col] = f2bf(v);
                }
            }
        }
    }
}

// ---------------- x_proj split-K partial reduce: xdbl = sum of 4 partials ----------------
__global__ __launch_bounds__(256) void xdbl_reduce(const float* __restrict__ part,
                                                   float* __restrict__ xdbl,
                                                   unsigned short* __restrict__ xdbl_bf) {
    int i = blockIdx.x * 256 + threadIdx.x;
    const size_t seg = (size_t)NROWS * XPAD;
    float s = part[i] + part[i + seg] + part[i + 2 * seg] + part[i + 3 * seg];
    xdbl[i] = s;
    xdbl_bf[i] = f2bf(s);
}

// ---------------- causal depthwise conv (k=4) + SiLU -> bf16 u (8-wide) ----------------
__global__ __launch_bounds__(256) void conv_silu(const unsigned short* __restrict__ xz,
                                                 const float* __restrict__ w,
                                                 const float* __restrict__ cb,
                                                 unsigned short* __restrict__ u) {
    int idx = (blockIdx.x * 256 + threadIdx.x) * 8;   // (b*L + l)*D_INNER + d, d%8==0
    int d = idx % D_INNER;
    int bl = idx / D_INNER;
    int l = bl & (SEQ - 1);
    float acc[8];
    float4 wv[8];
    #pragma unroll
    for (int j = 0; j < 8; j++) wv[j] = *(const float4*)(w + (d + j) * 4);
    float4 cb0 = *(const float4*)(cb + d);
    float4 cb1 = *(const float4*)(cb + d + 4);
    acc[0] = cb0.x; acc[1] = cb0.y; acc[2] = cb0.z; acc[3] = cb0.w;
    acc[4] = cb1.x; acc[5] = cb1.y; acc[6] = cb1.z; acc[7] = cb1.w;
    #pragma unroll
    for (int k = 0; k < 4; k++) {
        int lp = l - 3 + k;
        if (lp >= 0) {
            u16x8 s = *(const u16x8*)(xz + (size_t)(bl - 3 + k) * (2 * D_INNER) + d);
            #pragma unroll
            for (int j = 0; j < 8; j++) {
                float wk = (k == 0) ? wv[j].x : (k == 1) ? wv[j].y : (k == 2) ? wv[j].z : wv[j].w;
                acc[j] += bf2f((unsigned short)s[j]) * wk;
            }
        }
    }
    u16x8 o;
    #pragma unroll
    for (int j = 0; j < 8; j++) o[j] = f2bf(silu_f(acc[j]));
    *(u16x8*)(u + idx) = o;
}

// ---------------- selective scan: pass A (per-chunk affine) ----------------
__global__ __launch_bounds__(256) void scan_passA(const float* __restrict__ delta,
                                                  const unsigned short* __restrict__ u,
                                                  const float* __restrict__ xdbl,
                                                  const float* __restrict__ A_log,
                                                  float* __restrict__ P,
                                                  float* __restrict__ S) {
    int d = blockIdx.x * 256 + threadIdx.x;
    int c = blockIdx.y, b = blockIdx.z;
    __shared__ float bc[LC][16];
    int base_row = b * SEQ + c * LC;
    for (int e = threadIdx.x; e < LC * 16; e += 256) {
        int lrr = e >> 4, col = e & 15;
        bc[lrr][col] = xdbl[(size_t)(base_row + lrr) * XPAD + DT_RANK + col];
    }
    __syncthreads();
    float Ad[8];
    #pragma unroll
    for (int n = 0; n < 8; n++) Ad[n] = -__expf(A_log[d * 8 + n]);
    float prod[8], hs[8];
    #pragma unroll
    for (int n = 0; n < 8; n++) { prod[n] = 1.0f; hs[n] = 0.0f; }
    for (int lrr = 0; lrr < LC; lrr++) {
        int row = base_row + lrr;
        float dl = delta[(size_t)row * D_INNER + d];
        float uu = bf2f(u[(size_t)row * D_INNER + d]);
        float du = dl * uu;
        #pragma unroll
        for (int n = 0; n < 8; n++) {
            float dA = __expf(dl * Ad[n]);
            prod[n] *= dA;
            hs[n] = dA * hs[n] + du * bc[lrr][n];
        }
    }
    size_t o = ((size_t)((size_t)b * NC + c) * D_INNER + d) * 8;
    #pragma unroll
    for (int n = 0; n < 8; n++) { P[o + n] = prod[n]; S[o + n] = hs[n]; }
}

// ---------------- scan: pass B (combine chunks) ----------------
__global__ __launch_bounds__(256) void scan_passB(const float* __restrict__ P,
                                                  const float* __restrict__ S,
                                                  float* __restrict__ hstart) {
    int tid = blockIdx.x * 256 + threadIdx.x;    // B * D_INNER * 8 = 24576
    int b = tid / (D_INNER * 8);
    int rem = tid % (D_INNER * 8);
    float h = 0.0f;
    for (int c = 0; c < NC; c++) {
        size_t o = (size_t)(b * NC + c) * (D_INNER * 8) + rem;
        hstart[o] = h;
        h = P[o] * h + S[o];
    }
}

// ---------------- scan: pass C (final y + gate) -> bf16 ygate ----------------
__global__ __launch_bounds__(256) void scan_passC(const float* __restrict__ delta,
                                                  const unsigned short* __restrict__ u,
                                                  const float* __restrict__ xdbl,
                                                  const float* __restrict__ A_log,
                                                  const float* __restrict__ hstart,
                                                  const unsigned short* __restrict__ xz,
                                                  const float* __restrict__ Dp,
                                                  unsigned short* __restrict__ ygate) {
    int d = blockIdx.x * 256 + threadIdx.x;
    int c = blockIdx.y, b = blockIdx.z;
    __shared__ float bc[LC][16];
    int base_row = b * SEQ + c * LC;
    for (int e = threadIdx.x; e < LC * 16; e += 256) {
        int lrr = e >> 4, col = e & 15;
        bc[lrr][col] = xdbl[(size_t)(base_row + lrr) * XPAD + DT_RANK + col];
    }
    __syncthreads();
    float Ad[8];
    #pragma unroll
    for (int n = 0; n < 8; n++) Ad[n] = -__expf(A_log[d * 8 + n]);
    float h[8];
    size_t ho = ((size_t)((size_t)b * NC + c) * D_INNER + d) * 8;
    #pragma unroll
    for (int n = 0; n < 8; n++) h[n] = hstart[ho + n];
    float Dd = Dp[d];
    for (int lrr = 0; lrr < LC; lrr++) {
        int row = base_row + lrr;
        float dl = delta[(size_t)row * D_INNER + d];
        float uu = bf2f(u[(size_t)row * D_INNER + d]);
        float du = dl * uu;
        float y = 0.0f;
        #pragma unroll
        for (int n = 0; n < 8; n++) {
            float dA = __expf(dl * Ad[n]);
            h[n] = dA * h[n] + du * bc[lrr][n];
            y += h[n] * bc[lrr][8 + n];
        }
        y += uu * Dd;
        float z = bf2f(xz[(size_t)row * (2 * D_INNER) + D_INNER + d]);
        ygate[(size_t)row * D_INNER + d] = f2bf(y * silu_f(z));
    }
}

// ---------------- launch ----------------
extern "C" void kernel_launch(void* const* d_in, const int* in_sizes, int n_in,
                              void* d_out, int out_size, void* d_ws, size_t ws_size,
                              hipStream_t stream) {
    const float* x         = (const float*)d_in[0];
    const float* ln1_g     = (const float*)d_in[1];
    const float* ln1_b     = (const float*)d_in[2];
    const float* ln2_g     = (const float*)d_in[3];
    const float* ln2_b     = (const float*)d_in[4];
    const float* in_proj_w = (const float*)d_in[5];
    const float* conv_w    = (const float*)d_in[6];
    const float* conv_b    = (const float*)d_in[7];
    const float* x_proj_w  = (const float*)d_in[8];
    const float* dt_proj_w = (const float*)d_in[9];
    const float* dt_proj_b = (const float*)d_in[10];
    const float* A_log     = (const float*)d_in[11];
    const float* Dp        = (const float*)d_in[12];
    const float* out_proj_w= (const float*)d_in[13];
    const float* ffn_w1    = (const float*)d_in[14];
    const float* ffn_b1    = (const float*)d_in[15];
    const float* ffn_w2    = (const float*)d_in[16];
    const float* ffn_b2    = (const float*)d_in[17];
    float* out = (float*)d_out;

    // ---- workspace layout ----
    float* xdbl  = (float*)d_ws;                           // 4096*128 f32
    float* delta = xdbl + (size_t)NROWS * XPAD;            // 4096*1536 f32
    float* P     = delta + (size_t)NROWS * D_INNER;        // 2*32*1536*8
    float* S     = P + (size_t)BATCH * NC * D_INNER * 8;
    float* hst   = S + (size_t)BATCH * NC * D_INNER * 8;
    float* x2    = hst + (size_t)BATCH * NC * D_INNER * 8; // 4096*1024 f32
    float* part  = x2;                                     // overlay: x_proj split-K partials (8MB <= 16.8MB), dead before out_proj
    unsigned short* xz_bf   = (unsigned short*)(x2 + (size_t)NROWS * D_MODEL); // 4096*3072 bf16 (later hff overlay)
    unsigned short* xp_bf   = xz_bf + (size_t)NROWS * 2 * D_INNER;             // 4096*1024 (reused as xn_bf)
    unsigned short* u_bf    = xp_bf + (size_t)NROWS * D_MODEL;                 // 4096*1536
    unsigned short* xdbl_bf = u_bf + (size_t)NROWS * D_INNER;                  // 4096*128
    unsigned short* yg_bf   = xdbl_bf + (size_t)NROWS * XPAD;                  // 4096*1536
    unsigned short* w_in    = yg_bf + (size_t)NROWS * D_INNER;                 // 3072*1024
    unsigned short* w_xp    = w_in + (size_t)2 * D_INNER * D_MODEL;            // 128*1536 (padded)
    unsigned short* w_dt    = w_xp + (size_t)XPAD * D_INNER;                   // 1536*64
    unsigned short* w_out   = w_dt + (size_t)D_INNER * DT_RANK;                // 1024*1536
    unsigned short* w_f1    = w_out + (size_t)D_MODEL * D_INNER;               // 2048*1024
    unsigned short* w_f2    = w_f1 + (size_t)D_FF * D_MODEL;                   // 1024*2048
    unsigned short* hff_bf  = xz_bf;   // overlay: xz dead after scan_passC

    // 0. weight conversions
    wconv<<<4400, 256, 0, stream>>>(in_proj_w, w_in, dt_proj_w, w_dt, out_proj_w, w_out,
                                    ffn_w1, w_f1, ffn_w2, w_f2);
    xproj_pad<<<XPAD, 256, 0, stream>>>(x_proj_w, w_xp);
    // 1. LN1 -> bf16
    ln_kernel<<<NROWS, 256, 0, stream>>>(x, ln1_g, ln1_b, xp_bf);
    // 2. in_proj: xz = xp @ in_proj_w^T  (4096 x 3072, K=1024) -> bf16
    gemm_mfma<EPI_BF16, 1><<<dim3(3072 / 128, NROWS / 128), 256, 0, stream>>>(
        xp_bf, D_MODEL, w_in, D_MODEL, D_MODEL, nullptr, xz_bf, 2 * D_INNER, nullptr, nullptr, 0);
    // 3. conv + silu -> u (bf16)
    conv_silu<<<(NROWS * D_INNER) / (256 * 8), 256, 0, stream>>>(xz_bf, conv_w, conv_b, u_bf);
    // 4. x_proj split-K=4: part[z] = u @ x_proj_w^T |_{Kz}  (4096 x 128pad, K=384 each)
    gemm_mfma<EPI_F32, 4><<<dim3(1, NROWS / 128, 4), 256, 0, stream>>>(
        u_bf, D_INNER, w_xp, D_INNER, D_INNER / 4, part, nullptr, XPAD, nullptr, nullptr, 0);
    xdbl_reduce<<<(NROWS * XPAD) / 256, 256, 0, stream>>>(part, xdbl, xdbl_bf);
    // 5. dt_proj + softplus: delta (4096 x 1536, K=64)
    gemm_mfma<EPI_SOFTPLUS, 1><<<dim3(D_INNER / 128, NROWS / 128), 256, 0, stream>>>(
        xdbl_bf, XPAD, w_dt, DT_RANK, DT_RANK, delta, nullptr, D_INNER, dt_proj_b, nullptr, 0);
    // 6-8. selective scan
    scan_passA<<<dim3(D_INNER / 256, NC, BATCH), 256, 0, stream>>>(delta, u_bf, xdbl, A_log, P, S);
    scan_passB<<<(BATCH * D_INNER * 8) / 256, 256, 0, stream>>>(P, S, hst);
    scan_passC<<<dim3(D_INNER / 256, NC, BATCH), 256, 0, stream>>>(delta, u_bf, xdbl, A_log, hst, xz_bf, Dp, yg_bf);
    // 9. out_proj + residual: x2 = ygate @ out_proj_w^T + x  (4096 x 1024, K=1536)
    gemm_mfma<EPI_RESID, 1><<<dim3(D_MODEL / 128, NROWS / 128), 256, 0, stream>>>(
        yg_bf, D_INNER, w_out, D_INNER, D_INNER, x2, nullptr, D_MODEL, nullptr, x, D_MODEL);
    // 10. LN2 -> bf16 (reuse xp_bf)
    ln_kernel<<<NROWS, 256, 0, stream>>>(x2, ln2_g, ln2_b, xp_bf);
    // 11. ffn1 + gelu -> bf16 hff  (4096 x 2048, K=1024)
    gemm_mfma<EPI_GELU_BF16, 1><<<dim3(D_FF / 128, NROWS / 128), 256, 0, stream>>>(
        xp_bf, D_MODEL, w_f1, D_MODEL, D_MODEL, nullptr, hff_bf, D_FF, ffn_b1, nullptr, 0);
    // 12. ffn2 + bias + residual: out = x2 + hff @ ffn_w2^T + b2  (4096 x 1024, K=2048)
    gemm_mfma<EPI_BIAS_RESID, 1><<<dim3(D_MODEL / 128, NROWS / 128), 256, 0, stream>>>(
        hff_bf, D_FF, w_f2, D_FF, D_FF, out, nullptr, D_MODEL, ffn_b2, x2, D_MODEL);
}

// Round 6
// 306.193 us; speedup vs baseline: 4.1129x; 1.0233x over previous
//
#include <hip/hip_runtime.h>
#include <math.h>

#define D_MODEL 1024
#define D_STATE 8
#define D_CONV  4
#define D_INNER 1536
#define DT_RANK 64
#define D_FF    2048
#define BATCH   2
#define SEQ     2048
#define NROWS   (BATCH*SEQ)      // 4096
#define NC      32               // scan chunks
#define LC      (SEQ/NC)         // 64
#define XPAD    128              // padded x_dbl width (was 80)

typedef short bf16x8 __attribute__((ext_vector_type(8)));
typedef unsigned short u16x8 __attribute__((ext_vector_type(8)));
typedef float f32x4  __attribute__((ext_vector_type(4)));

__device__ inline unsigned short f2bf(float x) {
    union { float f; unsigned u; } v; v.f = x;
    unsigned r = v.u + 0x7fffu + ((v.u >> 16) & 1u);
    return (unsigned short)(r >> 16);
}
__device__ inline float bf2f(unsigned short h) {
    union { unsigned u; float f; } v; v.u = ((unsigned)h) << 16;
    return v.f;
}
__device__ inline float softplus_f(float x) {
    return (x > 20.0f) ? x : log1pf(__expf(x));
}
__device__ inline float gelu_f(float x) {
    return 0.5f * x * (1.0f + erff(x * 0.70710678118654752f));
}
__device__ inline float silu_f(float x) {
    return x / (1.0f + __expf(-x));
}
__device__ inline void gload16(const unsigned short* g, unsigned short* l) {
    typedef unsigned int u32;
    __builtin_amdgcn_global_load_lds(
        (const __attribute__((address_space(1))) u32*)g,
        (__attribute__((address_space(3))) u32*)l, 16, 0, 0);
}

#define PHASE_SYNC_PRE()  do { __builtin_amdgcn_s_barrier(); __builtin_amdgcn_sched_barrier(0); \
                               asm volatile("s_waitcnt lgkmcnt(0)" ::: "memory"); \
                               __builtin_amdgcn_sched_barrier(0); } while (0)
#define PHASE_SYNC_POST() do { __builtin_amdgcn_s_barrier(); __builtin_amdgcn_sched_barrier(0); } while (0)

// ---------------- weight f32 -> bf16 conversion (fused 5 segments) ----------------
__global__ __launch_bounds__(256) void wconv(const float* __restrict__ s0, unsigned short* __restrict__ d0,
                                             const float* __restrict__ s1, unsigned short* __restrict__ d1,
                                             const float* __restrict__ s2, unsigned short* __restrict__ d2,
                                             const float* __restrict__ s3, unsigned short* __restrict__ d3,
                                             const float* __restrict__ s4, unsigned short* __restrict__ d4) {
    int b = blockIdx.x;
    const float* s; unsigned short* d; int base;
    if      (b < 1536) { s = s0; d = d0; base = b * 2048; }
    else if (b < 1584) { s = s1; d = d1; base = (b - 1536) * 2048; }
    else if (b < 2352) { s = s2; d = d2; base = (b - 1584) * 2048; }
    else if (b < 3376) { s = s3; d = d3; base = (b - 2352) * 2048; }
    else               { s = s4; d = d4; base = (b - 3376) * 2048; }
    int i = base + threadIdx.x * 8;
    float4 v0 = *(const float4*)(s + i);
    float4 v1 = *(const float4*)(s + i + 4);
    ushort4 a, c;
    a.x = f2bf(v0.x); a.y = f2bf(v0.y); a.z = f2bf(v0.z); a.w = f2bf(v0.w);
    c.x = f2bf(v1.x); c.y = f2bf(v1.y); c.z = f2bf(v1.z); c.w = f2bf(v1.w);
    *(ushort4*)(d + i)     = a;
    *(ushort4*)(d + i + 4) = c;
}

// x_proj_w [80][1536] -> padded bf16 [128][1536]
__global__ __launch_bounds__(256) void xproj_pad(const float* __restrict__ src, unsigned short* __restrict__ dst) {
    int row = blockIdx.x;
    for (int c = threadIdx.x; c < D_INNER; c += 256)
        dst[row * D_INNER + c] = (row < 80) ? f2bf(src[row * D_INNER + c]) : (unsigned short)0;
}

// ---------------- LayerNorm -> bf16 ----------------
__global__ __launch_bounds__(256) void ln_kernel(const float* __restrict__ x,
                                                 const float* __restrict__ g,
                                                 const float* __restrict__ b,
                                                 unsigned short* __restrict__ out) {
    __shared__ float sbuf[4];
    int row = blockIdx.x;
    int t = threadIdx.x;
    const float4* xr = (const float4*)(x + (size_t)row * D_MODEL);
    float4 v = xr[t];
    float s = v.x + v.y + v.z + v.w;
    for (int o = 32; o; o >>= 1) s += __shfl_down(s, o, 64);
    if ((t & 63) == 0) sbuf[t >> 6] = s;
    __syncthreads();
    float mu = (sbuf[0] + sbuf[1] + sbuf[2] + sbuf[3]) * (1.0f / D_MODEL);
    __syncthreads();
    float d0 = v.x - mu, d1 = v.y - mu, d2 = v.z - mu, d3 = v.w - mu;
    float q = d0*d0 + d1*d1 + d2*d2 + d3*d3;
    for (int o = 32; o; o >>= 1) q += __shfl_down(q, o, 64);
    if ((t & 63) == 0) sbuf[t >> 6] = q;
    __syncthreads();
    float var = (sbuf[0] + sbuf[1] + sbuf[2] + sbuf[3]) * (1.0f / D_MODEL);
    float rs = rsqrtf(var + 1e-5f);
    float4 gv = ((const float4*)g)[t];
    float4 bv = ((const float4*)b)[t];
    ushort4 st;
    st.x = f2bf(d0 * rs * gv.x + bv.x);
    st.y = f2bf(d1 * rs * gv.y + bv.y);
    st.z = f2bf(d2 * rs * gv.z + bv.z);
    st.w = f2bf(d3 * rs * gv.w + bv.w);
    ((ushort4*)(out + (size_t)row * D_MODEL))[t] = st;
}

// ---------------- epilogue IDs ----------------
#define EPI_F32        0   // Cf = acc
#define EPI_F32_BF16   1   // Cf = acc, Cb = bf16(acc)
#define EPI_SOFTPLUS   2   // Cf = softplus(acc + bias)
#define EPI_RESID      3   // Cf = acc + resid
#define EPI_GELU_BF16  4   // Cb = bf16(gelu(acc + bias))
#define EPI_BIAS_RESID 5   // Cf = acc + bias + resid
#define EPI_BF16       6   // Cb = bf16(acc)

// ================= 8-phase 256-row MFMA GEMM (NT) =================
// BM=256, BN=WN*64 (WN=4 -> 256, WN=2 -> 128), BK=64, 8 waves (WMxWN),
// st_16x32 XOR swizzle (linear LDS dest + inverse-swizzled global src +
// swizzled ds_read), counted vmcnt at phases 4/8 only, setprio around MFMA,
// XCD-aware bijective block swizzle. Requires M%256==0, N%BN==0, K%128==0,
// grid blocks %8==0.
template<int WN, int EPI>
__global__ __launch_bounds__(512, 2) void gemm8p(
    const unsigned short* __restrict__ A, int lda,
    const unsigned short* __restrict__ Bm, int ldb, int K,
    float* __restrict__ Cf, unsigned short* __restrict__ Cb, int ldc,
    const float* __restrict__ bias,
    const float* __restrict__ resid, int ldr) {
    constexpr int WM = 8 / WN;            // 2 or 4
    constexpr int BN = WN * 64;           // 256 or 128
    constexpr int RW = 256 / WM;          // per-wave rows: 128 or 64
    constexpr int CW = 64;                // per-wave cols
    constexpr int MI = RW / 16;           // 8 or 4
    constexpr int NI = CW / 16;           // 4
    constexpr int MIH = MI / 2, NIH = NI / 2;
    constexpr int ABYTES = 256 * 128;     // 32 KB per A K-tile
    constexpr int BBYTES = BN * 128;      // 32 or 16 KB per B K-tile
    constexpr int BOFF = 2 * ABYTES;
    __shared__ unsigned short lds[(2 * ABYTES + 2 * BBYTES) / 2];

    const int t = threadIdx.x, l = t & 63, w = t >> 6;
    const int wr = w / WN, wc = w % WN;

    const int nx = gridDim.x;
    const int nwg = nx * gridDim.y;
    int bid = blockIdx.y * nx + blockIdx.x;
    int q = nwg >> 3;
    int swz = (bid & 7) * q + (bid >> 3);
    const int m0 = (swz / nx) * 256, n0 = (swz % nx) * BN;

    // staging lane constants: each gload round = 8KB (8 waves x 64 lanes x 16B)
    const int sr = l >> 3;                                   // row within 8-row wave chunk
    const int sj = ((l & 7) * 16) ^ (((l >> 5) & 1) << 5);   // inverse-swizzled byte-in-row
    const int row_l = w * 8;                                 // linear 64-row quarter
    const int row_c = (w >> 2) * 64 + (w & 3) * 8;           // chunked {0-31,64-95}

    auto STG = [&](int bufbyte, int rowbase, const unsigned short* G, int ldg, int gbase, int kt) {
        unsigned short* dst = (unsigned short*)((char*)lds + bufbyte + rowbase * 128);
        const unsigned short* src = G + (size_t)(gbase + rowbase + sr) * ldg + kt * 64 + (sj >> 1);
        gload16(src, dst);
    };
    auto S_Ah0 = [&](int b, int kt) {
        if (WN == 4) { STG(b * ABYTES, row_l, A, lda, m0, kt);       STG(b * ABYTES, 128 + row_l, A, lda, m0, kt); }
        else         { STG(b * ABYTES, row_c, A, lda, m0, kt);       STG(b * ABYTES, 128 + row_c, A, lda, m0, kt); }
    };
    auto S_Ah1 = [&](int b, int kt) {
        if (WN == 4) { STG(b * ABYTES, 64 + row_l, A, lda, m0, kt);  STG(b * ABYTES, 192 + row_l, A, lda, m0, kt); }
        else         { STG(b * ABYTES, 32 + row_c, A, lda, m0, kt);  STG(b * ABYTES, 160 + row_c, A, lda, m0, kt); }
    };
    auto S_Bc0 = [&](int b, int kt) {
        if (WN == 4) { STG(BOFF + b * BBYTES, row_c, Bm, ldb, n0, kt); STG(BOFF + b * BBYTES, 128 + row_c, Bm, ldb, n0, kt); }
        else         { STG(BOFF + b * BBYTES, row_c, Bm, ldb, n0, kt); }
    };
    auto S_Bc1 = [&](int b, int kt) {
        if (WN == 4) { STG(BOFF + b * BBYTES, 32 + row_c, Bm, ldb, n0, kt); STG(BOFF + b * BBYTES, 160 + row_c, Bm, ldb, n0, kt); }
        else         { STG(BOFF + b * BBYTES, 32 + row_c, Bm, ldb, n0, kt); }
    };

    // swizzled ds_read of one bf16x8 fragment
    auto LD = [&](int bytebase, int row, int kb) -> bf16x8 {
        int o = bytebase + row * 128 + (kb ^ (((row >> 2) & 1) << 5));
        return *(const bf16x8*)((const char*)lds + o);
    };

    f32x4 acc[MI][NI] = {};
    bf16x8 af[MIH][2], b0v[NIH][2], b1v[NIH][2];

    auto LDA_set = [&](int buf, int qr, auto& dst) {
        #pragma unroll
        for (int mi = 0; mi < MIH; mi++)
            #pragma unroll
            for (int ks = 0; ks < 2; ks++)
                dst[mi][ks] = LD(buf * ABYTES, wr * RW + qr * (RW / 2) + mi * 16 + (l & 15),
                                 ks * 64 + (l >> 4) * 16);
    };
    auto LDB_set = [&](int buf, int qc, auto& dst) {
        #pragma unroll
        for (int ni2 = 0; ni2 < NIH; ni2++)
            #pragma unroll
            for (int ks = 0; ks < 2; ks++)
                dst[ni2][ks] = LD(BOFF + buf * BBYTES, wc * CW + qc * 32 + ni2 * 16 + (l & 15),
                                  ks * 64 + (l >> 4) * 16);
    };
    auto MFMA_Q = [&](int qr, int qc, auto& a_, auto& b_) {
        __builtin_amdgcn_s_setprio(1);
        #pragma unroll
        for (int mi = 0; mi < MIH; mi++)
            #pragma unroll
            for (int ni2 = 0; ni2 < NIH; ni2++)
                #pragma unroll
                for (int ks = 0; ks < 2; ks++)
                    acc[qr * MIH + mi][qc * NIH + ni2] =
                        __builtin_amdgcn_mfma_f32_16x16x32_bf16(a_[mi][ks], b_[ni2][ks],
                                                                acc[qr * MIH + mi][qc * NIH + ni2], 0, 0, 0);
        __builtin_amdgcn_s_setprio(0);
    };
    auto VMW = [&](bool last) {
        if (last)            asm volatile("s_waitcnt vmcnt(0)" ::: "memory");
        else if (WN == 4)    asm volatile("s_waitcnt vmcnt(6)" ::: "memory");
        else                 asm volatile("s_waitcnt vmcnt(5)" ::: "memory");
        __builtin_amdgcn_sched_barrier(0);
    };

    const int ni_ = K >> 7;    // iterations; 2 K-tiles (of 64) per iter

    // prologue: stage tiles 0,1 fully; wait for tile 0
    S_Ah0(0, 0); S_Ah1(0, 0); S_Bc0(0, 0); S_Bc1(0, 0);
    S_Ah0(1, 1); S_Ah1(1, 1); S_Bc0(1, 1); S_Bc1(1, 1);
    if (WN == 4) asm volatile("s_waitcnt vmcnt(8)" ::: "memory");
    else         asm volatile("s_waitcnt vmcnt(6)" ::: "memory");
    __builtin_amdgcn_s_barrier();
    __builtin_amdgcn_sched_barrier(0);

    for (int i = 0; i < ni_; i++) {
        const bool last = (i == ni_ - 1);
        const int t2 = 2 * i + 2, t3 = 2 * i + 3;
        // phase 1: buf0 q(0,0)
        LDA_set(0, 0, af); LDB_set(0, 0, b0v);
        if (i) S_Bc0(1, 2 * i + 1);
        PHASE_SYNC_PRE(); MFMA_Q(0, 0, af, b0v); PHASE_SYNC_POST();
        // phase 2: buf0 q(0,1)
        LDB_set(0, 1, b1v);
        if (!last) S_Ah0(0, t2);
        PHASE_SYNC_PRE(); MFMA_Q(0, 1, af, b1v); PHASE_SYNC_POST();
        // phase 3: buf0 q(1,1)
        LDA_set(0, 1, af);
        PHASE_SYNC_PRE(); MFMA_Q(1, 1, af, b1v); PHASE_SYNC_POST();
        // phase 4: buf0 q(1,0)
        LDB_set(0, 0, b0v);
        if (!last) { S_Ah1(0, t2); S_Bc1(0, t2); }
        VMW(last);
        PHASE_SYNC_PRE(); MFMA_Q(1, 0, af, b0v); PHASE_SYNC_POST();
        // phase 5: buf1 q(0,0)
        LDA_set(1, 0, af); LDB_set(1, 0, b0v);
        if (!last) S_Bc0(0, t2);
        PHASE_SYNC_PRE(); MFMA_Q(0, 0, af, b0v); PHASE_SYNC_POST();
        // phase 6: buf1 q(0,1)
        LDB_set(1, 1, b1v);
        if (!last) S_Ah0(1, t3);
        PHASE_SYNC_PRE(); MFMA_Q(0, 1, af, b1v); PHASE_SYNC_POST();
        // phase 7: buf1 q(1,1)
        LDA_set(1, 1, af);
        PHASE_SYNC_PRE(); MFMA_Q(1, 1, af, b1v); PHASE_SYNC_POST();
        // phase 8: buf1 q(1,0)
        LDB_set(1, 0, b0v);
        if (!last) { S_Ah1(1, t3); S_Bc1(1, t3); }
        VMW(last);
        PHASE_SYNC_PRE(); MFMA_Q(1, 0, af, b0v); PHASE_SYNC_POST();
    }

    // epilogue: D layout col=lane&15, row=(lane>>4)*4+j  [m89 verified]
    #pragma unroll
    for (int ni2 = 0; ni2 < NI; ni2++) {
        int col = n0 + wc * CW + ni2 * 16 + (l & 15);
        float bv = 0.0f;
        if (EPI == EPI_SOFTPLUS || EPI == EPI_GELU_BF16 || EPI == EPI_BIAS_RESID) bv = bias[col];
        #pragma unroll
        for (int mi = 0; mi < MI; mi++) {
            #pragma unroll
            for (int j = 0; j < 4; j++) {
                int row = m0 + wr * RW + mi * 16 + (l >> 4) * 4 + j;
                float v = acc[mi][ni2][j];
                if (EPI == EPI_SOFTPLUS)        v = softplus_f(v + bv);
                else if (EPI == EPI_GELU_BF16)  v = gelu_f(v + bv);
                else if (EPI == EPI_RESID)      v = v + resid[(size_t)row * ldr + col];
                else if (EPI == EPI_BIAS_RESID) v = v + bv + resid[(size_t)row * ldr + col];
                if (EPI == EPI_GELU_BF16 || EPI == EPI_BF16) {
                    Cb[(size_t)row * ldc + col] = f2bf(v);
                } else {
                    Cf[(size_t)row * ldc + col] = v;
                    if (EPI == EPI_F32_BF16) Cb[(size_t)row * ldc + col] = f2bf(v);
                }
            }
        }
    }
}

// ---------------- small-GEMM path (x_proj, dt_proj): 128x128, 3-buf ----------------
template<int EPI, int SPLITK>
__global__ __launch_bounds__(256) void gemm_mfma(
    const unsigned short* __restrict__ A, int lda,
    const unsigned short* __restrict__ B, int ldb, int K,
    float* __restrict__ Cf, unsigned short* __restrict__ Cb, int ldc,
    const float* __restrict__ bias,
    const float* __restrict__ resid, int ldr) {
    __shared__ unsigned short As[3][128 * 32];
    __shared__ unsigned short Bs[3][128 * 32];
    int t = threadIdx.x, l = t & 63, w = t >> 6;
    int nx = gridDim.x;
    int nwg = nx * gridDim.y;
    int bid = blockIdx.y * nx + blockIdx.x;
    int q = nwg >> 3;
    int swz = (bid & 7) * q + (bid >> 3);
    int m0 = (swz / nx) * 128, n0 = (swz % nx) * 128;
    int kbase = (SPLITK > 1) ? blockIdx.z * K : 0;
    int c0 = 2 * w, c1 = 2 * w + 1;
    int srow = l >> 2, scol = (l & 3) * 8;
    const unsigned short* Ag0 = A + (size_t)(m0 + 16 * c0 + srow) * lda + kbase + scol;
    const unsigned short* Ag1 = A + (size_t)(m0 + 16 * c1 + srow) * lda + kbase + scol;
    const unsigned short* Bg0 = B + (size_t)(n0 + 16 * c0 + srow) * ldb + kbase + scol;
    const unsigned short* Bg1 = B + (size_t)(n0 + 16 * c1 + srow) * ldb + kbase + scol;
    int wr = w >> 1, wc = w & 1;
    int aoff = (wr * 64 + (l & 15)) * 32 + (l >> 4) * 8;
    int boff = (wc * 64 + (l & 15)) * 32 + (l >> 4) * 8;

    f32x4 acc[4][4] = {};
    int nt = K >> 5;

    gload16(Ag0, &As[0][c0 * 512]);
    gload16(Ag1, &As[0][c1 * 512]);
    gload16(Bg0, &Bs[0][c0 * 512]);
    gload16(Bg1, &Bs[0][c1 * 512]);
    if (nt > 1) {
        gload16(Ag0 + 32, &As[1][c0 * 512]);
        gload16(Ag1 + 32, &As[1][c1 * 512]);
        gload16(Bg0 + 32, &Bs[1][c0 * 512]);
        gload16(Bg1 + 32, &Bs[1][c1 * 512]);
    }

    int cur = 0;
    for (int ti = 0; ti < nt; ti++) {
        int pf = ti + 2;
        if (pf < nt) {
            int nb = cur - 1; if (nb < 0) nb += 3;
            int k0 = pf << 5;
            gload16(Ag0 + k0, &As[nb][c0 * 512]);
            gload16(Ag1 + k0, &As[nb][c1 * 512]);
            gload16(Bg0 + k0, &Bs[nb][c0 * 512]);
            gload16(Bg1 + k0, &Bs[nb][c1 * 512]);
        }
        int rem = nt - 1 - ti;
        if (rem >= 2)      asm volatile("s_waitcnt vmcnt(8)" ::: "memory");
        else if (rem == 1) asm volatile("s_waitcnt vmcnt(4)" ::: "memory");
        else               asm volatile("s_waitcnt vmcnt(0)" ::: "memory");
        __builtin_amdgcn_s_barrier();

        const unsigned short* Ab = &As[cur][0];
        const unsigned short* Bb = &Bs[cur][0];
        bf16x8 af[4], bfv[4];
        #pragma unroll
        for (int i = 0; i < 4; i++) af[i] = *(const bf16x8*)(Ab + aoff + i * 512);
        #pragma unroll
        for (int i = 0; i < 4; i++) bfv[i] = *(const bf16x8*)(Bb + boff + i * 512);
        __builtin_amdgcn_s_setprio(1);
        #pragma unroll
        for (int mi = 0; mi < 4; mi++)
            #pragma unroll
            for (int ni = 0; ni < 4; ni++)
                acc[mi][ni] = __builtin_amdgcn_mfma_f32_16x16x32_bf16(af[mi], bfv[ni], acc[mi][ni], 0, 0, 0);
        __builtin_amdgcn_s_setprio(0);
        __builtin_amdgcn_s_barrier();
        cur++; if (cur == 3) cur = 0;
    }

    if (SPLITK > 1) Cf += (size_t)blockIdx.z * NROWS * ldc;
    int colb = n0 + wc * 64 + (l & 15);
    int rowb = m0 + wr * 64 + (l >> 4) * 4;
    #pragma unroll
    for (int ni = 0; ni < 4; ni++) {
        int col = colb + ni * 16;
        float bv = 0.0f;
        if (EPI == EPI_SOFTPLUS || EPI == EPI_GELU_BF16 || EPI == EPI_BIAS_RESID) bv = bias[col];
        #pragma unroll
        for (int mi = 0; mi < 4; mi++) {
            #pragma unroll
            for (int j = 0; j < 4; j++) {
                int row = rowb + mi * 16 + j;
                float v = acc[mi][ni][j];
                if (EPI == EPI_SOFTPLUS)        v = softplus_f(v + bv);
                else if (EPI == EPI_GELU_BF16)  v = gelu_f(v + bv);
                else if (EPI == EPI_RESID)      v = v + resid[(size_t)row * ldr + col];
                else if (EPI == EPI_BIAS_RESID) v = v + bv + resid[(size_t)row * ldr + col];
                if (EPI == EPI_GELU_BF16 || EPI == EPI_BF16) {
                    Cb[(size_t)row * ldc + col] = f2bf(v);
                } else {
                    Cf[(size_t)row * ldc + col] = v;
                    if (EPI == EPI_F32_BF16) Cb[(size_t)row * ldc + col] = f2bf(v);
                }
            }
        }
    }
}

// ---------------- x_proj split-K partial reduce ----------------
__global__ __launch_bounds__(256) void xdbl_reduce(const float* __restrict__ part,
                                                   float* __restrict__ xdbl,
                                                   unsigned short* __restrict__ xdbl_bf) {
    int i = blockIdx.x * 256 + threadIdx.x;
    const size_t seg = (size_t)NROWS * XPAD;
    float s = part[i] + part[i + seg] + part[i + 2 * seg] + part[i + 3 * seg];
    xdbl[i] = s;
    xdbl_bf[i] = f2bf(s);
}

// ---------------- causal depthwise conv (k=4) + SiLU -> bf16 u (8-wide) ----------------
__global__ __launch_bounds__(256) void conv_silu(const unsigned short* __restrict__ xz,
                                                 const float* __restrict__ w,
                                                 const float* __restrict__ cb,
                                                 unsigned short* __restrict__ u) {
    int idx = (blockIdx.x * 256 + threadIdx.x) * 8;
    int d = idx % D_INNER;
    int bl = idx / D_INNER;
    int l = bl & (SEQ - 1);
    float acc[8];
    float4 wv[8];
    #pragma unroll
    for (int j = 0; j < 8; j++) wv[j] = *(const float4*)(w + (d + j) * 4);
    float4 cb0 = *(const float4*)(cb + d);
    float4 cb1 = *(const float4*)(cb + d + 4);
    acc[0] = cb0.x; acc[1] = cb0.y; acc[2] = cb0.z; acc[3] = cb0.w;
    acc[4] = cb1.x; acc[5] = cb1.y; acc[6] = cb1.z; acc[7] = cb1.w;
    #pragma unroll
    for (int k = 0; k < 4; k++) {
        int lp = l - 3 + k;
        if (lp >= 0) {
            u16x8 s = *(const u16x8*)(xz + (size_t)(bl - 3 + k) * (2 * D_INNER) + d);
            #pragma unroll
            for (int j = 0; j < 8; j++) {
                float wk = (k == 0) ? wv[j].x : (k == 1) ? wv[j].y : (k == 2) ? wv[j].z : wv[j].w;
                acc[j] += bf2f((unsigned short)s[j]) * wk;
            }
        }
    }
    u16x8 o;
    #pragma unroll
    for (int j = 0; j < 8; j++) o[j] = f2bf(silu_f(acc[j]));
    *(u16x8*)(u + idx) = o;
}

// ---------------- selective scan: pass A ----------------
__global__ __launch_bounds__(256) void scan_passA(const float* __restrict__ delta,
                                                  const unsigned short* __restrict__ u,
                                                  const float* __restrict__ xdbl,
                                                  const float* __restrict__ A_log,
                                                  float* __restrict__ P,
                                                  float* __restrict__ S) {
    int d = blockIdx.x * 256 + threadIdx.x;
    int c = blockIdx.y, b = blockIdx.z;
    __shared__ float bc[LC][16];
    int base_row = b * SEQ + c * LC;
    for (int e = threadIdx.x; e < LC * 16; e += 256) {
        int lrr = e >> 4, col = e & 15;
        bc[lrr][col] = xdbl[(size_t)(base_row + lrr) * XPAD + DT_RANK + col];
    }
    __syncthreads();
    float Ad[8];
    #pragma unroll
    for (int n = 0; n < 8; n++) Ad[n] = -__expf(A_log[d * 8 + n]);
    float prod[8], hs[8];
    #pragma unroll
    for (int n = 0; n < 8; n++) { prod[n] = 1.0f; hs[n] = 0.0f; }
    for (int lrr = 0; lrr < LC; lrr++) {
        int row = base_row + lrr;
        float dl = delta[(size_t)row * D_INNER + d];
        float uu = bf2f(u[(size_t)row * D_INNER + d]);
        float du = dl * uu;
        #pragma unroll
        for (int n = 0; n < 8; n++) {
            float dA = __expf(dl * Ad[n]);
            prod[n] *= dA;
            hs[n] = dA * hs[n] + du * bc[lrr][n];
        }
    }
    size_t o = ((size_t)((size_t)b * NC + c) * D_INNER + d) * 8;
    #pragma unroll
    for (int n = 0; n < 8; n++) { P[o + n] = prod[n]; S[o + n] = hs[n]; }
}

// ---------------- scan: pass B ----------------
__global__ __launch_bounds__(256) void scan_passB(const float* __restrict__ P,
                                                  const float* __restrict__ S,
                                                  float* __restrict__ hstart) {
    int tid = blockIdx.x * 256 + threadIdx.x;
    int b = tid / (D_INNER * 8);
    int rem = tid % (D_INNER * 8);
    float h = 0.0f;
    for (int c = 0; c < NC; c++) {
        size_t o = (size_t)(b * NC + c) * (D_INNER * 8) + rem;
        hstart[o] = h;
        h = P[o] * h + S[o];
    }
}

// ---------------- scan: pass C -> bf16 ygate ----------------
__global__ __launch_bounds__(256) void scan_passC(const float* __restrict__ delta,
                                                  const unsigned short* __restrict__ u,
                                                  const float* __restrict__ xdbl,
                                                  const float* __restrict__ A_log,
                                                  const float* __restrict__ hstart,
                                                  const unsigned short* __restrict__ xz,
                                                  const float* __restrict__ Dp,
                                                  unsigned short* __restrict__ ygate) {
    int d = blockIdx.x * 256 + threadIdx.x;
    int c = blockIdx.y, b = blockIdx.z;
    __shared__ float bc[LC][16];
    int base_row = b * SEQ + c * LC;
    for (int e = threadIdx.x; e < LC * 16; e += 256) {
        int lrr = e >> 4, col = e & 15;
        bc[lrr][col] = xdbl[(size_t)(base_row + lrr) * XPAD + DT_RANK + col];
    }
    __syncthreads();
    float Ad[8];
    #pragma unroll
    for (int n = 0; n < 8; n++) Ad[n] = -__expf(A_log[d * 8 + n]);
    float h[8];
    size_t ho = ((size_t)((size_t)b * NC + c) * D_INNER + d) * 8;
    #pragma unroll
    for (int n = 0; n < 8; n++) h[n] = hstart[ho + n];
    float Dd = Dp[d];
    for (int lrr = 0; lrr < LC; lrr++) {
        int row = base_row + lrr;
        float dl = delta[(size_t)row * D_INNER + d];
        float uu = bf2f(u[(size_t)row * D_INNER + d]);
        float du = dl * uu;
        float y = 0.0f;
        #pragma unroll
        for (int n = 0; n < 8; n++) {
            float dA = __expf(dl * Ad[n]);
            h[n] = dA * h[n] + du * bc[lrr][n];
            y += h[n] * bc[lrr][8 + n];
        }
        y += uu * Dd;
        float z = bf2f(xz[(size_t)row * (2 * D_INNER) + D_INNER + d]);
        ygate[(size_t)row * D_INNER + d] = f2bf(y * silu_f(z));
    }
}

// ---------------- launch ----------------
extern "C" void kernel_launch(void* const* d_in, const int* in_sizes, int n_in,
                              void* d_out, int out_size, void* d_ws, size_t ws_size,
                              hipStream_t stream) {
    const float* x         = (const float*)d_in[0];
    const float* ln1_g     = (const float*)d_in[1];
    const float* ln1_b     = (const float*)d_in[2];
    const float* ln2_g     = (const float*)d_in[3];
    const float* ln2_b     = (const float*)d_in[4];
    const float* in_proj_w = (const float*)d_in[5];
    const float* conv_w    = (const float*)d_in[6];
    const float* conv_b    = (const float*)d_in[7];
    const float* x_proj_w  = (const float*)d_in[8];
    const float* dt_proj_w = (const float*)d_in[9];
    const float* dt_proj_b = (const float*)d_in[10];
    const float* A_log     = (const float*)d_in[11];
    const float* Dp        = (const float*)d_in[12];
    const float* out_proj_w= (const float*)d_in[13];
    const float* ffn_w1    = (const float*)d_in[14];
    const float* ffn_b1    = (const float*)d_in[15];
    const float* ffn_w2    = (const float*)d_in[16];
    const float* ffn_b2    = (const float*)d_in[17];
    float* out = (float*)d_out;

    // ---- workspace layout ----
    float* xdbl  = (float*)d_ws;                           // 4096*128 f32
    float* delta = xdbl + (size_t)NROWS * XPAD;            // 4096*1536 f32
    float* P     = delta + (size_t)NROWS * D_INNER;
    float* S     = P + (size_t)BATCH * NC * D_INNER * 8;
    float* hst   = S + (size_t)BATCH * NC * D_INNER * 8;
    float* x2    = hst + (size_t)BATCH * NC * D_INNER * 8; // 4096*1024 f32
    float* part  = x2;                                     // overlay: x_proj split-K partials
    unsigned short* xz_bf   = (unsigned short*)(x2 + (size_t)NROWS * D_MODEL); // 4096*3072 bf16
    unsigned short* xp_bf   = xz_bf + (size_t)NROWS * 2 * D_INNER;             // 4096*1024
    unsigned short* u_bf    = xp_bf + (size_t)NROWS * D_MODEL;                 // 4096*1536
    unsigned short* xdbl_bf = u_bf + (size_t)NROWS * D_INNER;                  // 4096*128
    unsigned short* yg_bf   = xdbl_bf + (size_t)NROWS * XPAD;                  // 4096*1536
    unsigned short* w_in    = yg_bf + (size_t)NROWS * D_INNER;                 // 3072*1024
    unsigned short* w_xp    = w_in + (size_t)2 * D_INNER * D_MODEL;            // 128*1536
    unsigned short* w_dt    = w_xp + (size_t)XPAD * D_INNER;                   // 1536*64
    unsigned short* w_out   = w_dt + (size_t)D_INNER * DT_RANK;                // 1024*1536
    unsigned short* w_f1    = w_out + (size_t)D_MODEL * D_INNER;               // 2048*1024
    unsigned short* w_f2    = w_f1 + (size_t)D_FF * D_MODEL;                   // 1024*2048
    unsigned short* hff_bf  = xz_bf;   // overlay: xz dead after scan_passC

    // 0. weight conversions
    wconv<<<4400, 256, 0, stream>>>(in_proj_w, w_in, dt_proj_w, w_dt, out_proj_w, w_out,
                                    ffn_w1, w_f1, ffn_w2, w_f2);
    xproj_pad<<<XPAD, 256, 0, stream>>>(x_proj_w, w_xp);
    // 1. LN1 -> bf16
    ln_kernel<<<NROWS, 256, 0, stream>>>(x, ln1_g, ln1_b, xp_bf);
    // 2. in_proj: xz = xp @ in_proj_w^T  (4096 x 3072, K=1024) -> bf16   [8-phase 256x256]
    gemm8p<4, EPI_BF16><<<dim3(3072 / 256, NROWS / 256), 512, 0, stream>>>(
        xp_bf, D_MODEL, w_in, D_MODEL, D_MODEL, nullptr, xz_bf, 2 * D_INNER, nullptr, nullptr, 0);
    // 3. conv + silu -> u (bf16)
    conv_silu<<<(NROWS * D_INNER) / (256 * 8), 256, 0, stream>>>(xz_bf, conv_w, conv_b, u_bf);
    // 4. x_proj split-K=4 (4096 x 128pad, K=384 each)
    gemm_mfma<EPI_F32, 4><<<dim3(1, NROWS / 128, 4), 256, 0, stream>>>(
        u_bf, D_INNER, w_xp, D_INNER, D_INNER / 4, part, nullptr, XPAD, nullptr, nullptr, 0);
    xdbl_reduce<<<(NROWS * XPAD) / 256, 256, 0, stream>>>(part, xdbl, xdbl_bf);
    // 5. dt_proj + softplus: delta (4096 x 1536, K=64)
    gemm_mfma<EPI_SOFTPLUS, 1><<<dim3(D_INNER / 128, NROWS / 128), 256, 0, stream>>>(
        xdbl_bf, XPAD, w_dt, DT_RANK, DT_RANK, delta, nullptr, D_INNER, dt_proj_b, nullptr, 0);
    // 6-8. selective scan
    scan_passA<<<dim3(D_INNER / 256, NC, BATCH), 256, 0, stream>>>(delta, u_bf, xdbl, A_log, P, S);
    scan_passB<<<(BATCH * D_INNER * 8) / 256, 256, 0, stream>>>(P, S, hst);
    scan_passC<<<dim3(D_INNER / 256, NC, BATCH), 256, 0, stream>>>(delta, u_bf, xdbl, A_log, hst, xz_bf, Dp, yg_bf);
    // 9. out_proj + residual: x2 = ygate @ out_proj_w^T + x  (4096 x 1024, K=1536)  [8-phase 256x128]
    gemm8p<2, EPI_RESID><<<dim3(D_MODEL / 128, NROWS / 256), 512, 0, stream>>>(
        yg_bf, D_INNER, w_out, D_INNER, D_INNER, x2, nullptr, D_MODEL, nullptr, x, D_MODEL);
    // 10. LN2 -> bf16 (reuse xp_bf)
    ln_kernel<<<NROWS, 256, 0, stream>>>(x2, ln2_g, ln2_b, xp_bf);
    // 11. ffn1 + gelu -> bf16 hff  (4096 x 2048, K=1024)  [8-phase 256x128, 256 blocks]
    gemm8p<2, EPI_GELU_BF16><<<dim3(D_FF / 128, NROWS / 256), 512, 0, stream>>>(
        xp_bf, D_MODEL, w_f1, D_MODEL, D_MODEL, nullptr, hff_bf, D_FF, ffn_b1, nullptr, 0);
    // 12. ffn2 + bias + residual: out = x2 + hff @ ffn_w2^T + b2  (4096 x 1024, K=2048)  [8-phase 256x128]
    gemm8p<2, EPI_BIAS_RESID><<<dim3(D_MODEL / 128, NROWS / 256), 512, 0, stream>>>(
        hff_bf, D_FF, w_f2, D_FF, D_FF, out, nullptr, D_MODEL, ffn_b2, x2, D_MODEL);
}

// Round 7
// 290.416 us; speedup vs baseline: 4.3363x; 1.0543x over previous
//
#include <hip/hip_runtime.h>
#include <math.h>

#define D_MODEL 1024
#define D_STATE 8
#define D_CONV  4
#define D_INNER 1536
#define DT_RANK 64
#define D_FF    2048
#define BATCH   2
#define SEQ     2048
#define NROWS   (BATCH*SEQ)      // 4096
#define NC      32               // scan chunks
#define LC      (SEQ/NC)         // 64
#define XPAD    128              // padded x_dbl width (was 80)

typedef short bf16x8 __attribute__((ext_vector_type(8)));
typedef unsigned short u16x8 __attribute__((ext_vector_type(8)));
typedef float f32x4  __attribute__((ext_vector_type(4)));

__device__ inline unsigned short f2bf(float x) {
    union { float f; unsigned u; } v; v.f = x;
    unsigned r = v.u + 0x7fffu + ((v.u >> 16) & 1u);
    return (unsigned short)(r >> 16);
}
__device__ inline float bf2f(unsigned short h) {
    union { unsigned u; float f; } v; v.u = ((unsigned)h) << 16;
    return v.f;
}
__device__ inline float softplus_f(float x) {
    return (x > 20.0f) ? x : log1pf(__expf(x));
}
__device__ inline float gelu_f(float x) {
    return 0.5f * x * (1.0f + erff(x * 0.70710678118654752f));
}
__device__ inline float silu_f(float x) {
    return x / (1.0f + __expf(-x));
}
__device__ inline void gload16(const unsigned short* g, unsigned short* l) {
    typedef unsigned int u32;
    __builtin_amdgcn_global_load_lds(
        (const __attribute__((address_space(1))) u32*)g,
        (__attribute__((address_space(3))) u32*)l, 16, 0, 0);
}

#define PHASE_SYNC_PRE()  do { __builtin_amdgcn_s_barrier(); __builtin_amdgcn_sched_barrier(0); \
                               asm volatile("s_waitcnt lgkmcnt(0)" ::: "memory"); \
                               __builtin_amdgcn_sched_barrier(0); } while (0)
#define PHASE_SYNC_POST() do { __builtin_amdgcn_s_barrier(); __builtin_amdgcn_sched_barrier(0); } while (0)

// ---------------- weight f32 -> bf16 conversion (fused 5 segments) ----------------
__global__ __launch_bounds__(256) void wconv(const float* __restrict__ s0, unsigned short* __restrict__ d0,
                                             const float* __restrict__ s1, unsigned short* __restrict__ d1,
                                             const float* __restrict__ s2, unsigned short* __restrict__ d2,
                                             const float* __restrict__ s3, unsigned short* __restrict__ d3,
                                             const float* __restrict__ s4, unsigned short* __restrict__ d4) {
    int b = blockIdx.x;
    const float* s; unsigned short* d; int base;
    if      (b < 1536) { s = s0; d = d0; base = b * 2048; }
    else if (b < 1584) { s = s1; d = d1; base = (b - 1536) * 2048; }
    else if (b < 2352) { s = s2; d = d2; base = (b - 1584) * 2048; }
    else if (b < 3376) { s = s3; d = d3; base = (b - 2352) * 2048; }
    else               { s = s4; d = d4; base = (b - 3376) * 2048; }
    int i = base + threadIdx.x * 8;
    float4 v0 = *(const float4*)(s + i);
    float4 v1 = *(const float4*)(s + i + 4);
    ushort4 a, c;
    a.x = f2bf(v0.x); a.y = f2bf(v0.y); a.z = f2bf(v0.z); a.w = f2bf(v0.w);
    c.x = f2bf(v1.x); c.y = f2bf(v1.y); c.z = f2bf(v1.z); c.w = f2bf(v1.w);
    *(ushort4*)(d + i)     = a;
    *(ushort4*)(d + i + 4) = c;
}

// x_proj_w [80][1536] -> padded bf16 [128][1536]
__global__ __launch_bounds__(256) void xproj_pad(const float* __restrict__ src, unsigned short* __restrict__ dst) {
    int row = blockIdx.x;
    for (int c = threadIdx.x; c < D_INNER; c += 256)
        dst[row * D_INNER + c] = (row < 80) ? f2bf(src[row * D_INNER + c]) : (unsigned short)0;
}

// ---------------- LayerNorm -> bf16 ----------------
__global__ __launch_bounds__(256) void ln_kernel(const float* __restrict__ x,
                                                 const float* __restrict__ g,
                                                 const float* __restrict__ b,
                                                 unsigned short* __restrict__ out) {
    __shared__ float sbuf[4];
    int row = blockIdx.x;
    int t = threadIdx.x;
    const float4* xr = (const float4*)(x + (size_t)row * D_MODEL);
    float4 v = xr[t];
    float s = v.x + v.y + v.z + v.w;
    for (int o = 32; o; o >>= 1) s += __shfl_down(s, o, 64);
    if ((t & 63) == 0) sbuf[t >> 6] = s;
    __syncthreads();
    float mu = (sbuf[0] + sbuf[1] + sbuf[2] + sbuf[3]) * (1.0f / D_MODEL);
    __syncthreads();
    float d0 = v.x - mu, d1 = v.y - mu, d2 = v.z - mu, d3 = v.w - mu;
    float q = d0*d0 + d1*d1 + d2*d2 + d3*d3;
    for (int o = 32; o; o >>= 1) q += __shfl_down(q, o, 64);
    if ((t & 63) == 0) sbuf[t >> 6] = q;
    __syncthreads();
    float var = (sbuf[0] + sbuf[1] + sbuf[2] + sbuf[3]) * (1.0f / D_MODEL);
    float rs = rsqrtf(var + 1e-5f);
    float4 gv = ((const float4*)g)[t];
    float4 bv = ((const float4*)b)[t];
    ushort4 st;
    st.x = f2bf(d0 * rs * gv.x + bv.x);
    st.y = f2bf(d1 * rs * gv.y + bv.y);
    st.z = f2bf(d2 * rs * gv.z + bv.z);
    st.w = f2bf(d3 * rs * gv.w + bv.w);
    ((ushort4*)(out + (size_t)row * D_MODEL))[t] = st;
}

// ---------------- epilogue IDs ----------------
#define EPI_F32        0   // Cf = acc
#define EPI_F32_BF16   1   // Cf = acc, Cb = bf16(acc)
#define EPI_SOFTPLUS   2   // Cf = softplus(acc + bias)
#define EPI_RESID      3   // Cf = acc + resid
#define EPI_GELU_BF16  4   // Cb = bf16(gelu(acc + bias))
#define EPI_BIAS_RESID 5   // Cf = acc + bias + resid
#define EPI_BF16       6   // Cb = bf16(acc)

// ================= 8-phase 256-row MFMA GEMM (NT) =================
// BM=256, BN=WN*64, BK=64, 8 waves, involution LDS swizzle byte^=(row&7)<<4
// (linear dest + inverse-swizzled global src + swizzled ds_read), counted
// vmcnt at phases 4/8 only, setprio around MFMA, XCD-aware block swizzle.
template<int WN, int EPI, int SPLITK>
__global__ __launch_bounds__(512, 2) void gemm8p(
    const unsigned short* __restrict__ A, int lda,
    const unsigned short* __restrict__ Bm, int ldb, int K,   // K = per-split length
    float* __restrict__ Cf, unsigned short* __restrict__ Cb, int ldc,
    const float* __restrict__ bias,
    const float* __restrict__ resid, int ldr) {
    constexpr int WM = 8 / WN;            // 2 or 4
    constexpr int BN = WN * 64;           // 256 or 128
    constexpr int RW = 256 / WM;          // per-wave rows: 128 or 64
    constexpr int CW = 64;                // per-wave cols
    constexpr int MI = RW / 16;           // 8 or 4
    constexpr int NI = CW / 16;           // 4
    constexpr int MIH = MI / 2, NIH = NI / 2;
    constexpr int ABYTES = 256 * 128;     // 32 KB per A K-tile
    constexpr int BBYTES = BN * 128;      // 32 or 16 KB per B K-tile
    constexpr int BOFF = 2 * ABYTES;
    __shared__ unsigned short lds[(2 * ABYTES + 2 * BBYTES) / 2];

    const int t = threadIdx.x, l = t & 63, w = t >> 6;
    const int wr = w / WN, wc = w % WN;

    const int nx = gridDim.x;
    const int nwg = nx * gridDim.y;
    int bid = blockIdx.y * nx + blockIdx.x;
    int q = nwg >> 3;
    int swz = (bid & 7) * q + (bid >> 3);
    const int m0 = (swz / nx) * 256, n0 = (swz % nx) * BN;
    const int kbase = (SPLITK > 1) ? blockIdx.z * K : 0;

    // staging lane constants: inverse-swizzled source column (involution):
    // LDS[r][d] = G[r][d ^ ((r&7)<<4)];  lane l -> (row=l>>3, destbyte=(l&7)*16)
    const int sr = l >> 3;
    const int sj = ((l & 7) * 16) ^ ((l >> 3) << 4);
    const int row_l = w * 8;                                 // linear 64-row quarter
    const int row_c = (w >> 2) * 64 + (w & 3) * 8;           // chunked {0-31,64-95}

    auto STG = [&](int bufbyte, int rowbase, const unsigned short* G, int ldg, int gbase, int kt) {
        unsigned short* dst = (unsigned short*)((char*)lds + bufbyte + rowbase * 128);
        const unsigned short* src = G + (size_t)(gbase + rowbase + sr) * ldg + kbase + kt * 64 + (sj >> 1);
        gload16(src, dst);
    };
    auto S_Ah0 = [&](int b, int kt) {
        if (WN == 4) { STG(b * ABYTES, row_l, A, lda, m0, kt);       STG(b * ABYTES, 128 + row_l, A, lda, m0, kt); }
        else         { STG(b * ABYTES, row_c, A, lda, m0, kt);       STG(b * ABYTES, 128 + row_c, A, lda, m0, kt); }
    };
    auto S_Ah1 = [&](int b, int kt) {
        if (WN == 4) { STG(b * ABYTES, 64 + row_l, A, lda, m0, kt);  STG(b * ABYTES, 192 + row_l, A, lda, m0, kt); }
        else         { STG(b * ABYTES, 32 + row_c, A, lda, m0, kt);  STG(b * ABYTES, 160 + row_c, A, lda, m0, kt); }
    };
    auto S_Bc0 = [&](int b, int kt) {
        if (WN == 4) { STG(BOFF + b * BBYTES, row_c, Bm, ldb, n0, kt); STG(BOFF + b * BBYTES, 128 + row_c, Bm, ldb, n0, kt); }
        else         { STG(BOFF + b * BBYTES, row_c, Bm, ldb, n0, kt); }
    };
    auto S_Bc1 = [&](int b, int kt) {
        if (WN == 4) { STG(BOFF + b * BBYTES, 32 + row_c, Bm, ldb, n0, kt); STG(BOFF + b * BBYTES, 160 + row_c, Bm, ldb, n0, kt); }
        else         { STG(BOFF + b * BBYTES, 32 + row_c, Bm, ldb, n0, kt); }
    };

    // swizzled ds_read of one bf16x8 fragment (involution on byte-in-row)
    auto LD = [&](int bytebase, int row, int kb) -> bf16x8 {
        int o = bytebase + row * 128 + (kb ^ ((row & 7) << 4));
        return *(const bf16x8*)((const char*)lds + o);
    };

    f32x4 acc[MI][NI] = {};
    bf16x8 af[MIH][2], b0v[NIH][2], b1v[NIH][2];

    auto LDA_set = [&](int buf, int qr, auto& dst) {
        #pragma unroll
        for (int mi = 0; mi < MIH; mi++)
            #pragma unroll
            for (int ks = 0; ks < 2; ks++)
                dst[mi][ks] = LD(buf * ABYTES, wr * RW + qr * (RW / 2) + mi * 16 + (l & 15),
                                 ks * 64 + (l >> 4) * 16);
    };
    auto LDB_set = [&](int buf, int qc, auto& dst) {
        #pragma unroll
        for (int ni2 = 0; ni2 < NIH; ni2++)
            #pragma unroll
            for (int ks = 0; ks < 2; ks++)
                dst[ni2][ks] = LD(BOFF + buf * BBYTES, wc * CW + qc * 32 + ni2 * 16 + (l & 15),
                                  ks * 64 + (l >> 4) * 16);
    };
    auto MFMA_Q = [&](int qr, int qc, auto& a_, auto& b_) {
        __builtin_amdgcn_s_setprio(1);
        #pragma unroll
        for (int mi = 0; mi < MIH; mi++)
            #pragma unroll
            for (int ni2 = 0; ni2 < NIH; ni2++)
                #pragma unroll
                for (int ks = 0; ks < 2; ks++)
                    acc[qr * MIH + mi][qc * NIH + ni2] =
                        __builtin_amdgcn_mfma_f32_16x16x32_bf16(a_[mi][ks], b_[ni2][ks],
                                                                acc[qr * MIH + mi][qc * NIH + ni2], 0, 0, 0);
        __builtin_amdgcn_s_setprio(0);
    };
    auto VMW = [&](bool last) {
        if (last)            asm volatile("s_waitcnt vmcnt(0)" ::: "memory");
        else if (WN == 4)    asm volatile("s_waitcnt vmcnt(6)" ::: "memory");
        else                 asm volatile("s_waitcnt vmcnt(5)" ::: "memory");
        __builtin_amdgcn_sched_barrier(0);
    };

    const int ni_ = K >> 7;    // iterations; 2 K-tiles (of 64) per iter

    // prologue: stage tiles 0,1 fully; wait for tile 0
    S_Ah0(0, 0); S_Ah1(0, 0); S_Bc0(0, 0); S_Bc1(0, 0);
    S_Ah0(1, 1); S_Ah1(1, 1); S_Bc0(1, 1); S_Bc1(1, 1);
    if (WN == 4) asm volatile("s_waitcnt vmcnt(8)" ::: "memory");
    else         asm volatile("s_waitcnt vmcnt(6)" ::: "memory");
    __builtin_amdgcn_s_barrier();
    __builtin_amdgcn_sched_barrier(0);

    for (int i = 0; i < ni_; i++) {
        const bool last = (i == ni_ - 1);
        const int t2 = 2 * i + 2, t3 = 2 * i + 3;
        // phase 1: buf0 q(0,0)
        LDA_set(0, 0, af); LDB_set(0, 0, b0v);
        if (i) S_Bc0(1, 2 * i + 1);
        PHASE_SYNC_PRE(); MFMA_Q(0, 0, af, b0v); PHASE_SYNC_POST();
        // phase 2: buf0 q(0,1)
        LDB_set(0, 1, b1v);
        if (!last) S_Ah0(0, t2);
        PHASE_SYNC_PRE(); MFMA_Q(0, 1, af, b1v); PHASE_SYNC_POST();
        // phase 3: buf0 q(1,1)
        LDA_set(0, 1, af);
        PHASE_SYNC_PRE(); MFMA_Q(1, 1, af, b1v); PHASE_SYNC_POST();
        // phase 4: buf0 q(1,0)
        LDB_set(0, 0, b0v);
        if (!last) { S_Ah1(0, t2); S_Bc1(0, t2); }
        VMW(last);
        PHASE_SYNC_PRE(); MFMA_Q(1, 0, af, b0v); PHASE_SYNC_POST();
        // phase 5: buf1 q(0,0)
        LDA_set(1, 0, af); LDB_set(1, 0, b0v);
        if (!last) S_Bc0(0, t2);
        PHASE_SYNC_PRE(); MFMA_Q(0, 0, af, b0v); PHASE_SYNC_POST();
        // phase 6: buf1 q(0,1)
        LDB_set(1, 1, b1v);
        if (!last) S_Ah0(1, t3);
        PHASE_SYNC_PRE(); MFMA_Q(0, 1, af, b1v); PHASE_SYNC_POST();
        // phase 7: buf1 q(1,1)
        LDA_set(1, 1, af);
        PHASE_SYNC_PRE(); MFMA_Q(1, 1, af, b1v); PHASE_SYNC_POST();
        // phase 8: buf1 q(1,0)
        LDB_set(1, 0, b0v);
        if (!last) { S_Ah1(1, t3); S_Bc1(1, t3); }
        VMW(last);
        PHASE_SYNC_PRE(); MFMA_Q(1, 0, af, b0v); PHASE_SYNC_POST();
    }

    // epilogue: D layout col=lane&15, row=(lane>>4)*4+j  [m89 verified]
    float* Cfp = Cf;
    if (SPLITK > 1) Cfp += (size_t)blockIdx.z * NROWS * ldc;
    #pragma unroll
    for (int ni2 = 0; ni2 < NI; ni2++) {
        int col = n0 + wc * CW + ni2 * 16 + (l & 15);
        float bv = 0.0f;
        if (EPI == EPI_SOFTPLUS || EPI == EPI_GELU_BF16 || EPI == EPI_BIAS_RESID) bv = bias[col];
        #pragma unroll
        for (int mi = 0; mi < MI; mi++) {
            #pragma unroll
            for (int j = 0; j < 4; j++) {
                int row = m0 + wr * RW + mi * 16 + (l >> 4) * 4 + j;
                float v = acc[mi][ni2][j];
                if (EPI == EPI_SOFTPLUS)        v = softplus_f(v + bv);
                else if (EPI == EPI_GELU_BF16)  v = gelu_f(v + bv);
                else if (EPI == EPI_RESID)      v = v + resid[(size_t)row * ldr + col];
                else if (EPI == EPI_BIAS_RESID) v = v + bv + resid[(size_t)row * ldr + col];
                if (EPI == EPI_GELU_BF16 || EPI == EPI_BF16) {
                    Cb[(size_t)row * ldc + col] = f2bf(v);
                } else {
                    Cfp[(size_t)row * ldc + col] = v;
                    if (EPI == EPI_F32_BF16) Cb[(size_t)row * ldc + col] = f2bf(v);
                }
            }
        }
    }
}

// ---------------- split-K=2 reduce with fused epilogue ----------------
template<int WITH_BIAS>
__global__ __launch_bounds__(256) void sk2_reduce(const float* __restrict__ p,
                                                  const float* __restrict__ bias,
                                                  const float* __restrict__ resid,
                                                  float* __restrict__ o) {
    int i = (blockIdx.x * 256 + threadIdx.x) * 4;
    const size_t seg = (size_t)NROWS * D_MODEL;
    float4 a = *(const float4*)(p + i);
    float4 b = *(const float4*)(p + i + seg);
    float4 r = *(const float4*)(resid + i);
    float4 o4;
    if (WITH_BIAS) {
        float4 bb = *(const float4*)(bias + (i & (D_MODEL - 1)));
        o4.x = a.x + b.x + r.x + bb.x;
        o4.y = a.y + b.y + r.y + bb.y;
        o4.z = a.z + b.z + r.z + bb.z;
        o4.w = a.w + b.w + r.w + bb.w;
    } else {
        o4.x = a.x + b.x + r.x;
        o4.y = a.y + b.y + r.y;
        o4.z = a.z + b.z + r.z;
        o4.w = a.w + b.w + r.w;
    }
    *(float4*)(o + i) = o4;
}

// ---------------- small-GEMM path (x_proj, dt_proj): 128x128, 3-buf ----------------
template<int EPI, int SPLITK>
__global__ __launch_bounds__(256) void gemm_mfma(
    const unsigned short* __restrict__ A, int lda,
    const unsigned short* __restrict__ B, int ldb, int K,
    float* __restrict__ Cf, unsigned short* __restrict__ Cb, int ldc,
    const float* __restrict__ bias,
    const float* __restrict__ resid, int ldr) {
    __shared__ unsigned short As[3][128 * 32];
    __shared__ unsigned short Bs[3][128 * 32];
    int t = threadIdx.x, l = t & 63, w = t >> 6;
    int nx = gridDim.x;
    int nwg = nx * gridDim.y;
    int bid = blockIdx.y * nx + blockIdx.x;
    int q = nwg >> 3;
    int swz = (bid & 7) * q + (bid >> 3);
    int m0 = (swz / nx) * 128, n0 = (swz % nx) * 128;
    int kbase = (SPLITK > 1) ? blockIdx.z * K : 0;
    int c0 = 2 * w, c1 = 2 * w + 1;
    int srow = l >> 2, scol = (l & 3) * 8;
    const unsigned short* Ag0 = A + (size_t)(m0 + 16 * c0 + srow) * lda + kbase + scol;
    const unsigned short* Ag1 = A + (size_t)(m0 + 16 * c1 + srow) * lda + kbase + scol;
    const unsigned short* Bg0 = B + (size_t)(n0 + 16 * c0 + srow) * ldb + kbase + scol;
    const unsigned short* Bg1 = B + (size_t)(n0 + 16 * c1 + srow) * ldb + kbase + scol;
    int wr = w >> 1, wc = w & 1;
    int aoff = (wr * 64 + (l & 15)) * 32 + (l >> 4) * 8;
    int boff = (wc * 64 + (l & 15)) * 32 + (l >> 4) * 8;

    f32x4 acc[4][4] = {};
    int nt = K >> 5;

    gload16(Ag0, &As[0][c0 * 512]);
    gload16(Ag1, &As[0][c1 * 512]);
    gload16(Bg0, &Bs[0][c0 * 512]);
    gload16(Bg1, &Bs[0][c1 * 512]);
    if (nt > 1) {
        gload16(Ag0 + 32, &As[1][c0 * 512]);
        gload16(Ag1 + 32, &As[1][c1 * 512]);
        gload16(Bg0 + 32, &Bs[1][c0 * 512]);
        gload16(Bg1 + 32, &Bs[1][c1 * 512]);
    }

    int cur = 0;
    for (int ti = 0; ti < nt; ti++) {
        int pf = ti + 2;
        if (pf < nt) {
            int nb = cur - 1; if (nb < 0) nb += 3;
            int k0 = pf << 5;
            gload16(Ag0 + k0, &As[nb][c0 * 512]);
            gload16(Ag1 + k0, &As[nb][c1 * 512]);
            gload16(Bg0 + k0, &Bs[nb][c0 * 512]);
            gload16(Bg1 + k0, &Bs[nb][c1 * 512]);
        }
        int rem = nt - 1 - ti;
        if (rem >= 2)      asm volatile("s_waitcnt vmcnt(8)" ::: "memory");
        else if (rem == 1) asm volatile("s_waitcnt vmcnt(4)" ::: "memory");
        else               asm volatile("s_waitcnt vmcnt(0)" ::: "memory");
        __builtin_amdgcn_s_barrier();

        const unsigned short* Ab = &As[cur][0];
        const unsigned short* Bb = &Bs[cur][0];
        bf16x8 af[4], bfv[4];
        #pragma unroll
        for (int i = 0; i < 4; i++) af[i] = *(const bf16x8*)(Ab + aoff + i * 512);
        #pragma unroll
        for (int i = 0; i < 4; i++) bfv[i] = *(const bf16x8*)(Bb + boff + i * 512);
        __builtin_amdgcn_s_setprio(1);
        #pragma unroll
        for (int mi = 0; mi < 4; mi++)
            #pragma unroll
            for (int ni = 0; ni < 4; ni++)
                acc[mi][ni] = __builtin_amdgcn_mfma_f32_16x16x32_bf16(af[mi], bfv[ni], acc[mi][ni], 0, 0, 0);
        __builtin_amdgcn_s_setprio(0);
        __builtin_amdgcn_s_barrier();
        cur++; if (cur == 3) cur = 0;
    }

    if (SPLITK > 1) Cf += (size_t)blockIdx.z * NROWS * ldc;
    int colb = n0 + wc * 64 + (l & 15);
    int rowb = m0 + wr * 64 + (l >> 4) * 4;
    #pragma unroll
    for (int ni = 0; ni < 4; ni++) {
        int col = colb + ni * 16;
        float bv = 0.0f;
        if (EPI == EPI_SOFTPLUS || EPI == EPI_GELU_BF16 || EPI == EPI_BIAS_RESID) bv = bias[col];
        #pragma unroll
        for (int mi = 0; mi < 4; mi++) {
            #pragma unroll
            for (int j = 0; j < 4; j++) {
                int row = rowb + mi * 16 + j;
                float v = acc[mi][ni][j];
                if (EPI == EPI_SOFTPLUS)        v = softplus_f(v + bv);
                else if (EPI == EPI_GELU_BF16)  v = gelu_f(v + bv);
                else if (EPI == EPI_RESID)      v = v + resid[(size_t)row * ldr + col];
                else if (EPI == EPI_BIAS_RESID) v = v + bv + resid[(size_t)row * ldr + col];
                if (EPI == EPI_GELU_BF16 || EPI == EPI_BF16) {
                    Cb[(size_t)row * ldc + col] = f2bf(v);
                } else {
                    Cf[(size_t)row * ldc + col] = v;
                    if (EPI == EPI_F32_BF16) Cb[(size_t)row * ldc + col] = f2bf(v);
                }
            }
        }
    }
}

// ---------------- x_proj split-K partial reduce ----------------
__global__ __launch_bounds__(256) void xdbl_reduce(const float* __restrict__ part,
                                                   float* __restrict__ xdbl,
                                                   unsigned short* __restrict__ xdbl_bf) {
    int i = blockIdx.x * 256 + threadIdx.x;
    const size_t seg = (size_t)NROWS * XPAD;
    float s = part[i] + part[i + seg] + part[i + 2 * seg] + part[i + 3 * seg];
    xdbl[i] = s;
    xdbl_bf[i] = f2bf(s);
}

// ---------------- causal depthwise conv (k=4) + SiLU -> bf16 u (8-wide) ----------------
__global__ __launch_bounds__(256) void conv_silu(const unsigned short* __restrict__ xz,
                                                 const float* __restrict__ w,
                                                 const float* __restrict__ cb,
                                                 unsigned short* __restrict__ u) {
    int idx = (blockIdx.x * 256 + threadIdx.x) * 8;
    int d = idx % D_INNER;
    int bl = idx / D_INNER;
    int l = bl & (SEQ - 1);
    float acc[8];
    float4 wv[8];
    #pragma unroll
    for (int j = 0; j < 8; j++) wv[j] = *(const float4*)(w + (d + j) * 4);
    float4 cb0 = *(const float4*)(cb + d);
    float4 cb1 = *(const float4*)(cb + d + 4);
    acc[0] = cb0.x; acc[1] = cb0.y; acc[2] = cb0.z; acc[3] = cb0.w;
    acc[4] = cb1.x; acc[5] = cb1.y; acc[6] = cb1.z; acc[7] = cb1.w;
    #pragma unroll
    for (int k = 0; k < 4; k++) {
        int lp = l - 3 + k;
        if (lp >= 0) {
            u16x8 s = *(const u16x8*)(xz + (size_t)(bl - 3 + k) * (2 * D_INNER) + d);
            #pragma unroll
            for (int j = 0; j < 8; j++) {
                float wk = (k == 0) ? wv[j].x : (k == 1) ? wv[j].y : (k == 2) ? wv[j].z : wv[j].w;
                acc[j] += bf2f((unsigned short)s[j]) * wk;
            }
        }
    }
    u16x8 o;
    #pragma unroll
    for (int j = 0; j < 8; j++) o[j] = f2bf(silu_f(acc[j]));
    *(u16x8*)(u + idx) = o;
}

// ---------------- selective scan: pass A ----------------
__global__ __launch_bounds__(256) void scan_passA(const float* __restrict__ delta,
                                                  const unsigned short* __restrict__ u,
                                                  const float* __restrict__ xdbl,
                                                  const float* __restrict__ A_log,
                                                  float* __restrict__ P,
                                                  float* __restrict__ S) {
    int d = blockIdx.x * 256 + threadIdx.x;
    int c = blockIdx.y, b = blockIdx.z;
    __shared__ float bc[LC][16];
    int base_row = b * SEQ + c * LC;
    for (int e = threadIdx.x; e < LC * 16; e += 256) {
        int lrr = e >> 4, col = e & 15;
        bc[lrr][col] = xdbl[(size_t)(base_row + lrr) * XPAD + DT_RANK + col];
    }
    __syncthreads();
    float Ad[8];
    #pragma unroll
    for (int n = 0; n < 8; n++) Ad[n] = -__expf(A_log[d * 8 + n]);
    float prod[8], hs[8];
    #pragma unroll
    for (int n = 0; n < 8; n++) { prod[n] = 1.0f; hs[n] = 0.0f; }
    for (int lrr = 0; lrr < LC; lrr++) {
        int row = base_row + lrr;
        float dl = delta[(size_t)row * D_INNER + d];
        float uu = bf2f(u[(size_t)row * D_INNER + d]);
        float du = dl * uu;
        #pragma unroll
        for (int n = 0; n < 8; n++) {
            float dA = __expf(dl * Ad[n]);
            prod[n] *= dA;
            hs[n] = dA * hs[n] + du * bc[lrr][n];
        }
    }
    size_t o = ((size_t)((size_t)b * NC + c) * D_INNER + d) * 8;
    #pragma unroll
    for (int n = 0; n < 8; n++) { P[o + n] = prod[n]; S[o + n] = hs[n]; }
}

// ---------------- scan: pass B ----------------
__global__ __launch_bounds__(256) void scan_passB(const float* __restrict__ P,
                                                  const float* __restrict__ S,
                                                  float* __restrict__ hstart) {
    int tid = blockIdx.x * 256 + threadIdx.x;
    int b = tid / (D_INNER * 8);
    int rem = tid % (D_INNER * 8);
    float h = 0.0f;
    for (int c = 0; c < NC; c++) {
        size_t o = (size_t)(b * NC + c) * (D_INNER * 8) + rem;
        hstart[o] = h;
        h = P[o] * h + S[o];
    }
}

// ---------------- scan: pass C -> bf16 ygate ----------------
__global__ __launch_bounds__(256) void scan_passC(const float* __restrict__ delta,
                                                  const unsigned short* __restrict__ u,
                                                  const float* __restrict__ xdbl,
                                                  const float* __restrict__ A_log,
                                                  const float* __restrict__ hstart,
                                                  const unsigned short* __restrict__ xz,
                                                  const float* __restrict__ Dp,
                                                  unsigned short* __restrict__ ygate) {
    int d = blockIdx.x * 256 + threadIdx.x;
    int c = blockIdx.y, b = blockIdx.z;
    __shared__ float bc[LC][16];
    int base_row = b * SEQ + c * LC;
    for (int e = threadIdx.x; e < LC * 16; e += 256) {
        int lrr = e >> 4, col = e & 15;
        bc[lrr][col] = xdbl[(size_t)(base_row + lrr) * XPAD + DT_RANK + col];
    }
    __syncthreads();
    float Ad[8];
    #pragma unroll
    for (int n = 0; n < 8; n++) Ad[n] = -__expf(A_log[d * 8 + n]);
    float h[8];
    size_t ho = ((size_t)((size_t)b * NC + c) * D_INNER + d) * 8;
    #pragma unroll
    for (int n = 0; n < 8; n++) h[n] = hstart[ho + n];
    float Dd = Dp[d];
    for (int lrr = 0; lrr < LC; lrr++) {
        int row = base_row + lrr;
        float dl = delta[(size_t)row * D_INNER + d];
        float uu = bf2f(u[(size_t)row * D_INNER + d]);
        float du = dl * uu;
        float y = 0.0f;
        #pragma unroll
        for (int n = 0; n < 8; n++) {
            float dA = __expf(dl * Ad[n]);
            h[n] = dA * h[n] + du * bc[lrr][n];
            y += h[n] * bc[lrr][8 + n];
        }
        y += uu * Dd;
        float z = bf2f(xz[(size_t)row * (2 * D_INNER) + D_INNER + d]);
        ygate[(size_t)row * D_INNER + d] = f2bf(y * silu_f(z));
    }
}

// ---------------- launch ----------------
extern "C" void kernel_launch(void* const* d_in, const int* in_sizes, int n_in,
                              void* d_out, int out_size, void* d_ws, size_t ws_size,
                              hipStream_t stream) {
    const float* x         = (const float*)d_in[0];
    const float* ln1_g     = (const float*)d_in[1];
    const float* ln1_b     = (const float*)d_in[2];
    const float* ln2_g     = (const float*)d_in[3];
    const float* ln2_b     = (const float*)d_in[4];
    const float* in_proj_w = (const float*)d_in[5];
    const float* conv_w    = (const float*)d_in[6];
    const float* conv_b    = (const float*)d_in[7];
    const float* x_proj_w  = (const float*)d_in[8];
    const float* dt_proj_w = (const float*)d_in[9];
    const float* dt_proj_b = (const float*)d_in[10];
    const float* A_log     = (const float*)d_in[11];
    const float* Dp        = (const float*)d_in[12];
    const float* out_proj_w= (const float*)d_in[13];
    const float* ffn_w1    = (const float*)d_in[14];
    const float* ffn_b1    = (const float*)d_in[15];
    const float* ffn_w2    = (const float*)d_in[16];
    const float* ffn_b2    = (const float*)d_in[17];
    float* out = (float*)d_out;

    // ---- workspace layout ----
    float* xdbl  = (float*)d_ws;                           // 4096*128 f32
    float* delta = xdbl + (size_t)NROWS * XPAD;            // 4096*1536 f32
    float* P     = delta + (size_t)NROWS * D_INNER;
    float* S     = P + (size_t)BATCH * NC * D_INNER * 8;
    float* hst   = S + (size_t)BATCH * NC * D_INNER * 8;
    float* x2    = hst + (size_t)BATCH * NC * D_INNER * 8; // 4096*1024 f32
    float* part  = x2;                                     // overlay: x_proj split-K partials (dead before out_proj)
    float* psum  = delta;                                  // overlay: split-K=2 partials (2*4096*1024 f32 spans delta..hst, dead after scan)
    unsigned short* xz_bf   = (unsigned short*)(x2 + (size_t)NROWS * D_MODEL); // 4096*3072 bf16
    unsigned short* xp_bf   = xz_bf + (size_t)NROWS * 2 * D_INNER;             // 4096*1024
    unsigned short* u_bf    = xp_bf + (size_t)NROWS * D_MODEL;                 // 4096*1536
    unsigned short* xdbl_bf = u_bf + (size_t)NROWS * D_INNER;                  // 4096*128
    unsigned short* yg_bf   = xdbl_bf + (size_t)NROWS * XPAD;                  // 4096*1536
    unsigned short* w_in    = yg_bf + (size_t)NROWS * D_INNER;                 // 3072*1024
    unsigned short* w_xp    = w_in + (size_t)2 * D_INNER * D_MODEL;            // 128*1536
    unsigned short* w_dt    = w_xp + (size_t)XPAD * D_INNER;                   // 1536*64
    unsigned short* w_out   = w_dt + (size_t)D_INNER * DT_RANK;                // 1024*1536
    unsigned short* w_f1    = w_out + (size_t)D_MODEL * D_INNER;               // 2048*1024
    unsigned short* w_f2    = w_f1 + (size_t)D_FF * D_MODEL;                   // 1024*2048
    unsigned short* hff_bf  = xz_bf;   // overlay: xz dead after scan_passC

    // 0. weight conversions
    wconv<<<4400, 256, 0, stream>>>(in_proj_w, w_in, dt_proj_w, w_dt, out_proj_w, w_out,
                                    ffn_w1, w_f1, ffn_w2, w_f2);
    xproj_pad<<<XPAD, 256, 0, stream>>>(x_proj_w, w_xp);
    // 1. LN1 -> bf16
    ln_kernel<<<NROWS, 256, 0, stream>>>(x, ln1_g, ln1_b, xp_bf);
    // 2. in_proj: xz = xp @ in_proj_w^T  (4096 x 3072, K=1024) -> bf16   [8-phase 256x256]
    gemm8p<4, EPI_BF16, 1><<<dim3(3072 / 256, NROWS / 256), 512, 0, stream>>>(
        xp_bf, D_MODEL, w_in, D_MODEL, D_MODEL, nullptr, xz_bf, 2 * D_INNER, nullptr, nullptr, 0);
    // 3. conv + silu -> u (bf16)
    conv_silu<<<(NROWS * D_INNER) / (256 * 8), 256, 0, stream>>>(xz_bf, conv_w, conv_b, u_bf);
    // 4. x_proj split-K=4 (4096 x 128pad, K=384 each)
    gemm_mfma<EPI_F32, 4><<<dim3(1, NROWS / 128, 4), 256, 0, stream>>>(
        u_bf, D_INNER, w_xp, D_INNER, D_INNER / 4, part, nullptr, XPAD, nullptr, nullptr, 0);
    xdbl_reduce<<<(NROWS * XPAD) / 256, 256, 0, stream>>>(part, xdbl, xdbl_bf);
    // 5. dt_proj + softplus: delta (4096 x 1536, K=64)
    gemm_mfma<EPI_SOFTPLUS, 1><<<dim3(D_INNER / 128, NROWS / 128), 256, 0, stream>>>(
        xdbl_bf, XPAD, w_dt, DT_RANK, DT_RANK, delta, nullptr, D_INNER, dt_proj_b, nullptr, 0);
    // 6-8. selective scan
    scan_passA<<<dim3(D_INNER / 256, NC, BATCH), 256, 0, stream>>>(delta, u_bf, xdbl, A_log, P, S);
    scan_passB<<<(BATCH * D_INNER * 8) / 256, 256, 0, stream>>>(P, S, hst);
    scan_passC<<<dim3(D_INNER / 256, NC, BATCH), 256, 0, stream>>>(delta, u_bf, xdbl, A_log, hst, xz_bf, Dp, yg_bf);
    // 9. out_proj split-K=2: psum = ygate @ out_proj_w^T  (4096 x 1024, K=768 each)  [8-phase 256x128, 256 blocks]
    gemm8p<2, EPI_F32, 2><<<dim3(D_MODEL / 128, NROWS / 256, 2), 512, 0, stream>>>(
        yg_bf, D_INNER, w_out, D_INNER, D_INNER / 2, psum, nullptr, D_MODEL, nullptr, nullptr, 0);
    sk2_reduce<0><<<(NROWS * D_MODEL) / 1024, 256, 0, stream>>>(psum, nullptr, x, x2);
    // 10. LN2 -> bf16 (reuse xp_bf)
    ln_kernel<<<NROWS, 256, 0, stream>>>(x2, ln2_g, ln2_b, xp_bf);
    // 11. ffn1 + gelu -> bf16 hff  (4096 x 2048, K=1024)  [8-phase 256x128, 256 blocks]
    gemm8p<2, EPI_GELU_BF16, 1><<<dim3(D_FF / 128, NROWS / 256), 512, 0, stream>>>(
        xp_bf, D_MODEL, w_f1, D_MODEL, D_MODEL, nullptr, hff_bf, D_FF, ffn_b1, nullptr, 0);
    // 12. ffn2 split-K=2: psum = hff @ ffn_w2^T  (4096 x 1024, K=1024 each)  [8-phase 256x128, 256 blocks]
    gemm8p<2, EPI_F32, 2><<<dim3(D_MODEL / 128, NROWS / 256, 2), 512, 0, stream>>>(
        hff_bf, D_FF, w_f2, D_FF, D_FF / 2, psum, nullptr, D_MODEL, nullptr, nullptr, 0);
    sk2_reduce<1><<<(NROWS * D_MODEL) / 1024, 256, 0, stream>>>(psum, ffn_b2, x2, out);
}

// Round 8
// 281.131 us; speedup vs baseline: 4.4796x; 1.0330x over previous
//
#include <hip/hip_runtime.h>
#include <math.h>

#define D_MODEL 1024
#define D_STATE 8
#define D_CONV  4
#define D_INNER 1536
#define DT_RANK 64
#define D_FF    2048
#define BATCH   2
#define SEQ     2048
#define NROWS   (BATCH*SEQ)      // 4096
#define NC      32               // scan chunks
#define LC      (SEQ/NC)         // 64
#define XPAD    128              // padded x_dbl width (was 80)

typedef short bf16x8 __attribute__((ext_vector_type(8)));
typedef unsigned short u16x8 __attribute__((ext_vector_type(8)));
typedef float f32x4  __attribute__((ext_vector_type(4)));

__device__ inline unsigned short f2bf(float x) {
    union { float f; unsigned u; } v; v.f = x;
    unsigned r = v.u + 0x7fffu + ((v.u >> 16) & 1u);
    return (unsigned short)(r >> 16);
}
__device__ inline float bf2f(unsigned short h) {
    union { unsigned u; float f; } v; v.u = ((unsigned)h) << 16;
    return v.f;
}
__device__ inline float softplus_f(float x) {
    return (x > 20.0f) ? x : log1pf(__expf(x));
}
__device__ inline float gelu_f(float x) {
    return 0.5f * x * (1.0f + erff(x * 0.70710678118654752f));
}
__device__ inline float silu_f(float x) {
    return x / (1.0f + __expf(-x));
}
__device__ inline void gload16(const unsigned short* g, unsigned short* l) {
    typedef unsigned int u32;
    __builtin_amdgcn_global_load_lds(
        (const __attribute__((address_space(1))) u32*)g,
        (__attribute__((address_space(3))) u32*)l, 16, 0, 0);
}

// no sched_barrier(0): m141 showed order-pinning costs ~1.7x. asm "memory"
// clobbers still order all memory ops; compiler tracks ds_read->MFMA deps.
#define PHASE_SYNC_PRE()  do { __builtin_amdgcn_s_barrier(); \
                               asm volatile("s_waitcnt lgkmcnt(0)" ::: "memory"); } while (0)
#define PHASE_SYNC_POST() do { __builtin_amdgcn_s_barrier(); } while (0)

// ---------------- prep mega-kernel: weight conv + xproj pad + LN1 ----------------
__global__ __launch_bounds__(256) void prep_kernel(
    const float* __restrict__ s0, unsigned short* __restrict__ d0,
    const float* __restrict__ s1, unsigned short* __restrict__ d1,
    const float* __restrict__ s2, unsigned short* __restrict__ d2,
    const float* __restrict__ s3, unsigned short* __restrict__ d3,
    const float* __restrict__ s4, unsigned short* __restrict__ d4,
    const float* __restrict__ xpw, unsigned short* __restrict__ xpd,
    const float* __restrict__ x, const float* __restrict__ g1,
    const float* __restrict__ b1, unsigned short* __restrict__ xout) {
    int b = blockIdx.x;
    if (b < 4400) {
        const float* s; unsigned short* d; int base;
        if      (b < 1536) { s = s0; d = d0; base = b * 2048; }
        else if (b < 1584) { s = s1; d = d1; base = (b - 1536) * 2048; }
        else if (b < 2352) { s = s2; d = d2; base = (b - 1584) * 2048; }
        else if (b < 3376) { s = s3; d = d3; base = (b - 2352) * 2048; }
        else               { s = s4; d = d4; base = (b - 3376) * 2048; }
        int i = base + threadIdx.x * 8;
        float4 v0 = *(const float4*)(s + i);
        float4 v1 = *(const float4*)(s + i + 4);
        ushort4 a, c;
        a.x = f2bf(v0.x); a.y = f2bf(v0.y); a.z = f2bf(v0.z); a.w = f2bf(v0.w);
        c.x = f2bf(v1.x); c.y = f2bf(v1.y); c.z = f2bf(v1.z); c.w = f2bf(v1.w);
        *(ushort4*)(d + i)     = a;
        *(ushort4*)(d + i + 4) = c;
    } else if (b < 4528) {
        int row = b - 4400;
        for (int c = threadIdx.x; c < D_INNER; c += 256)
            xpd[row * D_INNER + c] = (row < 80) ? f2bf(xpw[row * D_INNER + c]) : (unsigned short)0;
    } else {
        __shared__ float sbuf[4];
        int row = b - 4528;
        int t = threadIdx.x;
        float4 v = ((const float4*)(x + (size_t)row * D_MODEL))[t];
        float s = v.x + v.y + v.z + v.w;
        for (int o = 32; o; o >>= 1) s += __shfl_down(s, o, 64);
        if ((t & 63) == 0) sbuf[t >> 6] = s;
        __syncthreads();
        float mu = (sbuf[0] + sbuf[1] + sbuf[2] + sbuf[3]) * (1.0f / D_MODEL);
        __syncthreads();
        float e0 = v.x - mu, e1 = v.y - mu, e2 = v.z - mu, e3 = v.w - mu;
        float q = e0*e0 + e1*e1 + e2*e2 + e3*e3;
        for (int o = 32; o; o >>= 1) q += __shfl_down(q, o, 64);
        if ((t & 63) == 0) sbuf[t >> 6] = q;
        __syncthreads();
        float var = (sbuf[0] + sbuf[1] + sbuf[2] + sbuf[3]) * (1.0f / D_MODEL);
        float rs = rsqrtf(var + 1e-5f);
        float4 gv = ((const float4*)g1)[t];
        float4 bv = ((const float4*)b1)[t];
        ushort4 st;
        st.x = f2bf(e0 * rs * gv.x + bv.x);
        st.y = f2bf(e1 * rs * gv.y + bv.y);
        st.z = f2bf(e2 * rs * gv.z + bv.z);
        st.w = f2bf(e3 * rs * gv.w + bv.w);
        ((ushort4*)(xout + (size_t)row * D_MODEL))[t] = st;
    }
}

// ---------------- LayerNorm -> bf16 (standalone, unused slots kept small) ----------------
__global__ __launch_bounds__(256) void ln_kernel(const float* __restrict__ x,
                                                 const float* __restrict__ g,
                                                 const float* __restrict__ b,
                                                 unsigned short* __restrict__ out) {
    __shared__ float sbuf[4];
    int row = blockIdx.x;
    int t = threadIdx.x;
    float4 v = ((const float4*)(x + (size_t)row * D_MODEL))[t];
    float s = v.x + v.y + v.z + v.w;
    for (int o = 32; o; o >>= 1) s += __shfl_down(s, o, 64);
    if ((t & 63) == 0) sbuf[t >> 6] = s;
    __syncthreads();
    float mu = (sbuf[0] + sbuf[1] + sbuf[2] + sbuf[3]) * (1.0f / D_MODEL);
    __syncthreads();
    float d0 = v.x - mu, d1 = v.y - mu, d2 = v.z - mu, d3 = v.w - mu;
    float q = d0*d0 + d1*d1 + d2*d2 + d3*d3;
    for (int o = 32; o; o >>= 1) q += __shfl_down(q, o, 64);
    if ((t & 63) == 0) sbuf[t >> 6] = q;
    __syncthreads();
    float var = (sbuf[0] + sbuf[1] + sbuf[2] + sbuf[3]) * (1.0f / D_MODEL);
    float rs = rsqrtf(var + 1e-5f);
    float4 gv = ((const float4*)g)[t];
    float4 bv = ((const float4*)b)[t];
    ushort4 st;
    st.x = f2bf(d0 * rs * gv.x + bv.x);
    st.y = f2bf(d1 * rs * gv.y + bv.y);
    st.z = f2bf(d2 * rs * gv.z + bv.z);
    st.w = f2bf(d3 * rs * gv.w + bv.w);
    ((ushort4*)(out + (size_t)row * D_MODEL))[t] = st;
}

// ---------------- epilogue IDs ----------------
#define EPI_F32        0
#define EPI_F32_BF16   1
#define EPI_SOFTPLUS   2
#define EPI_RESID      3
#define EPI_GELU_BF16  4
#define EPI_BIAS_RESID 5
#define EPI_BF16       6
#define EPI_SOFTPLUS_BF16 7   // Cb = bf16(softplus(acc + bias))

// ================= 8-phase 256-row MFMA GEMM (NT) =================
template<int WN, int EPI, int SPLITK>
__global__ __launch_bounds__(512, 2) void gemm8p(
    const unsigned short* __restrict__ A, int lda,
    const unsigned short* __restrict__ Bm, int ldb, int K,
    float* __restrict__ Cf, unsigned short* __restrict__ Cb, int ldc,
    const float* __restrict__ bias,
    const float* __restrict__ resid, int ldr) {
    constexpr int WM = 8 / WN;
    constexpr int BN = WN * 64;
    constexpr int RW = 256 / WM;
    constexpr int CW = 64;
    constexpr int MI = RW / 16;
    constexpr int NI = CW / 16;
    constexpr int MIH = MI / 2, NIH = NI / 2;
    constexpr int ABYTES = 256 * 128;
    constexpr int BBYTES = BN * 128;
    constexpr int BOFF = 2 * ABYTES;
    __shared__ unsigned short lds[(2 * ABYTES + 2 * BBYTES) / 2];

    const int t = threadIdx.x, l = t & 63, w = t >> 6;
    const int wr = w / WN, wc = w % WN;

    const int nx = gridDim.x;
    const int nwg = nx * gridDim.y;
    int bid = blockIdx.y * nx + blockIdx.x;
    int q = nwg >> 3;
    int swz = (bid & 7) * q + (bid >> 3);
    const int m0 = (swz / nx) * 256, n0 = (swz % nx) * BN;
    const int kbase = (SPLITK > 1) ? blockIdx.z * K : 0;

    // involution swizzle: LDS[r][byte] = G[r][byte ^ ((r&7)<<4)]
    const int sr = l >> 3;
    const int sj = ((l & 7) * 16) ^ ((l >> 3) << 4);
    const int row_l = w * 8;
    const int row_c = (w >> 2) * 64 + (w & 3) * 8;

    auto STG = [&](int bufbyte, int rowbase, const unsigned short* G, int ldg, int gbase, int kt) {
        unsigned short* dst = (unsigned short*)((char*)lds + bufbyte + rowbase * 128);
        const unsigned short* src = G + (size_t)(gbase + rowbase + sr) * ldg + kbase + kt * 64 + (sj >> 1);
        gload16(src, dst);
    };
    auto S_Ah0 = [&](int b, int kt) {
        if (WN == 4) { STG(b * ABYTES, row_l, A, lda, m0, kt);       STG(b * ABYTES, 128 + row_l, A, lda, m0, kt); }
        else         { STG(b * ABYTES, row_c, A, lda, m0, kt);       STG(b * ABYTES, 128 + row_c, A, lda, m0, kt); }
    };
    auto S_Ah1 = [&](int b, int kt) {
        if (WN == 4) { STG(b * ABYTES, 64 + row_l, A, lda, m0, kt);  STG(b * ABYTES, 192 + row_l, A, lda, m0, kt); }
        else         { STG(b * ABYTES, 32 + row_c, A, lda, m0, kt);  STG(b * ABYTES, 160 + row_c, A, lda, m0, kt); }
    };
    auto S_Bc0 = [&](int b, int kt) {
        if (WN == 4) { STG(BOFF + b * BBYTES, row_c, Bm, ldb, n0, kt); STG(BOFF + b * BBYTES, 128 + row_c, Bm, ldb, n0, kt); }
        else         { STG(BOFF + b * BBYTES, row_c, Bm, ldb, n0, kt); }
    };
    auto S_Bc1 = [&](int b, int kt) {
        if (WN == 4) { STG(BOFF + b * BBYTES, 32 + row_c, Bm, ldb, n0, kt); STG(BOFF + b * BBYTES, 160 + row_c, Bm, ldb, n0, kt); }
        else         { STG(BOFF + b * BBYTES, 32 + row_c, Bm, ldb, n0, kt); }
    };

    auto LD = [&](int bytebase, int row, int kb) -> bf16x8 {
        int o = bytebase + row * 128 + (kb ^ ((row & 7) << 4));
        return *(const bf16x8*)((const char*)lds + o);
    };

    f32x4 acc[MI][NI] = {};
    bf16x8 af[MIH][2], b0v[NIH][2], b1v[NIH][2];

    auto LDA_set = [&](int buf, int qr, auto& dst) {
        #pragma unroll
        for (int mi = 0; mi < MIH; mi++)
            #pragma unroll
            for (int ks = 0; ks < 2; ks++)
                dst[mi][ks] = LD(buf * ABYTES, wr * RW + qr * (RW / 2) + mi * 16 + (l & 15),
                                 ks * 64 + (l >> 4) * 16);
    };
    auto LDB_set = [&](int buf, int qc, auto& dst) {
        #pragma unroll
        for (int ni2 = 0; ni2 < NIH; ni2++)
            #pragma unroll
            for (int ks = 0; ks < 2; ks++)
                dst[ni2][ks] = LD(BOFF + buf * BBYTES, wc * CW + qc * 32 + ni2 * 16 + (l & 15),
                                  ks * 64 + (l >> 4) * 16);
    };
    auto MFMA_Q = [&](int qr, int qc, auto& a_, auto& b_) {
        __builtin_amdgcn_s_setprio(1);
        #pragma unroll
        for (int mi = 0; mi < MIH; mi++)
            #pragma unroll
            for (int ni2 = 0; ni2 < NIH; ni2++)
                #pragma unroll
                for (int ks = 0; ks < 2; ks++)
                    acc[qr * MIH + mi][qc * NIH + ni2] =
                        __builtin_amdgcn_mfma_f32_16x16x32_bf16(a_[mi][ks], b_[ni2][ks],
                                                                acc[qr * MIH + mi][qc * NIH + ni2], 0, 0, 0);
        __builtin_amdgcn_s_setprio(0);
    };
    auto VMW = [&](bool last) {
        if (last)            asm volatile("s_waitcnt vmcnt(0)" ::: "memory");
        else if (WN == 4)    asm volatile("s_waitcnt vmcnt(6)" ::: "memory");
        else                 asm volatile("s_waitcnt vmcnt(5)" ::: "memory");
    };

    const int ni_ = K >> 7;

    S_Ah0(0, 0); S_Ah1(0, 0); S_Bc0(0, 0); S_Bc1(0, 0);
    S_Ah0(1, 1); S_Ah1(1, 1); S_Bc0(1, 1); S_Bc1(1, 1);
    if (WN == 4) asm volatile("s_waitcnt vmcnt(8)" ::: "memory");
    else         asm volatile("s_waitcnt vmcnt(6)" ::: "memory");
    __builtin_amdgcn_s_barrier();

    for (int i = 0; i < ni_; i++) {
        const bool last = (i == ni_ - 1);
        const int t2 = 2 * i + 2, t3 = 2 * i + 3;
        // phase 1
        LDA_set(0, 0, af); LDB_set(0, 0, b0v);
        if (i) S_Bc0(1, 2 * i + 1);
        PHASE_SYNC_PRE(); MFMA_Q(0, 0, af, b0v); PHASE_SYNC_POST();
        // phase 2
        LDB_set(0, 1, b1v);
        if (!last) S_Ah0(0, t2);
        PHASE_SYNC_PRE(); MFMA_Q(0, 1, af, b1v); PHASE_SYNC_POST();
        // phase 3
        LDA_set(0, 1, af);
        PHASE_SYNC_PRE(); MFMA_Q(1, 1, af, b1v); PHASE_SYNC_POST();
        // phase 4
        LDB_set(0, 0, b0v);
        if (!last) { S_Ah1(0, t2); S_Bc1(0, t2); }
        VMW(last);
        PHASE_SYNC_PRE(); MFMA_Q(1, 0, af, b0v); PHASE_SYNC_POST();
        // phase 5
        LDA_set(1, 0, af); LDB_set(1, 0, b0v);
        if (!last) S_Bc0(0, t2);
        PHASE_SYNC_PRE(); MFMA_Q(0, 0, af, b0v); PHASE_SYNC_POST();
        // phase 6
        LDB_set(1, 1, b1v);
        if (!last) S_Ah0(1, t3);
        PHASE_SYNC_PRE(); MFMA_Q(0, 1, af, b1v); PHASE_SYNC_POST();
        // phase 7
        LDA_set(1, 1, af);
        PHASE_SYNC_PRE(); MFMA_Q(1, 1, af, b1v); PHASE_SYNC_POST();
        // phase 8
        LDB_set(1, 0, b0v);
        if (!last) { S_Ah1(1, t3); S_Bc1(1, t3); }
        VMW(last);
        PHASE_SYNC_PRE(); MFMA_Q(1, 0, af, b0v); PHASE_SYNC_POST();
    }

    float* Cfp = Cf;
    if (SPLITK > 1) Cfp += (size_t)blockIdx.z * NROWS * ldc;
    #pragma unroll
    for (int ni2 = 0; ni2 < NI; ni2++) {
        int col = n0 + wc * CW + ni2 * 16 + (l & 15);
        float bv = 0.0f;
        if (EPI == EPI_SOFTPLUS || EPI == EPI_GELU_BF16 || EPI == EPI_BIAS_RESID) bv = bias[col];
        #pragma unroll
        for (int mi = 0; mi < MI; mi++) {
            #pragma unroll
            for (int j = 0; j < 4; j++) {
                int row = m0 + wr * RW + mi * 16 + (l >> 4) * 4 + j;
                float v = acc[mi][ni2][j];
                if (EPI == EPI_SOFTPLUS)        v = softplus_f(v + bv);
                else if (EPI == EPI_GELU_BF16)  v = gelu_f(v + bv);
                else if (EPI == EPI_RESID)      v = v + resid[(size_t)row * ldr + col];
                else if (EPI == EPI_BIAS_RESID) v = v + bv + resid[(size_t)row * ldr + col];
                if (EPI == EPI_GELU_BF16 || EPI == EPI_BF16) {
                    Cb[(size_t)row * ldc + col] = f2bf(v);
                } else {
                    Cfp[(size_t)row * ldc + col] = v;
                    if (EPI == EPI_F32_BF16) Cb[(size_t)row * ldc + col] = f2bf(v);
                }
            }
        }
    }
}

// ---------------- fused split-K=2 reduce (+resid) + LayerNorm -> x2 f32, xn bf16 ----------------
__global__ __launch_bounds__(256) void sk2_ln(const float* __restrict__ p,
                                              const float* __restrict__ resid,
                                              const float* __restrict__ g,
                                              const float* __restrict__ b,
                                              float* __restrict__ x2,
                                              unsigned short* __restrict__ xn) {
    __shared__ float sbuf[4];
    int row = blockIdx.x;
    int t = threadIdx.x;
    const size_t seg = (size_t)NROWS * D_MODEL;
    size_t base = (size_t)row * D_MODEL + t * 4;
    float4 a = *(const float4*)(p + base);
    float4 bb = *(const float4*)(p + base + seg);
    float4 r = *(const float4*)(resid + base);
    float4 v;
    v.x = a.x + bb.x + r.x;
    v.y = a.y + bb.y + r.y;
    v.z = a.z + bb.z + r.z;
    v.w = a.w + bb.w + r.w;
    *(float4*)(x2 + base) = v;
    float s = v.x + v.y + v.z + v.w;
    for (int o = 32; o; o >>= 1) s += __shfl_down(s, o, 64);
    if ((t & 63) == 0) sbuf[t >> 6] = s;
    __syncthreads();
    float mu = (sbuf[0] + sbuf[1] + sbuf[2] + sbuf[3]) * (1.0f / D_MODEL);
    __syncthreads();
    float d0 = v.x - mu, d1 = v.y - mu, d2 = v.z - mu, d3 = v.w - mu;
    float qq = d0*d0 + d1*d1 + d2*d2 + d3*d3;
    for (int o = 32; o; o >>= 1) qq += __shfl_down(qq, o, 64);
    if ((t & 63) == 0) sbuf[t >> 6] = qq;
    __syncthreads();
    float var = (sbuf[0] + sbuf[1] + sbuf[2] + sbuf[3]) * (1.0f / D_MODEL);
    float rs = rsqrtf(var + 1e-5f);
    float4 gv = ((const float4*)g)[t];
    float4 bv = ((const float4*)b)[t];
    ushort4 st;
    st.x = f2bf(d0 * rs * gv.x + bv.x);
    st.y = f2bf(d1 * rs * gv.y + bv.y);
    st.z = f2bf(d2 * rs * gv.z + bv.z);
    st.w = f2bf(d3 * rs * gv.w + bv.w);
    ((ushort4*)(xn + (size_t)row * D_MODEL))[t] = st;
}

// ---------------- split-K=2 reduce + bias + resid (final output) ----------------
__global__ __launch_bounds__(256) void sk2_reduce(const float* __restrict__ p,
                                                  const float* __restrict__ bias,
                                                  const float* __restrict__ resid,
                                                  float* __restrict__ o) {
    int i = (blockIdx.x * 256 + threadIdx.x) * 4;
    const size_t seg = (size_t)NROWS * D_MODEL;
    float4 a = *(const float4*)(p + i);
    float4 b = *(const float4*)(p + i + seg);
    float4 r = *(const float4*)(resid + i);
    float4 bb = *(const float4*)(bias + (i & (D_MODEL - 1)));
    float4 o4;
    o4.x = a.x + b.x + r.x + bb.x;
    o4.y = a.y + b.y + r.y + bb.y;
    o4.z = a.z + b.z + r.z + bb.z;
    o4.w = a.w + b.w + r.w + bb.w;
    *(float4*)(o + i) = o4;
}

// ---------------- small-GEMM path (x_proj, dt_proj): 128x128, 3-buf ----------------
template<int EPI, int SPLITK>
__global__ __launch_bounds__(256) void gemm_mfma(
    const unsigned short* __restrict__ A, int lda,
    const unsigned short* __restrict__ B, int ldb, int K,
    float* __restrict__ Cf, unsigned short* __restrict__ Cb, int ldc,
    const float* __restrict__ bias,
    const float* __restrict__ resid, int ldr) {
    __shared__ unsigned short As[3][128 * 32];
    __shared__ unsigned short Bs[3][128 * 32];
    int t = threadIdx.x, l = t & 63, w = t >> 6;
    int nx = gridDim.x;
    int nwg = nx * gridDim.y;
    int bid = blockIdx.y * nx + blockIdx.x;
    int q = nwg >> 3;
    int swz = (bid & 7) * q + (bid >> 3);
    int m0 = (swz / nx) * 128, n0 = (swz % nx) * 128;
    int kbase = (SPLITK > 1) ? blockIdx.z * K : 0;
    int c0 = 2 * w, c1 = 2 * w + 1;
    int srow = l >> 2, scol = (l & 3) * 8;
    const unsigned short* Ag0 = A + (size_t)(m0 + 16 * c0 + srow) * lda + kbase + scol;
    const unsigned short* Ag1 = A + (size_t)(m0 + 16 * c1 + srow) * lda + kbase + scol;
    const unsigned short* Bg0 = B + (size_t)(n0 + 16 * c0 + srow) * ldb + kbase + scol;
    const unsigned short* Bg1 = B + (size_t)(n0 + 16 * c1 + srow) * ldb + kbase + scol;
    int wr = w >> 1, wc = w & 1;
    int aoff = (wr * 64 + (l & 15)) * 32 + (l >> 4) * 8;
    int boff = (wc * 64 + (l & 15)) * 32 + (l >> 4) * 8;

    f32x4 acc[4][4] = {};
    int nt = K >> 5;

    gload16(Ag0, &As[0][c0 * 512]);
    gload16(Ag1, &As[0][c1 * 512]);
    gload16(Bg0, &Bs[0][c0 * 512]);
    gload16(Bg1, &Bs[0][c1 * 512]);
    if (nt > 1) {
        gload16(Ag0 + 32, &As[1][c0 * 512]);
        gload16(Ag1 + 32, &As[1][c1 * 512]);
        gload16(Bg0 + 32, &Bs[1][c0 * 512]);
        gload16(Bg1 + 32, &Bs[1][c1 * 512]);
    }

    int cur = 0;
    for (int ti = 0; ti < nt; ti++) {
        int pf = ti + 2;
        if (pf < nt) {
            int nb = cur - 1; if (nb < 0) nb += 3;
            int k0 = pf << 5;
            gload16(Ag0 + k0, &As[nb][c0 * 512]);
            gload16(Ag1 + k0, &As[nb][c1 * 512]);
            gload16(Bg0 + k0, &Bs[nb][c0 * 512]);
            gload16(Bg1 + k0, &Bs[nb][c1 * 512]);
        }
        int rem = nt - 1 - ti;
        if (rem >= 2)      asm volatile("s_waitcnt vmcnt(8)" ::: "memory");
        else if (rem == 1) asm volatile("s_waitcnt vmcnt(4)" ::: "memory");
        else               asm volatile("s_waitcnt vmcnt(0)" ::: "memory");
        __builtin_amdgcn_s_barrier();

        const unsigned short* Ab = &As[cur][0];
        const unsigned short* Bb = &Bs[cur][0];
        bf16x8 af[4], bfv[4];
        #pragma unroll
        for (int i = 0; i < 4; i++) af[i] = *(const bf16x8*)(Ab + aoff + i * 512);
        #pragma unroll
        for (int i = 0; i < 4; i++) bfv[i] = *(const bf16x8*)(Bb + boff + i * 512);
        __builtin_amdgcn_s_setprio(1);
        #pragma unroll
        for (int mi = 0; mi < 4; mi++)
            #pragma unroll
            for (int ni = 0; ni < 4; ni++)
                acc[mi][ni] = __builtin_amdgcn_mfma_f32_16x16x32_bf16(af[mi], bfv[ni], acc[mi][ni], 0, 0, 0);
        __builtin_amdgcn_s_setprio(0);
        __builtin_amdgcn_s_barrier();
        cur++; if (cur == 3) cur = 0;
    }

    if (SPLITK > 1) Cf += (size_t)blockIdx.z * NROWS * ldc;
    int colb = n0 + wc * 64 + (l & 15);
    int rowb = m0 + wr * 64 + (l >> 4) * 4;
    #pragma unroll
    for (int ni = 0; ni < 4; ni++) {
        int col = colb + ni * 16;
        float bv = 0.0f;
        if (EPI == EPI_SOFTPLUS || EPI == EPI_GELU_BF16 || EPI == EPI_BIAS_RESID || EPI == EPI_SOFTPLUS_BF16) bv = bias[col];
        #pragma unroll
        for (int mi = 0; mi < 4; mi++) {
            #pragma unroll
            for (int j = 0; j < 4; j++) {
                int row = rowb + mi * 16 + j;
                float v = acc[mi][ni][j];
                if (EPI == EPI_SOFTPLUS || EPI == EPI_SOFTPLUS_BF16) v = softplus_f(v + bv);
                else if (EPI == EPI_GELU_BF16)  v = gelu_f(v + bv);
                else if (EPI == EPI_RESID)      v = v + resid[(size_t)row * ldr + col];
                else if (EPI == EPI_BIAS_RESID) v = v + bv + resid[(size_t)row * ldr + col];
                if (EPI == EPI_GELU_BF16 || EPI == EPI_BF16 || EPI == EPI_SOFTPLUS_BF16) {
                    Cb[(size_t)row * ldc + col] = f2bf(v);
                } else {
                    Cf[(size_t)row * ldc + col] = v;
                    if (EPI == EPI_F32_BF16) Cb[(size_t)row * ldc + col] = f2bf(v);
                }
            }
        }
    }
}

// ---------------- x_proj split-K partial reduce ----------------
__global__ __launch_bounds__(256) void xdbl_reduce(const float* __restrict__ part,
                                                   float* __restrict__ xdbl,
                                                   unsigned short* __restrict__ xdbl_bf) {
    int i = blockIdx.x * 256 + threadIdx.x;
    const size_t seg = (size_t)NROWS * XPAD;
    float s = part[i] + part[i + seg] + part[i + 2 * seg] + part[i + 3 * seg];
    xdbl[i] = s;
    xdbl_bf[i] = f2bf(s);
}

// ---------------- causal depthwise conv (k=4) + SiLU -> bf16 u (8-wide) ----------------
__global__ __launch_bounds__(256) void conv_silu(const unsigned short* __restrict__ xz,
                                                 const float* __restrict__ w,
                                                 const float* __restrict__ cb,
                                                 unsigned short* __restrict__ u) {
    int idx = (blockIdx.x * 256 + threadIdx.x) * 8;
    int d = idx % D_INNER;
    int bl = idx / D_INNER;
    int l = bl & (SEQ - 1);
    float acc[8];
    float4 wv[8];
    #pragma unroll
    for (int j = 0; j < 8; j++) wv[j] = *(const float4*)(w + (d + j) * 4);
    float4 cb0 = *(const float4*)(cb + d);
    float4 cb1 = *(const float4*)(cb + d + 4);
    acc[0] = cb0.x; acc[1] = cb0.y; acc[2] = cb0.z; acc[3] = cb0.w;
    acc[4] = cb1.x; acc[5] = cb1.y; acc[6] = cb1.z; acc[7] = cb1.w;
    #pragma unroll
    for (int k = 0; k < 4; k++) {
        int lp = l - 3 + k;
        if (lp >= 0) {
            u16x8 s = *(const u16x8*)(xz + (size_t)(bl - 3 + k) * (2 * D_INNER) + d);
            #pragma unroll
            for (int j = 0; j < 8; j++) {
                float wk = (k == 0) ? wv[j].x : (k == 1) ? wv[j].y : (k == 2) ? wv[j].z : wv[j].w;
                acc[j] += bf2f((unsigned short)s[j]) * wk;
            }
        }
    }
    u16x8 o;
    #pragma unroll
    for (int j = 0; j < 8; j++) o[j] = f2bf(silu_f(acc[j]));
    *(u16x8*)(u + idx) = o;
}

// ---------------- selective scan: pass A ----------------
__global__ __launch_bounds__(256) void scan_passA(const unsigned short* __restrict__ delta,
                                                  const unsigned short* __restrict__ u,
                                                  const float* __restrict__ xdbl,
                                                  const float* __restrict__ A_log,
                                                  float* __restrict__ P,
                                                  float* __restrict__ S) {
    int d = blockIdx.x * 256 + threadIdx.x;
    int c = blockIdx.y, b = blockIdx.z;
    __shared__ float bc[LC][16];
    int base_row = b * SEQ + c * LC;
    for (int e = threadIdx.x; e < LC * 16; e += 256) {
        int lrr = e >> 4, col = e & 15;
        bc[lrr][col] = xdbl[(size_t)(base_row + lrr) * XPAD + DT_RANK + col];
    }
    __syncthreads();
    float Ad[8];
    #pragma unroll
    for (int n = 0; n < 8; n++) Ad[n] = -__expf(A_log[d * 8 + n]);
    float prod[8], hs[8];
    #pragma unroll
    for (int n = 0; n < 8; n++) { prod[n] = 1.0f; hs[n] = 0.0f; }
    for (int lrr = 0; lrr < LC; lrr++) {
        int row = base_row + lrr;
        float dl = bf2f(delta[(size_t)row * D_INNER + d]);
        float uu = bf2f(u[(size_t)row * D_INNER + d]);
        float du = dl * uu;
        #pragma unroll
        for (int n = 0; n < 8; n++) {
            float dA = __expf(dl * Ad[n]);
            prod[n] *= dA;
            hs[n] = dA * hs[n] + du * bc[lrr][n];
        }
    }
    size_t o = ((size_t)((size_t)b * NC + c) * D_INNER + d) * 8;
    #pragma unroll
    for (int n = 0; n < 8; n++) { P[o + n] = prod[n]; S[o + n] = hs[n]; }
}

// ---------------- scan: pass B ----------------
__global__ __launch_bounds__(256) void scan_passB(const float* __restrict__ P,
                                                  const float* __restrict__ S,
                                                  float* __restrict__ hstart) {
    int tid = blockIdx.x * 256 + threadIdx.x;
    int b = tid / (D_INNER * 8);
    int rem = tid % (D_INNER * 8);
    float h = 0.0f;
    for (int c = 0; c < NC; c++) {
        size_t o = (size_t)(b * NC + c) * (D_INNER * 8) + rem;
        hstart[o] = h;
        h = P[o] * h + S[o];
    }
}

// ---------------- scan: pass C -> bf16 ygate ----------------
__global__ __launch_bounds__(256) void scan_passC(const unsigned short* __restrict__ delta,
                                                  const unsigned short* __restrict__ u,
                                                  const float* __restrict__ xdbl,
                                                  const float* __restrict__ A_log,
                                                  const float* __restrict__ hstart,
                                                  const unsigned short* __restrict__ xz,
                                                  const float* __restrict__ Dp,
                                                  unsigned short* __restrict__ ygate) {
    int d = blockIdx.x * 256 + threadIdx.x;
    int c = blockIdx.y, b = blockIdx.z;
    __shared__ float bc[LC][16];
    int base_row = b * SEQ + c * LC;
    for (int e = threadIdx.x; e < LC * 16; e += 256) {
        int lrr = e >> 4, col = e & 15;
        bc[lrr][col] = xdbl[(size_t)(base_row + lrr) * XPAD + DT_RANK + col];
    }
    __syncthreads();
    float Ad[8];
    #pragma unroll
    for (int n = 0; n < 8; n++) Ad[n] = -__expf(A_log[d * 8 + n]);
    float h[8];
    size_t ho = ((size_t)((size_t)b * NC + c) * D_INNER + d) * 8;
    #pragma unroll
    for (int n = 0; n < 8; n++) h[n] = hstart[ho + n];
    float Dd = Dp[d];
    for (int lrr = 0; lrr < LC; lrr++) {
        int row = base_row + lrr;
        float dl = bf2f(delta[(size_t)row * D_INNER + d]);
        float uu = bf2f(u[(size_t)row * D_INNER + d]);
        float du = dl * uu;
        float y = 0.0f;
        #pragma unroll
        for (int n = 0; n < 8; n++) {
            float dA = __expf(dl * Ad[n]);
            h[n] = dA * h[n] + du * bc[lrr][n];
            y += h[n] * bc[lrr][8 + n];
        }
        y += uu * Dd;
        float z = bf2f(xz[(size_t)row * (2 * D_INNER) + D_INNER + d]);
        ygate[(size_t)row * D_INNER + d] = f2bf(y * silu_f(z));
    }
}

// ---------------- launch ----------------
extern "C" void kernel_launch(void* const* d_in, const int* in_sizes, int n_in,
                              void* d_out, int out_size, void* d_ws, size_t ws_size,
                              hipStream_t stream) {
    const float* x         = (const float*)d_in[0];
    const float* ln1_g     = (const float*)d_in[1];
    const float* ln1_b     = (const float*)d_in[2];
    const float* ln2_g     = (const float*)d_in[3];
    const float* ln2_b     = (const float*)d_in[4];
    const float* in_proj_w = (const float*)d_in[5];
    const float* conv_w    = (const float*)d_in[6];
    const float* conv_b    = (const float*)d_in[7];
    const float* x_proj_w  = (const float*)d_in[8];
    const float* dt_proj_w = (const float*)d_in[9];
    const float* dt_proj_b = (const float*)d_in[10];
    const float* A_log     = (const float*)d_in[11];
    const float* Dp        = (const float*)d_in[12];
    const float* out_proj_w= (const float*)d_in[13];
    const float* ffn_w1    = (const float*)d_in[14];
    const float* ffn_b1    = (const float*)d_in[15];
    const float* ffn_w2    = (const float*)d_in[16];
    const float* ffn_b2    = (const float*)d_in[17];
    float* out = (float*)d_out;

    // ---- workspace layout (f32 region, then bf16 region) ----
    float* xdbl  = (float*)d_ws;                           // 4096*128
    float* P     = xdbl + (size_t)NROWS * XPAD;            // 786432
    float* S     = P + (size_t)BATCH * NC * D_INNER * 8;
    float* hst   = S + (size_t)BATCH * NC * D_INNER * 8;
    float* x2    = hst + (size_t)BATCH * NC * D_INNER * 8; // 4096*1024
    float* psum  = x2 + (size_t)NROWS * D_MODEL;           // 2*4096*1024 (dedicated)
    float* part  = psum;                                   // overlay: x_proj splitK partials (dead before out_proj)
    unsigned short* xz_bf   = (unsigned short*)(psum + 2 * (size_t)NROWS * D_MODEL); // 4096*3072
    unsigned short* xp_bf   = xz_bf + (size_t)NROWS * 2 * D_INNER;   // 4096*1024 (reused as xn_bf)
    unsigned short* u_bf    = xp_bf + (size_t)NROWS * D_MODEL;       // 4096*1536
    unsigned short* xdbl_bf = u_bf + (size_t)NROWS * D_INNER;        // 4096*128
    unsigned short* yg_bf   = xdbl_bf + (size_t)NROWS * XPAD;        // 4096*1536
    unsigned short* dl_bf   = yg_bf + (size_t)NROWS * D_INNER;       // 4096*1536 (delta bf16)
    unsigned short* w_in    = dl_bf + (size_t)NROWS * D_INNER;       // 3072*1024
    unsigned short* w_xp    = w_in + (size_t)2 * D_INNER * D_MODEL;  // 128*1536
    unsigned short* w_dt    = w_xp + (size_t)XPAD * D_INNER;         // 1536*64
    unsigned short* w_out   = w_dt + (size_t)D_INNER * DT_RANK;      // 1024*1536
    unsigned short* w_f1    = w_out + (size_t)D_MODEL * D_INNER;     // 2048*1024
    unsigned short* w_f2    = w_f1 + (size_t)D_FF * D_MODEL;         // 1024*2048
    unsigned short* hff_bf  = xz_bf;   // overlay: xz dead after scan_passC

    // 0+1. prep: weight conversions + x_proj pad + LN1  (one kernel)
    prep_kernel<<<4400 + XPAD + NROWS, 256, 0, stream>>>(
        in_proj_w, w_in, dt_proj_w, w_dt, out_proj_w, w_out, ffn_w1, w_f1, ffn_w2, w_f2,
        x_proj_w, w_xp, x, ln1_g, ln1_b, xp_bf);
    // 2. in_proj (4096 x 3072, K=1024) -> bf16   [8-phase 256x256]
    gemm8p<4, EPI_BF16, 1><<<dim3(3072 / 256, NROWS / 256), 512, 0, stream>>>(
        xp_bf, D_MODEL, w_in, D_MODEL, D_MODEL, nullptr, xz_bf, 2 * D_INNER, nullptr, nullptr, 0);
    // 3. conv + silu -> u (bf16)
    conv_silu<<<(NROWS * D_INNER) / (256 * 8), 256, 0, stream>>>(xz_bf, conv_w, conv_b, u_bf);
    // 4. x_proj split-K=4 (4096 x 128pad, K=384 each)
    gemm_mfma<EPI_F32, 4><<<dim3(1, NROWS / 128, 4), 256, 0, stream>>>(
        u_bf, D_INNER, w_xp, D_INNER, D_INNER / 4, part, nullptr, XPAD, nullptr, nullptr, 0);
    xdbl_reduce<<<(NROWS * XPAD) / 256, 256, 0, stream>>>(part, xdbl, xdbl_bf);
    // 5. dt_proj + softplus -> delta bf16 (4096 x 1536, K=64)
    gemm_mfma<EPI_SOFTPLUS_BF16, 1><<<dim3(D_INNER / 128, NROWS / 128), 256, 0, stream>>>(
        xdbl_bf, XPAD, w_dt, DT_RANK, DT_RANK, nullptr, dl_bf, D_INNER, dt_proj_b, nullptr, 0);
    // 6-8. selective scan
    scan_passA<<<dim3(D_INNER / 256, NC, BATCH), 256, 0, stream>>>(dl_bf, u_bf, xdbl, A_log, P, S);
    scan_passB<<<(BATCH * D_INNER * 8) / 256, 256, 0, stream>>>(P, S, hst);
    scan_passC<<<dim3(D_INNER / 256, NC, BATCH), 256, 0, stream>>>(dl_bf, u_bf, xdbl, A_log, hst, xz_bf, Dp, yg_bf);
    // 9. out_proj split-K=2 (4096 x 1024, K=768 each)  [8-phase 256x128, 256 blocks]
    gemm8p<2, EPI_F32, 2><<<dim3(D_MODEL / 128, NROWS / 256, 2), 512, 0, stream>>>(
        yg_bf, D_INNER, w_out, D_INNER, D_INNER / 2, psum, nullptr, D_MODEL, nullptr, nullptr, 0);
    // 10. fused reduce + residual + LN2 -> x2 f32, xn bf16
    sk2_ln<<<NROWS, 256, 0, stream>>>(psum, x, ln2_g, ln2_b, x2, xp_bf);
    // 11. ffn1 + gelu -> bf16 hff  (4096 x 2048, K=1024)
    gemm8p<2, EPI_GELU_BF16, 1><<<dim3(D_FF / 128, NROWS / 256), 512, 0, stream>>>(
        xp_bf, D_MODEL, w_f1, D_MODEL, D_MODEL, nullptr, hff_bf, D_FF, ffn_b1, nullptr, 0);
    // 12. ffn2 split-K=2 (4096 x 1024, K=1024 each)
    gemm8p<2, EPI_F32, 2><<<dim3(D_MODEL / 128, NROWS / 256, 2), 512, 0, stream>>>(
        hff_bf, D_FF, w_f2, D_FF, D_FF / 2, psum, nullptr, D_MODEL, nullptr, nullptr, 0);
    sk2_reduce<<<(NROWS * D_MODEL) / 1024, 256, 0, stream>>>(psum, ffn_b2, x2, out);
}